// Round 1
// baseline (10573.747 us; speedup 1.0000x reference)
//
#include <hip/hip_runtime.h>
#include <hip/hip_bf16.h>
#include <math.h>

#define NU 100000
#define NI 50000
#define NENT 80000
#define NN 180000
#define NEDGE 800000

__device__ __forceinline__ float bcastf(float v, int k) {
    return __uint_as_float(__builtin_amdgcn_readlane(__float_as_uint(v), k));
}
__device__ __forceinline__ float sigmoid_f(float x) {
    return 1.0f / (1.0f + __expf(-x));
}
__device__ __forceinline__ void afadd(float* p, float v) {
    unsafeAtomicAdd(p, v);
}

// ---------------- edge pass: center softmax accum + offset-net accum ----------------
__global__ __launch_bounds__(256) void edge_pass(
    const float* __restrict__ embU, const float* __restrict__ embE,
    const float* __restrict__ offU, const float* __restrict__ offE,
    const int* __restrict__ head, const int* __restrict__ tail,
    const float* __restrict__ cW1, const float* __restrict__ cb1,
    const float* __restrict__ cW2, const float* __restrict__ cb2,
    const float* __restrict__ oW1, const float* __restrict__ ob1,
    float* __restrict__ numacc, float* __restrict__ sacc,
    float* __restrict__ sumact, float* __restrict__ redv, float* __restrict__ cntv)
{
    __shared__ float W1t[4096];
    __shared__ float W2t[4096];
    __shared__ float O1t[4096];
    // store transposed: Wt[k*64+d] = W[d*64+k]; coalesced LDS writes, scattered (cached) global reads
    for (int i = threadIdx.x; i < 4096; i += 256) {
        int k = i >> 6, d = i & 63;
        W1t[i] = cW1[d * 64 + k];
        W2t[i] = cW2[d * 64 + k];
        O1t[i] = oW1[d * 64 + k];
    }
    __syncthreads();
    int lane = threadIdx.x & 63;
    int eid = blockIdx.x * 4 + (threadIdx.x >> 6);
    if (eid >= NEDGE) return;
    int h = head[eid], t = tail[eid];
    float x = (t < NU) ? embU[(size_t)t * 64 + lane] : embE[(size_t)(t - NU) * 64 + lane];
    float o = (t < NU) ? offU[(size_t)t * 64 + lane] : offE[(size_t)(t - NU) * 64 + lane];
    o = fmaxf(o, 0.0f);

    // act1 = relu(cW1 x + cb1)
    float a1 = cb1[lane];
    #pragma unroll
    for (int k = 0; k < 64; ++k) a1 = fmaf(bcastf(x, k), W1t[k * 64 + lane], a1);
    a1 = fmaxf(a1, 0.0f);
    // logits = cW2 act1 + cb2   (skip segment-max shift: |logit| << 1, exp safe)
    float lg = cb2[lane];
    #pragma unroll
    for (int k = 0; k < 64; ++k) lg = fmaf(bcastf(a1, k), W2t[k * 64 + lane], lg);
    float ev = __expf(lg);
    afadd(&sacc[(size_t)h * 64 + lane], ev);
    afadd(&numacc[(size_t)h * 64 + lane], ev * x);

    // offset-net class (wave-uniform branch)
    int row; bool ismin;
    if (h < NU) {
        if (t < NU) return;                       // user->user edge: no offset mask
        else if (t < NU + NI) { row = h;      ismin = true;  }   // m_inter (min)
        else                  { row = NU + h; ismin = false; }   // m_ut (max)
    } else if (h < NU + NI) { row = 2 * NU + (h - NU); ismin = false; }  // m_item (max)
    else                    { row = 2 * NU + (h - NU); ismin = true;  }  // m_tag (min)

    float ao = ob1[lane];
    #pragma unroll
    for (int k = 0; k < 64; ++k) ao = fmaf(bcastf(o, k), O1t[k * 64 + lane], ao);
    ao = fmaxf(ao, 0.0f);
    afadd(&sumact[(size_t)row * 64 + lane], ao);
    if (lane == 0) afadd(&cntv[row], 1.0f);
    unsigned int* rp = (unsigned int*)(&redv[(size_t)row * 64 + lane]);
    unsigned int ob = __float_as_uint(o);        // o >= 0: uint order == float order
    if (ismin) atomicMin(rp, ob);
    else       atomicMax(rp, ob);
}

// ---------------- center finalize: num/s + row L2 normalize ----------------
__global__ __launch_bounds__(256) void center_fin(
    const float* __restrict__ numacc, const float* __restrict__ sacc,
    float* __restrict__ outU, float* __restrict__ outE)
{
    int lane = threadIdx.x & 63;
    int n = blockIdx.x * 4 + (threadIdx.x >> 6);
    if (n >= NN) return;
    float s = sacc[(size_t)n * 64 + lane];
    float v = (s > 0.0f) ? numacc[(size_t)n * 64 + lane] / s : 0.0f;
    float sq = v * v;
    #pragma unroll
    for (int m = 32; m; m >>= 1) sq += __shfl_xor(sq, m, 64);
    v = v / fmaxf(sqrtf(sq), 1e-12f);
    if (n < NU) outU[(size_t)n * 64 + lane] = v;
    else        outE[(size_t)(n - NU) * 64 + lane] = v;
}

// ---------------- user offset finalize (fused 2-level offset net) ----------------
__global__ __launch_bounds__(256) void user_fin(
    const float* __restrict__ sumact, const float* __restrict__ redv, const float* __restrict__ cntv,
    const float* __restrict__ oW1, const float* __restrict__ ob1,
    const float* __restrict__ oW2, const float* __restrict__ ob2,
    float* __restrict__ outOffU)
{
    __shared__ float O1t[4096];
    __shared__ float O2t[4096];
    for (int i = threadIdx.x; i < 4096; i += 256) {
        int k = i >> 6, d = i & 63;
        O1t[i] = oW1[d * 64 + k];
        O2t[i] = oW2[d * 64 + k];
    }
    __syncthreads();
    int lane = threadIdx.x & 63;
    int u = blockIdx.x * 4 + (threadIdx.x >> 6);
    if (u >= NU) return;
    float b1 = ob1[lane], b2 = ob2[lane];

    // inter (min class)
    float ci = fmaxf(cntv[u], 1.0f);
    float mi = sumact[(size_t)u * 64 + lane] / ci;
    float gi = b2;
    #pragma unroll
    for (int k = 0; k < 64; ++k) gi = fmaf(bcastf(mi, k), O2t[k * 64 + lane], gi);
    gi = sigmoid_f(gi);
    float ri = redv[(size_t)u * 64 + lane];
    if (ri > 1e37f) ri = 0.0f;
    float iu = ri * gi;

    // ut (max class)
    float cu = fmaxf(cntv[NU + u], 1.0f);
    float mu = sumact[(size_t)(NU + u) * 64 + lane] / cu;
    float gu = b2;
    #pragma unroll
    for (int k = 0; k < 64; ++k) gu = fmaf(bcastf(mu, k), O2t[k * 64 + lane], gu);
    gu = sigmoid_f(gu);
    float ru = redv[(size_t)(NU + u) * 64 + lane];
    if (ru > 1e37f) ru = 0.0f;
    float uu = ru * gu;

    // second-level offset net over the 2 rows {iu, uu}
    float a1 = b1, a2 = b1;
    #pragma unroll
    for (int k = 0; k < 64; ++k) a1 = fmaf(bcastf(iu, k), O1t[k * 64 + lane], a1);
    #pragma unroll
    for (int k = 0; k < 64; ++k) a2 = fmaf(bcastf(uu, k), O1t[k * 64 + lane], a2);
    float mn = (fmaxf(a1, 0.0f) + fmaxf(a2, 0.0f)) * 0.5f;
    float g = b2;
    #pragma unroll
    for (int k = 0; k < 64; ++k) g = fmaf(bcastf(mn, k), O2t[k * 64 + lane], g);
    g = sigmoid_f(g);
    outOffU[(size_t)u * 64 + lane] = fmaxf(fmaxf(iu, uu) * g, 0.0f);
}

// ---------------- ent (item+tag) offset finalize ----------------
__global__ __launch_bounds__(256) void ent_fin(
    const float* __restrict__ sumact, const float* __restrict__ redv, const float* __restrict__ cntv,
    const float* __restrict__ oW2, const float* __restrict__ ob2,
    float* __restrict__ outOffE)
{
    __shared__ float O2t[4096];
    for (int i = threadIdx.x; i < 4096; i += 256) {
        int k = i >> 6, d = i & 63;
        O2t[i] = oW2[d * 64 + k];
    }
    __syncthreads();
    int lane = threadIdx.x & 63;
    int idx = blockIdx.x * 4 + (threadIdx.x >> 6);
    if (idx >= NENT) return;
    size_t row = (size_t)(2 * NU) + idx;
    float c = fmaxf(cntv[row], 1.0f);
    float m = sumact[row * 64 + lane] / c;
    float g = ob2[lane];
    #pragma unroll
    for (int k = 0; k < 64; ++k) g = fmaf(bcastf(m, k), O2t[k * 64 + lane], g);
    g = sigmoid_f(g);
    float r = redv[row * 64 + lane];
    if (r > 1e37f) r = 0.0f;
    outOffE[(size_t)idx * 64 + lane] = r * g;
}

extern "C" void kernel_launch(void* const* d_in, const int* in_sizes, int n_in,
                              void* d_out, int out_size, void* d_ws, size_t ws_size,
                              hipStream_t stream)
{
    const float* user_emb = (const float*)d_in[0];
    const float* user_off = (const float*)d_in[1];
    const float* item_emb = (const float*)d_in[2];
    const float* item_off = (const float*)d_in[3];
    const float* cW1 = (const float*)d_in[4];
    const float* cb1 = (const float*)d_in[5];
    const float* cW2 = (const float*)d_in[6];
    const float* cb2 = (const float*)d_in[7];
    const float* oW1 = (const float*)d_in[8];
    const float* ob1 = (const float*)d_in[9];
    const float* oW2 = (const float*)d_in[10];
    const float* ob2 = (const float*)d_in[11];
    const int* head = (const int*)d_in[12];
    const int* tail = (const int*)d_in[13];
    float* out = (float*)d_out;

    float* ws = (float*)d_ws;
    const size_t SZ_NODE = (size_t)NN * 64;                 // 11,520,000 floats
    const size_t SEG_ROWS = (size_t)(2 * NU + NENT);        // 280,000 rows
    const size_t SZ_SEG = SEG_ROWS * 64;                    // 17,920,000 floats
    float* A  = ws;                 // layer-1 output embs [NN,64]
    float* B  = A + SZ_NODE;        // layer-1 output offs [NN,64]
    float* C  = B + SZ_NODE;        // softmax numerator
    float* Dp = C + SZ_NODE;        // softmax denominator
    float* Ep = Dp + SZ_NODE;       // masked act sums [280000,64]
    float* Gp = Ep + SZ_SEG;        // counts [280000]
    float* Fp = Gp + SEG_ROWS;      // min/max reductions [280000,64]

    for (int layer = 0; layer < 2; ++layer) {
        // zero num/denom/act-sums/counts (contiguous C..G)
        hipMemsetAsync(C, 0, (2 * SZ_NODE + SZ_SEG + SEG_ROWS) * sizeof(float), stream);
        // red init: min rows -> 0x7F7F7F7F (~3.4e38); max rows -> 0.0f
        hipMemsetAsync(Fp, 0x7F, (size_t)NU * 64 * sizeof(float), stream);                          // inter (min)
        hipMemsetAsync(Fp + (size_t)NU * 64, 0x00, (size_t)(NU + NI) * 64 * sizeof(float), stream); // ut + items (max)
        hipMemsetAsync(Fp + (size_t)(2 * NU + NI) * 64, 0x7F,
                       (size_t)(NENT - NI) * 64 * sizeof(float), stream);                           // tags (min)

        const float* eU = (layer == 0) ? user_emb : A;
        const float* eE = (layer == 0) ? item_emb : A + (size_t)NU * 64;
        const float* oU = (layer == 0) ? user_off : B;
        const float* oE = (layer == 0) ? item_off : B + (size_t)NU * 64;
        float *embUout, *embEout, *offUout, *offEout;
        if (layer == 0) {
            embUout = A; embEout = A + (size_t)NU * 64;
            offUout = B; offEout = B + (size_t)NU * 64;
        } else {
            embUout = out;
            offUout = out + (size_t)NU * 64;
            embEout = out + (size_t)2 * NU * 64;
            offEout = out + (size_t)2 * NU * 64 + (size_t)NENT * 64;
        }

        edge_pass<<<NEDGE / 4, 256, 0, stream>>>(eU, eE, oU, oE, head, tail,
                                                 cW1, cb1, cW2, cb2, oW1, ob1,
                                                 C, Dp, Ep, Fp, Gp);
        center_fin<<<(NN + 3) / 4, 256, 0, stream>>>(C, Dp, embUout, embEout);
        user_fin<<<(NU + 3) / 4, 256, 0, stream>>>(Ep, Fp, Gp, oW1, ob1, oW2, ob2, offUout);
        ent_fin<<<(NENT + 3) / 4, 256, 0, stream>>>(Ep, Fp, Gp, oW2, ob2, offEout);
    }
}

// Round 3
// 4244.648 us; speedup vs baseline: 2.4911x; 2.4911x over previous
//
#include <hip/hip_runtime.h>
#include <hip/hip_bf16.h>
#include <math.h>

#define NU 100000
#define NI 50000
#define NENT 80000
#define NN 180000
#define NEDGE 800000

__device__ __forceinline__ float bcastf(float v, int k) {
    return __uint_as_float(__builtin_amdgcn_readlane(__float_as_uint(v), k));
}
__device__ __forceinline__ float sigmoid_f(float x) {
    return 1.0f / (1.0f + __expf(-x));
}
__device__ __forceinline__ void afadd(float* p, float v) {
    unsafeAtomicAdd(p, v);
}

// ---------------- node pass: per-node matvecs (hoisted out of edge pass) ----------------
// EV[n] = exp(cW2 @ relu(cW1 @ x_n + cb1) + cb2)
// AO[n] = relu(oW1 @ relu(o_n) + ob1)
__global__ __launch_bounds__(256) void node_pass(
    const float* __restrict__ embU, const float* __restrict__ embE,
    const float* __restrict__ offU, const float* __restrict__ offE,
    const float* __restrict__ cW1, const float* __restrict__ cb1,
    const float* __restrict__ cW2, const float* __restrict__ cb2,
    const float* __restrict__ oW1, const float* __restrict__ ob1,
    float* __restrict__ EV, float* __restrict__ AO)
{
    __shared__ float W1t[4096];
    __shared__ float W2t[4096];
    __shared__ float O1t[4096];
    for (int i = threadIdx.x; i < 4096; i += 256) {
        int k = i >> 6, d = i & 63;
        W1t[i] = cW1[d * 64 + k];
        W2t[i] = cW2[d * 64 + k];
        O1t[i] = oW1[d * 64 + k];
    }
    __syncthreads();
    int lane = threadIdx.x & 63;
    int n = blockIdx.x * 4 + (threadIdx.x >> 6);
    if (n >= NN) return;
    float x = (n < NU) ? embU[(size_t)n * 64 + lane] : embE[(size_t)(n - NU) * 64 + lane];
    float o = fmaxf((n < NU) ? offU[(size_t)n * 64 + lane] : offE[(size_t)(n - NU) * 64 + lane], 0.0f);

    // a1 = relu(cW1 x + cb1), 4-way ILP
    float s0 = 0, s1 = 0, s2 = 0, s3 = 0;
    #pragma unroll
    for (int k = 0; k < 64; k += 4) {
        s0 = fmaf(bcastf(x, k + 0), W1t[(k + 0) * 64 + lane], s0);
        s1 = fmaf(bcastf(x, k + 1), W1t[(k + 1) * 64 + lane], s1);
        s2 = fmaf(bcastf(x, k + 2), W1t[(k + 2) * 64 + lane], s2);
        s3 = fmaf(bcastf(x, k + 3), W1t[(k + 3) * 64 + lane], s3);
    }
    float a1 = fmaxf((s0 + s1) + (s2 + s3) + cb1[lane], 0.0f);

    // lg = cW2 a1 + cb2
    s0 = 0; s1 = 0; s2 = 0; s3 = 0;
    #pragma unroll
    for (int k = 0; k < 64; k += 4) {
        s0 = fmaf(bcastf(a1, k + 0), W2t[(k + 0) * 64 + lane], s0);
        s1 = fmaf(bcastf(a1, k + 1), W2t[(k + 1) * 64 + lane], s1);
        s2 = fmaf(bcastf(a1, k + 2), W2t[(k + 2) * 64 + lane], s2);
        s3 = fmaf(bcastf(a1, k + 3), W2t[(k + 3) * 64 + lane], s3);
    }
    float lg = (s0 + s1) + (s2 + s3) + cb2[lane];
    EV[(size_t)n * 64 + lane] = __expf(lg);   // segment-max shift skipped: |lg| << 1

    // ao = relu(oW1 o + ob1)
    s0 = 0; s1 = 0; s2 = 0; s3 = 0;
    #pragma unroll
    for (int k = 0; k < 64; k += 4) {
        s0 = fmaf(bcastf(o, k + 0), O1t[(k + 0) * 64 + lane], s0);
        s1 = fmaf(bcastf(o, k + 1), O1t[(k + 1) * 64 + lane], s1);
        s2 = fmaf(bcastf(o, k + 2), O1t[(k + 2) * 64 + lane], s2);
        s3 = fmaf(bcastf(o, k + 3), O1t[(k + 3) * 64 + lane], s3);
    }
    AO[(size_t)n * 64 + lane] = fmaxf((s0 + s1) + (s2 + s3) + ob1[lane], 0.0f);
}

// ---------------- edge pass: pure gather + atomic scatter ----------------
__global__ __launch_bounds__(256) void edge_pass(
    const float* __restrict__ embU, const float* __restrict__ embE,
    const float* __restrict__ offU, const float* __restrict__ offE,
    const float* __restrict__ EV, const float* __restrict__ AO,
    const int* __restrict__ head, const int* __restrict__ tail,
    float* __restrict__ numacc, float* __restrict__ sacc,
    float* __restrict__ sumact, float* __restrict__ redv, float* __restrict__ cntv)
{
    int lane = threadIdx.x & 63;
    int eid = blockIdx.x * 4 + (threadIdx.x >> 6);
    if (eid >= NEDGE) return;
    int h = head[eid], t = tail[eid];
    float ev = EV[(size_t)t * 64 + lane];
    float x = (t < NU) ? embU[(size_t)t * 64 + lane] : embE[(size_t)(t - NU) * 64 + lane];
    afadd(&sacc[(size_t)h * 64 + lane], ev);
    afadd(&numacc[(size_t)h * 64 + lane], ev * x);

    int row; bool ismin;
    if (h < NU) {
        if (t < NU) return;                       // user->user edge: no offset mask
        else if (t < NU + NI) { row = h;      ismin = true;  }   // m_inter (min)
        else                  { row = NU + h; ismin = false; }   // m_ut (max)
    } else if (h < NU + NI) { row = 2 * NU + (h - NU); ismin = false; }  // m_item (max)
    else                    { row = 2 * NU + (h - NU); ismin = true;  }  // m_tag (min)

    float ao = AO[(size_t)t * 64 + lane];
    float o = fmaxf((t < NU) ? offU[(size_t)t * 64 + lane] : offE[(size_t)(t - NU) * 64 + lane], 0.0f);
    afadd(&sumact[(size_t)row * 64 + lane], ao);
    if (lane == 0) afadd(&cntv[row], 1.0f);
    unsigned int* rp = (unsigned int*)(&redv[(size_t)row * 64 + lane]);
    unsigned int ob = __float_as_uint(o);        // o >= 0: uint order == float order
    if (ismin) atomicMin(rp, ob);
    else       atomicMax(rp, ob);
}

// ---------------- center finalize: num/s + row L2 normalize ----------------
__global__ __launch_bounds__(256) void center_fin(
    const float* __restrict__ numacc, const float* __restrict__ sacc,
    float* __restrict__ outU, float* __restrict__ outE)
{
    int lane = threadIdx.x & 63;
    int n = blockIdx.x * 4 + (threadIdx.x >> 6);
    if (n >= NN) return;
    float s = sacc[(size_t)n * 64 + lane];
    float v = (s > 0.0f) ? numacc[(size_t)n * 64 + lane] / s : 0.0f;
    float sq = v * v;
    #pragma unroll
    for (int m = 32; m; m >>= 1) sq += __shfl_xor(sq, m, 64);
    v = v / fmaxf(sqrtf(sq), 1e-12f);
    if (n < NU) outU[(size_t)n * 64 + lane] = v;
    else        outE[(size_t)(n - NU) * 64 + lane] = v;
}

// ---------------- user offset finalize (fused 2-level offset net) ----------------
__global__ __launch_bounds__(256) void user_fin(
    const float* __restrict__ sumact, const float* __restrict__ redv, const float* __restrict__ cntv,
    const float* __restrict__ oW1, const float* __restrict__ ob1,
    const float* __restrict__ oW2, const float* __restrict__ ob2,
    float* __restrict__ outOffU)
{
    __shared__ float O1t[4096];
    __shared__ float O2t[4096];
    for (int i = threadIdx.x; i < 4096; i += 256) {
        int k = i >> 6, d = i & 63;
        O1t[i] = oW1[d * 64 + k];
        O2t[i] = oW2[d * 64 + k];
    }
    __syncthreads();
    int lane = threadIdx.x & 63;
    int u = blockIdx.x * 4 + (threadIdx.x >> 6);
    if (u >= NU) return;
    float b1 = ob1[lane], b2 = ob2[lane];

    float ci = fmaxf(cntv[u], 1.0f);
    float mi = sumact[(size_t)u * 64 + lane] / ci;
    float gi = b2;
    #pragma unroll
    for (int k = 0; k < 64; ++k) gi = fmaf(bcastf(mi, k), O2t[k * 64 + lane], gi);
    gi = sigmoid_f(gi);
    float ri = redv[(size_t)u * 64 + lane];
    if (ri > 1e37f) ri = 0.0f;
    float iu = ri * gi;

    float cu = fmaxf(cntv[NU + u], 1.0f);
    float mu = sumact[(size_t)(NU + u) * 64 + lane] / cu;
    float gu = b2;
    #pragma unroll
    for (int k = 0; k < 64; ++k) gu = fmaf(bcastf(mu, k), O2t[k * 64 + lane], gu);
    gu = sigmoid_f(gu);
    float ru = redv[(size_t)(NU + u) * 64 + lane];
    if (ru > 1e37f) ru = 0.0f;
    float uu = ru * gu;

    float a1 = b1, a2 = b1;
    #pragma unroll
    for (int k = 0; k < 64; ++k) a1 = fmaf(bcastf(iu, k), O1t[k * 64 + lane], a1);
    #pragma unroll
    for (int k = 0; k < 64; ++k) a2 = fmaf(bcastf(uu, k), O1t[k * 64 + lane], a2);
    float mn = (fmaxf(a1, 0.0f) + fmaxf(a2, 0.0f)) * 0.5f;
    float g = b2;
    #pragma unroll
    for (int k = 0; k < 64; ++k) g = fmaf(bcastf(mn, k), O2t[k * 64 + lane], g);
    g = sigmoid_f(g);
    outOffU[(size_t)u * 64 + lane] = fmaxf(fmaxf(iu, uu) * g, 0.0f);
}

// ---------------- ent (item+tag) offset finalize ----------------
__global__ __launch_bounds__(256) void ent_fin(
    const float* __restrict__ sumact, const float* __restrict__ redv, const float* __restrict__ cntv,
    const float* __restrict__ oW2, const float* __restrict__ ob2,
    float* __restrict__ outOffE)
{
    __shared__ float O2t[4096];
    for (int i = threadIdx.x; i < 4096; i += 256) {
        int k = i >> 6, d = i & 63;
        O2t[i] = oW2[d * 64 + k];
    }
    __syncthreads();
    int lane = threadIdx.x & 63;
    int idx = blockIdx.x * 4 + (threadIdx.x >> 6);
    if (idx >= NENT) return;
    size_t row = (size_t)(2 * NU) + idx;
    float c = fmaxf(cntv[row], 1.0f);
    float m = sumact[row * 64 + lane] / c;
    float g = ob2[lane];
    #pragma unroll
    for (int k = 0; k < 64; ++k) g = fmaf(bcastf(m, k), O2t[k * 64 + lane], g);
    g = sigmoid_f(g);
    float r = redv[row * 64 + lane];
    if (r > 1e37f) r = 0.0f;
    outOffE[(size_t)idx * 64 + lane] = r * g;
}

extern "C" void kernel_launch(void* const* d_in, const int* in_sizes, int n_in,
                              void* d_out, int out_size, void* d_ws, size_t ws_size,
                              hipStream_t stream)
{
    const float* user_emb = (const float*)d_in[0];
    const float* user_off = (const float*)d_in[1];
    const float* item_emb = (const float*)d_in[2];
    const float* item_off = (const float*)d_in[3];
    const float* cW1 = (const float*)d_in[4];
    const float* cb1 = (const float*)d_in[5];
    const float* cW2 = (const float*)d_in[6];
    const float* cb2 = (const float*)d_in[7];
    const float* oW1 = (const float*)d_in[8];
    const float* ob1 = (const float*)d_in[9];
    const float* oW2 = (const float*)d_in[10];
    const float* ob2 = (const float*)d_in[11];
    const int* head = (const int*)d_in[12];
    const int* tail = (const int*)d_in[13];
    float* out = (float*)d_out;

    float* ws = (float*)d_ws;
    const size_t SZ_NODE = (size_t)NN * 64;                 // 11,520,000 floats
    const size_t SEG_ROWS = (size_t)(2 * NU + NENT);        // 280,000 rows
    const size_t SZ_SEG = SEG_ROWS * 64;                    // 17,920,000 floats
    // Workspace high-water mark kept identical to the R1 layout (known to fit):
    float* A   = ws;                 // layer-1 output embs [NN,64]
    float* B   = A + SZ_NODE;        // layer-1 output offs [NN,64]
    float* C   = B + SZ_NODE;        // softmax numerator
    float* Dp  = C + SZ_NODE;        // softmax denominator
    float* Ep  = Dp + SZ_NODE;       // masked act sums [280000,64]
    float* Gp  = Ep + SZ_SEG;        // counts [280000]
    float* Fp  = Gp + SEG_ROWS;      // min/max reductions [280000,64]

    for (int layer = 0; layer < 2; ++layer) {
        hipMemsetAsync(C, 0, (2 * SZ_NODE + SZ_SEG + SEG_ROWS) * sizeof(float), stream);
        hipMemsetAsync(Fp, 0x7F, (size_t)NU * 64 * sizeof(float), stream);                          // inter (min)
        hipMemsetAsync(Fp + (size_t)NU * 64, 0x00, (size_t)(NU + NI) * 64 * sizeof(float), stream); // ut + items (max)
        hipMemsetAsync(Fp + (size_t)(2 * NU + NI) * 64, 0x7F,
                       (size_t)(NENT - NI) * 64 * sizeof(float), stream);                           // tags (min)

        const float* eU = (layer == 0) ? user_emb : A;
        const float* eE = (layer == 0) ? item_emb : A + (size_t)NU * 64;
        const float* oU = (layer == 0) ? user_off : B;
        const float* oE = (layer == 0) ? item_off : B + (size_t)NU * 64;
        float *embUout, *embEout, *offUout, *offEout;
        float *EVp, *AOp;
        if (layer == 0) {
            embUout = A; embEout = A + (size_t)NU * 64;
            offUout = B; offEout = B + (size_t)NU * 64;
            // EV/AO live in the not-yet-written layer-0 output buffers:
            // edge_pass consumes them before the finalizers write A/B.
            EVp = A; AOp = B;
        } else {
            embUout = out;
            offUout = out + (size_t)NU * 64;
            embEout = out + (size_t)2 * NU * 64;
            offEout = out + (size_t)2 * NU * 64 + (size_t)NENT * 64;
            // EV/AO live in d_out (2*SZ_NODE floats = exactly out_size):
            // dead before the finalizers overwrite every element of out.
            EVp = out; AOp = out + SZ_NODE;
        }

        node_pass<<<(NN + 3) / 4, 256, 0, stream>>>(eU, eE, oU, oE,
                                                    cW1, cb1, cW2, cb2, oW1, ob1,
                                                    EVp, AOp);
        edge_pass<<<NEDGE / 4, 256, 0, stream>>>(eU, eE, oU, oE, EVp, AOp, head, tail,
                                                 C, Dp, Ep, Fp, Gp);
        center_fin<<<(NN + 3) / 4, 256, 0, stream>>>(C, Dp, embUout, embEout);
        user_fin<<<(NU + 3) / 4, 256, 0, stream>>>(Ep, Fp, Gp, oW1, ob1, oW2, ob2, offUout);
        ent_fin<<<(NENT + 3) / 4, 256, 0, stream>>>(Ep, Fp, Gp, oW2, ob2, offEout);
    }
}

// Round 4
// 1539.320 us; speedup vs baseline: 6.8691x; 2.7575x over previous
//
#include <hip/hip_runtime.h>
#include <math.h>

#define NU 100000
#define NI 50000
#define NENT 80000
#define NN 180000
#define NEDGE 800000

__device__ __forceinline__ float rlf(float v, int k) {
    return __uint_as_float(__builtin_amdgcn_readlane(__float_as_uint(v), k));
}
__device__ __forceinline__ float sigmoid_f(float x) { return 1.0f / (1.0f + __expf(-x)); }

// batched matvec: acc[i][lane] += sum_k in[i][k] * Wt[k*64+lane]
// one LDS read serves 16 FMAs; broadcast via v_readlane (dynamic k in SGPR).
__device__ __forceinline__ void matvec16(const float* __restrict__ Wt,
                                         const float (&in)[16], float (&acc)[16], int lane) {
    #pragma unroll 8
    for (int k = 0; k < 64; ++k) {
        float w = Wt[k * 64 + lane];
        #pragma unroll
        for (int i = 0; i < 16; ++i) acc[i] = fmaf(rlf(in[i], k), w, acc[i]);
    }
}

// ---------------- node pass: per-node matvecs, 16 nodes/wave ----------------
// EV[n]=exp(cW2@relu(cW1@x+cb1)+cb2); P[n]=EV[n]*x[n]; AO[n]=relu(oW1@relu(o)+ob1)
__global__ __launch_bounds__(256) void node_pass(
    const float* __restrict__ embU, const float* __restrict__ embE,
    const float* __restrict__ offU, const float* __restrict__ offE,
    const float* __restrict__ cW1, const float* __restrict__ cb1,
    const float* __restrict__ cW2, const float* __restrict__ cb2,
    const float* __restrict__ oW1, const float* __restrict__ ob1,
    float* __restrict__ EV, float* __restrict__ P, float* __restrict__ AO)
{
    __shared__ float W1t[4096], W2t[4096], O1t[4096];
    for (int i = threadIdx.x; i < 4096; i += 256) {
        int k = i >> 6, d = i & 63;
        W1t[i] = cW1[d * 64 + k]; W2t[i] = cW2[d * 64 + k]; O1t[i] = oW1[d * 64 + k];
    }
    __syncthreads();
    int lane = threadIdx.x & 63;
    int n0 = (blockIdx.x * 4 + (threadIdx.x >> 6)) * 16;
    if (n0 >= NN) return;
    // NU % 16 == 0 -> a 16-node group never straddles the user/ent boundary
    const float* eb; const float* ob;
    if (n0 < NU) { eb = embU + (size_t)n0 * 64; ob = offU + (size_t)n0 * 64; }
    else         { eb = embE + (size_t)(n0 - NU) * 64; ob = offE + (size_t)(n0 - NU) * 64; }
    int nv = NN - n0; if (nv > 16) nv = 16;

    float x[16], acc[16], lg[16];
    float b1 = cb1[lane], b2 = cb2[lane];
    #pragma unroll
    for (int i = 0; i < 16; ++i) { x[i] = (i < nv) ? eb[(size_t)i * 64 + lane] : 0.0f; acc[i] = b1; }
    matvec16(W1t, x, acc, lane);
    #pragma unroll
    for (int i = 0; i < 16; ++i) { acc[i] = fmaxf(acc[i], 0.0f); lg[i] = b2; }
    matvec16(W2t, acc, lg, lane);
    #pragma unroll
    for (int i = 0; i < 16; ++i) {
        float ev = __expf(lg[i]);   // segment-max shift skipped: |lg| << 1
        if (i < nv) { EV[(size_t)(n0 + i) * 64 + lane] = ev; P[(size_t)(n0 + i) * 64 + lane] = ev * x[i]; }
    }
    float b1o = ob1[lane];
    #pragma unroll
    for (int i = 0; i < 16; ++i) { x[i] = (i < nv) ? fmaxf(ob[(size_t)i * 64 + lane], 0.0f) : 0.0f; acc[i] = b1o; }
    matvec16(O1t, x, acc, lane);
    #pragma unroll
    for (int i = 0; i < 16; ++i) if (i < nv) AO[(size_t)(n0 + i) * 64 + lane] = fmaxf(acc[i], 0.0f);
}

// ---------------- CSR build ----------------
__global__ __launch_bounds__(256) void hist_k(const int* __restrict__ head, int* __restrict__ counts) {
    int e = blockIdx.x * 256 + threadIdx.x;
    if (e < NEDGE) atomicAdd(&counts[head[e]], 1);
}

__global__ __launch_bounds__(1024) void scan_k(const int* __restrict__ counts,
                                               int* __restrict__ offsets, int* __restrict__ cursor) {
    __shared__ int wsum[16];
    __shared__ int carry;
    int tid = threadIdx.x, lane = tid & 63, wid = tid >> 6;
    if (tid == 0) carry = 0;
    __syncthreads();
    const int CH = (NN + 1023) / 1024;
    for (int c = 0; c < CH; ++c) {
        int i = c * 1024 + tid;
        int v = (i < NN) ? counts[i] : 0;
        int s = v;
        #pragma unroll
        for (int d = 1; d < 64; d <<= 1) { int u = __shfl_up(s, d, 64); if (lane >= d) s += u; }
        if (lane == 63) wsum[wid] = s;
        __syncthreads();
        if (wid == 0 && lane < 16) {
            int wsv = wsum[lane];
            #pragma unroll
            for (int d = 1; d < 16; d <<= 1) { int u = __shfl_up(wsv, d, 64); if (lane >= d) wsv += u; }
            wsum[lane] = wsv;
        }
        __syncthreads();
        int base = carry + (wid ? wsum[wid - 1] : 0);
        int total = wsum[15];
        if (i < NN) { int ex = base + s - v; offsets[i] = ex; cursor[i] = ex; }
        __syncthreads();
        if (tid == 0) carry += total;
        __syncthreads();
    }
    if (tid == 0) offsets[NN] = NEDGE;
}

__global__ __launch_bounds__(256) void scatter_k(const int* __restrict__ head, const int* __restrict__ tail,
                                                 int* __restrict__ cursor, int* __restrict__ sorted_t) {
    int e = blockIdx.x * 256 + threadIdx.x;
    if (e < NEDGE) { int pos = atomicAdd(&cursor[head[e]], 1); sorted_t[pos] = tail[e]; }
}

// ---------------- segment pass: one wave per head node, zero atomics ----------------
__global__ __launch_bounds__(1024) void seg_pass(
    const float* __restrict__ EV, const float* __restrict__ P, const float* __restrict__ AO,
    const float* __restrict__ offU, const float* __restrict__ offE,
    const int* __restrict__ offsets, const int* __restrict__ sorted_t,
    const float* __restrict__ oW2, const float* __restrict__ ob2,
    float* __restrict__ embOutU, float* __restrict__ embOutE,
    float* __restrict__ entOff,
    float* __restrict__ meanI, float* __restrict__ redI,
    float* __restrict__ meanU, float* __restrict__ redU)
{
    __shared__ float O2t[4096];
    for (int i = threadIdx.x; i < 4096; i += 1024) { int k = i >> 6, d = i & 63; O2t[i] = oW2[d * 64 + k]; }
    __syncthreads();
    int lane = threadIdx.x & 63;
    int h = blockIdx.x * 16 + (threadIdx.x >> 6);
    if (h >= NN) return;
    int beg = offsets[h], end = offsets[h + 1];
    bool isUser = (h < NU);
    bool entMin = (h >= NU + NI);
    float num = 0.f, den = 0.f;
    float s_i = 0.f, s_u = 0.f, m_u = 0.f;
    float m_i = isUser ? INFINITY : (entMin ? INFINITY : 0.0f);  // ents reuse s_i/m_i/c_i
    int c_i = 0, c_u = 0;
    for (int e = beg; e < end; ++e) {
        int t = sorted_t[e];
        size_t r = (size_t)t * 64 + lane;
        den += EV[r]; num += P[r];
        if (isUser) {
            if (t >= NU) {
                float ao = AO[r];
                float o = fmaxf(offE[(size_t)(t - NU) * 64 + lane], 0.0f);
                if (t < NU + NI) { s_i += ao; m_i = fminf(m_i, o); c_i++; }
                else             { s_u += ao; m_u = fmaxf(m_u, o); c_u++; }
            }
        } else {
            float ao = AO[r];
            float o = fmaxf((t < NU) ? offU[r] : offE[(size_t)(t - NU) * 64 + lane], 0.0f);
            s_i += ao; c_i++;
            m_i = entMin ? fminf(m_i, o) : fmaxf(m_i, o);
        }
    }
    // center: softmax-weighted mean + row L2 normalize
    float v = (den > 0.f) ? num / den : 0.f;
    float sq = v * v;
    #pragma unroll
    for (int m = 32; m; m >>= 1) sq += __shfl_xor(sq, m, 64);
    v = v / fmaxf(sqrtf(sq), 1e-12f);
    if (isUser) embOutU[(size_t)h * 64 + lane] = v;
    else        embOutE[(size_t)(h - NU) * 64 + lane] = v;

    if (isUser) {
        size_t r = (size_t)h * 64 + lane;
        meanI[r] = s_i / fmaxf((float)c_i, 1.f);
        redI[r]  = (m_i > 1e37f) ? 0.f : m_i;
        meanU[r] = s_u / fmaxf((float)c_u, 1.f);
        redU[r]  = m_u;
    } else {
        float mean = s_i / fmaxf((float)c_i, 1.f);
        float g = ob2[lane];
        #pragma unroll 8
        for (int k = 0; k < 64; ++k) g = fmaf(rlf(mean, k), O2t[k * 64 + lane], g);
        g = sigmoid_f(g);
        float rdv = (m_i > 1e37f) ? 0.f : m_i;
        entOff[(size_t)(h - NU) * 64 + lane] = rdv * g;
    }
}

// ---------------- user offset finalize, 16 users/wave ----------------
__global__ __launch_bounds__(256) void user_fin2(
    const float* __restrict__ meanI, const float* __restrict__ redI,
    const float* __restrict__ meanU, const float* __restrict__ redU,
    const float* __restrict__ oW1, const float* __restrict__ ob1,
    const float* __restrict__ oW2, const float* __restrict__ ob2,
    float* __restrict__ outOffU)
{
    __shared__ float O1t[4096], O2t[4096];
    for (int i = threadIdx.x; i < 4096; i += 256) {
        int k = i >> 6, d = i & 63;
        O1t[i] = oW1[d * 64 + k]; O2t[i] = oW2[d * 64 + k];
    }
    __syncthreads();
    int lane = threadIdx.x & 63;
    int u0 = (blockIdx.x * 4 + (threadIdx.x >> 6)) * 16;
    if (u0 >= NU) return;
    int nv = NU - u0; if (nv > 16) nv = 16;
    float b1 = ob1[lane], b2 = ob2[lane];
    float in[16], acc[16], iu[16], uu[16];
    #pragma unroll
    for (int i = 0; i < 16; ++i) { in[i] = (i < nv) ? meanI[(size_t)(u0 + i) * 64 + lane] : 0.f; acc[i] = b2; }
    matvec16(O2t, in, acc, lane);
    #pragma unroll
    for (int i = 0; i < 16; ++i) { float r = (i < nv) ? redI[(size_t)(u0 + i) * 64 + lane] : 0.f; iu[i] = r * sigmoid_f(acc[i]); }
    #pragma unroll
    for (int i = 0; i < 16; ++i) { in[i] = (i < nv) ? meanU[(size_t)(u0 + i) * 64 + lane] : 0.f; acc[i] = b2; }
    matvec16(O2t, in, acc, lane);
    #pragma unroll
    for (int i = 0; i < 16; ++i) { float r = (i < nv) ? redU[(size_t)(u0 + i) * 64 + lane] : 0.f; uu[i] = r * sigmoid_f(acc[i]); }
    // a1 = relu(O1@iu+b1); a2 = relu(O1@uu+b1); mn = (a1+a2)/2
    #pragma unroll
    for (int i = 0; i < 16; ++i) acc[i] = b1;
    matvec16(O1t, iu, acc, lane);
    #pragma unroll
    for (int i = 0; i < 16; ++i) in[i] = fmaxf(acc[i], 0.f);
    #pragma unroll
    for (int i = 0; i < 16; ++i) acc[i] = b1;
    matvec16(O1t, uu, acc, lane);
    #pragma unroll
    for (int i = 0; i < 16; ++i) in[i] = 0.5f * (in[i] + fmaxf(acc[i], 0.f));
    #pragma unroll
    for (int i = 0; i < 16; ++i) acc[i] = b2;
    matvec16(O2t, in, acc, lane);
    #pragma unroll
    for (int i = 0; i < 16; ++i) if (i < nv)
        outOffU[(size_t)(u0 + i) * 64 + lane] = fmaxf(fmaxf(iu[i], uu[i]) * sigmoid_f(acc[i]), 0.f);
}

extern "C" void kernel_launch(void* const* d_in, const int* in_sizes, int n_in,
                              void* d_out, int out_size, void* d_ws, size_t ws_size,
                              hipStream_t stream)
{
    const float* user_emb = (const float*)d_in[0];
    const float* user_off = (const float*)d_in[1];
    const float* item_emb = (const float*)d_in[2];
    const float* item_off = (const float*)d_in[3];
    const float* cW1 = (const float*)d_in[4];
    const float* cb1 = (const float*)d_in[5];
    const float* cW2 = (const float*)d_in[6];
    const float* cb2 = (const float*)d_in[7];
    const float* oW1 = (const float*)d_in[8];
    const float* ob1 = (const float*)d_in[9];
    const float* oW2 = (const float*)d_in[10];
    const float* ob2 = (const float*)d_in[11];
    const int* head = (const int*)d_in[12];
    const int* tail = (const int*)d_in[13];
    float* out = (float*)d_out;

    float* ws = (float*)d_ws;
    const size_t SZ = (size_t)NN * 64;
    // budget: 5*11.52M + 3*6.4M floats + 1.34M ints = 78.1M float-equiv < 82.2M (R1-proven fit)
    float* A    = ws;                          // layer-0 emb out [NN,64]
    float* B    = A + SZ;                      // layer-0 off out [NN,64]
    float* EVp  = B + SZ;
    float* Pp   = EVp + SZ;
    float* AOp  = Pp + SZ;
    float* redI_  = AOp + SZ;                  // [NU,64]
    float* meanU_ = redI_ + (size_t)NU * 64;
    float* redU_  = meanU_ + (size_t)NU * 64;
    int* counts   = (int*)(redU_ + (size_t)NU * 64);
    int* offsets  = counts + NN;               // NN+1
    int* cursor   = offsets + NN + 1;
    int* sorted_t = cursor + NN;               // NEDGE

    // CSR build (per call; layer-independent)
    hipMemsetAsync(counts, 0, NN * sizeof(int), stream);
    hist_k<<<(NEDGE + 255) / 256, 256, 0, stream>>>(head, counts);
    scan_k<<<1, 1024, 0, stream>>>(counts, offsets, cursor);
    scatter_k<<<(NEDGE + 255) / 256, 256, 0, stream>>>(head, tail, cursor, sorted_t);

    for (int layer = 0; layer < 2; ++layer) {
        const float *eU, *eE, *oU, *oE;
        float *embOutU, *embOutE, *entOff, *meanI_, *uOffOut;
        if (layer == 0) {
            eU = user_emb; eE = item_emb; oU = user_off; oE = item_off;
            embOutU = A;               embOutE = A + (size_t)NU * 64;
            entOff  = B + (size_t)NU * 64;
            meanI_  = B;               // rows [0,NU) of B; user_fin2 reads row u then writes row u
            uOffOut = B;
        } else {
            eU = A; eE = A + (size_t)NU * 64; oU = B; oE = B + (size_t)NU * 64;
            embOutU = out;             embOutE = out + (size_t)2 * NU * 64;
            entOff  = out + ((size_t)2 * NU + NENT) * 64;
            meanI_  = out + (size_t)NU * 64;   // offU output region as scratch (row-matched)
            uOffOut = out + (size_t)NU * 64;
        }
        node_pass<<<(NN + 63) / 64, 256, 0, stream>>>(eU, eE, oU, oE,
                                                      cW1, cb1, cW2, cb2, oW1, ob1,
                                                      EVp, Pp, AOp);
        seg_pass<<<(NN + 15) / 16, 1024, 0, stream>>>(EVp, Pp, AOp, oU, oE, offsets, sorted_t,
                                                      oW2, ob2, embOutU, embOutE, entOff,
                                                      meanI_, redI_, meanU_, redU_);
        user_fin2<<<(NU + 63) / 64, 256, 0, stream>>>(meanI_, redI_, meanU_, redU_,
                                                      oW1, ob1, oW2, ob2, uOffOut);
    }
}

// Round 5
// 1232.963 us; speedup vs baseline: 8.5759x; 1.2485x over previous
//
#include <hip/hip_runtime.h>
#include <hip/hip_fp16.h>
#include <math.h>

#define NU 100000
#define NI 50000
#define NENT 80000
#define NN 180000
#define NEDGE 800000
#define SCAN_NB ((NN + 1023) / 1024)   // 176

__device__ __forceinline__ float rlf(float v, int k) {
    return __uint_as_float(__builtin_amdgcn_readlane(__float_as_uint(v), k));
}
__device__ __forceinline__ float sigmoid_f(float x) { return 1.0f / (1.0f + __expf(-x)); }
__device__ __forceinline__ unsigned pack2(float a, float b) {
    __half2 h = __floats2half2_rn(a, b);
    return *(unsigned*)&h;
}
__device__ __forceinline__ float2 unpack2(unsigned u) {
    __half2 h = *(__half2*)&u;
    return __half22float2(h);
}

// batched matvec: acc[i][lane] += sum_k in[i][k] * Wt[k*64+lane]
__device__ __forceinline__ void matvec16(const float* __restrict__ Wt,
                                         const float (&in)[16], float (&acc)[16], int lane) {
    #pragma unroll 8
    for (int k = 0; k < 64; ++k) {
        float w = Wt[k * 64 + lane];
        #pragma unroll
        for (int i = 0; i < 16; ++i) acc[i] = fmaf(rlf(in[i], k), w, acc[i]);
    }
}

// ---------------- node pass: 16 nodes/wave; writes packed fp16 quad {EV,P,AO,OFF} ----------------
__global__ __launch_bounds__(256) void node_pass(
    const float* __restrict__ embU, const float* __restrict__ embE,
    const float* __restrict__ offU, const float* __restrict__ offE,
    const float* __restrict__ cW1, const float* __restrict__ cb1,
    const float* __restrict__ cW2, const float* __restrict__ cb2,
    const float* __restrict__ oW1, const float* __restrict__ ob1,
    uint2* __restrict__ packed)
{
    __shared__ float W1t[4096], W2t[4096], O1t[4096];
    for (int i = threadIdx.x; i < 4096; i += 256) {
        int k = i >> 6, d = i & 63;
        W1t[i] = cW1[d * 64 + k]; W2t[i] = cW2[d * 64 + k]; O1t[i] = oW1[d * 64 + k];
    }
    __syncthreads();
    int lane = threadIdx.x & 63;
    int n0 = (blockIdx.x * 4 + (threadIdx.x >> 6)) * 16;
    if (n0 >= NN) return;
    // NU and NN are multiples of 16 -> groups never straddle the user/ent boundary
    const float* eb; const float* ob;
    if (n0 < NU) { eb = embU + (size_t)n0 * 64; ob = offU + (size_t)n0 * 64; }
    else         { eb = embE + (size_t)(n0 - NU) * 64; ob = offE + (size_t)(n0 - NU) * 64; }

    float x[16], acc[16], lg[16];
    unsigned lo[16];
    float b1 = cb1[lane], b2 = cb2[lane];
    #pragma unroll
    for (int i = 0; i < 16; ++i) { x[i] = eb[(size_t)i * 64 + lane]; acc[i] = b1; }
    matvec16(W1t, x, acc, lane);
    #pragma unroll
    for (int i = 0; i < 16; ++i) { acc[i] = fmaxf(acc[i], 0.0f); lg[i] = b2; }
    matvec16(W2t, acc, lg, lane);
    #pragma unroll
    for (int i = 0; i < 16; ++i) {
        float ev = __expf(lg[i]);          // segment-max shift skipped: |lg| << 1
        lo[i] = pack2(ev, ev * x[i]);      // {EV, P}
    }
    float b1o = ob1[lane];
    #pragma unroll
    for (int i = 0; i < 16; ++i) { x[i] = fmaxf(ob[(size_t)i * 64 + lane], 0.0f); acc[i] = b1o; }
    matvec16(O1t, x, acc, lane);
    #pragma unroll
    for (int i = 0; i < 16; ++i)
        packed[(size_t)(n0 + i) * 64 + lane] = make_uint2(lo[i], pack2(fmaxf(acc[i], 0.0f), x[i])); // {AO, OFF}
}

// ---------------- CSR build ----------------
__global__ __launch_bounds__(256) void hist_k(const int* __restrict__ head, int* __restrict__ counts) {
    int e = blockIdx.x * 256 + threadIdx.x;
    if (e < NEDGE) atomicAdd(&counts[head[e]], 1);
}

// 3-phase parallel exclusive scan over counts[NN]
__global__ __launch_bounds__(1024) void scan_local(const int* __restrict__ counts,
                                                   int* __restrict__ excl, int* __restrict__ partials) {
    __shared__ int wsum[16];
    int tid = threadIdx.x, lane = tid & 63, wid = tid >> 6;
    int i = blockIdx.x * 1024 + tid;
    int v = (i < NN) ? counts[i] : 0;
    int s = v;
    #pragma unroll
    for (int d = 1; d < 64; d <<= 1) { int u = __shfl_up(s, d, 64); if (lane >= d) s += u; }
    if (lane == 63) wsum[wid] = s;
    __syncthreads();
    if (wid == 0 && lane < 16) {
        int w = wsum[lane];
        #pragma unroll
        for (int d = 1; d < 16; d <<= 1) { int u = __shfl_up(w, d, 64); if (lane >= d) w += u; }
        wsum[lane] = w;
    }
    __syncthreads();
    int base = wid ? wsum[wid - 1] : 0;
    if (i < NN) excl[i] = base + s - v;
    if (tid == 1023) partials[blockIdx.x] = wsum[15];
}

__global__ __launch_bounds__(256) void scan_carry(const int* __restrict__ partials, int* __restrict__ carries) {
    __shared__ int ws[4];
    int tid = threadIdx.x, lane = tid & 63, wid = tid >> 6;
    int v = (tid < SCAN_NB) ? partials[tid] : 0;
    int s = v;
    #pragma unroll
    for (int d = 1; d < 64; d <<= 1) { int u = __shfl_up(s, d, 64); if (lane >= d) s += u; }
    if (lane == 63) ws[wid] = s;
    __syncthreads();
    int add = 0;
    for (int w = 0; w < wid; ++w) add += ws[w];
    if (tid < SCAN_NB) carries[tid] = add + s - v;
}

__global__ __launch_bounds__(1024) void scan_add(int* __restrict__ excl, const int* __restrict__ carries,
                                                 int* __restrict__ cursor) {
    int i = blockIdx.x * 1024 + threadIdx.x;
    if (i < NN) { int o = excl[i] + carries[blockIdx.x]; excl[i] = o; cursor[i] = o; }
    if (i == 0) excl[NN] = NEDGE;
}

__global__ __launch_bounds__(256) void scatter_k(const int* __restrict__ head, const int* __restrict__ tail,
                                                 int* __restrict__ cursor, int* __restrict__ sorted_t) {
    int e = blockIdx.x * 256 + threadIdx.x;
    if (e < NEDGE) { int pos = atomicAdd(&cursor[head[e]], 1); sorted_t[pos] = tail[e]; }
}

// ---------------- segment pass: one wave per head node, one 8B gather per edge ----------------
__global__ __launch_bounds__(1024) void seg_pass(
    const uint2* __restrict__ packed,
    const int* __restrict__ offsets, const int* __restrict__ sorted_t,
    const float* __restrict__ oW2, const float* __restrict__ ob2,
    float* __restrict__ embOutU, float* __restrict__ embOutE,
    float* __restrict__ entOff,
    float* __restrict__ meanI, float* __restrict__ redI,
    float* __restrict__ meanU, float* __restrict__ redU)
{
    __shared__ float O2t[4096];
    for (int i = threadIdx.x; i < 4096; i += 1024) { int k = i >> 6, d = i & 63; O2t[i] = oW2[d * 64 + k]; }
    __syncthreads();
    int lane = threadIdx.x & 63;
    int h = blockIdx.x * 16 + (threadIdx.x >> 6);
    if (h >= NN) return;
    int beg = offsets[h], end = offsets[h + 1];
    bool isUser = (h < NU);
    bool entMin = (h >= NU + NI);
    float num = 0.f, den = 0.f;
    float s_i = 0.f, s_u = 0.f, m_u = 0.f;
    float m_i = (isUser || entMin) ? INFINITY : 0.0f;   // ents reuse s_i/m_i/c_i
    int c_i = 0, c_u = 0;

    int t = 0; uint2 q = make_uint2(0u, 0u);
    if (beg < end) { t = sorted_t[beg]; q = packed[(size_t)t * 64 + lane]; }
    for (int e = beg; e < end; ++e) {
        int tc = t; uint2 qc = q;
        if (e + 1 < end) {                      // 1-ahead prefetch
            t = sorted_t[e + 1];
            q = packed[(size_t)t * 64 + lane];
        }
        float2 evp = unpack2(qc.x);             // {EV, P}
        den += evp.x; num += evp.y;
        float2 ao_o = unpack2(qc.y);            // {AO, OFF}
        if (isUser) {
            if (tc >= NU) {
                if (tc < NU + NI) { s_i += ao_o.x; m_i = fminf(m_i, ao_o.y); c_i++; }
                else              { s_u += ao_o.x; m_u = fmaxf(m_u, ao_o.y); c_u++; }
            }
        } else {
            s_i += ao_o.x; c_i++;
            m_i = entMin ? fminf(m_i, ao_o.y) : fmaxf(m_i, ao_o.y);
        }
    }
    // center: softmax-weighted mean + row L2 normalize
    float v = (den > 0.f) ? num / den : 0.f;
    float sq = v * v;
    #pragma unroll
    for (int m = 32; m; m >>= 1) sq += __shfl_xor(sq, m, 64);
    v = v / fmaxf(sqrtf(sq), 1e-12f);
    if (isUser) embOutU[(size_t)h * 64 + lane] = v;
    else        embOutE[(size_t)(h - NU) * 64 + lane] = v;

    if (isUser) {
        size_t r = (size_t)h * 64 + lane;
        meanI[r] = s_i / fmaxf((float)c_i, 1.f);
        redI[r]  = (m_i > 1e37f) ? 0.f : m_i;
        meanU[r] = s_u / fmaxf((float)c_u, 1.f);
        redU[r]  = m_u;
    } else {
        float mean = s_i / fmaxf((float)c_i, 1.f);
        float g = ob2[lane];
        #pragma unroll 8
        for (int k = 0; k < 64; ++k) g = fmaf(rlf(mean, k), O2t[k * 64 + lane], g);
        g = sigmoid_f(g);
        float rdv = (m_i > 1e37f) ? 0.f : m_i;
        entOff[(size_t)(h - NU) * 64 + lane] = rdv * g;
    }
}

// ---------------- user offset finalize, 16 users/wave ----------------
__global__ __launch_bounds__(256) void user_fin2(
    const float* __restrict__ meanI, const float* __restrict__ redI,
    const float* __restrict__ meanU, const float* __restrict__ redU,
    const float* __restrict__ oW1, const float* __restrict__ ob1,
    const float* __restrict__ oW2, const float* __restrict__ ob2,
    float* __restrict__ outOffU)
{
    __shared__ float O1t[4096], O2t[4096];
    for (int i = threadIdx.x; i < 4096; i += 256) {
        int k = i >> 6, d = i & 63;
        O1t[i] = oW1[d * 64 + k]; O2t[i] = oW2[d * 64 + k];
    }
    __syncthreads();
    int lane = threadIdx.x & 63;
    int u0 = (blockIdx.x * 4 + (threadIdx.x >> 6)) * 16;
    if (u0 >= NU) return;   // NU % 16 == 0: full groups only
    float b1 = ob1[lane], b2 = ob2[lane];
    float in[16], acc[16], iu[16], uu[16];
    #pragma unroll
    for (int i = 0; i < 16; ++i) { in[i] = meanI[(size_t)(u0 + i) * 64 + lane]; acc[i] = b2; }
    matvec16(O2t, in, acc, lane);
    #pragma unroll
    for (int i = 0; i < 16; ++i) iu[i] = redI[(size_t)(u0 + i) * 64 + lane] * sigmoid_f(acc[i]);
    #pragma unroll
    for (int i = 0; i < 16; ++i) { in[i] = meanU[(size_t)(u0 + i) * 64 + lane]; acc[i] = b2; }
    matvec16(O2t, in, acc, lane);
    #pragma unroll
    for (int i = 0; i < 16; ++i) uu[i] = redU[(size_t)(u0 + i) * 64 + lane] * sigmoid_f(acc[i]);
    #pragma unroll
    for (int i = 0; i < 16; ++i) acc[i] = b1;
    matvec16(O1t, iu, acc, lane);
    #pragma unroll
    for (int i = 0; i < 16; ++i) in[i] = fmaxf(acc[i], 0.f);
    #pragma unroll
    for (int i = 0; i < 16; ++i) acc[i] = b1;
    matvec16(O1t, uu, acc, lane);
    #pragma unroll
    for (int i = 0; i < 16; ++i) in[i] = 0.5f * (in[i] + fmaxf(acc[i], 0.f));
    #pragma unroll
    for (int i = 0; i < 16; ++i) acc[i] = b2;
    matvec16(O2t, in, acc, lane);
    #pragma unroll
    for (int i = 0; i < 16; ++i)
        outOffU[(size_t)(u0 + i) * 64 + lane] = fmaxf(fmaxf(iu[i], uu[i]) * sigmoid_f(acc[i]), 0.f);
}

extern "C" void kernel_launch(void* const* d_in, const int* in_sizes, int n_in,
                              void* d_out, int out_size, void* d_ws, size_t ws_size,
                              hipStream_t stream)
{
    const float* user_emb = (const float*)d_in[0];
    const float* user_off = (const float*)d_in[1];
    const float* item_emb = (const float*)d_in[2];
    const float* item_off = (const float*)d_in[3];
    const float* cW1 = (const float*)d_in[4];
    const float* cb1 = (const float*)d_in[5];
    const float* cW2 = (const float*)d_in[6];
    const float* cb2 = (const float*)d_in[7];
    const float* oW1 = (const float*)d_in[8];
    const float* ob1 = (const float*)d_in[9];
    const float* oW2 = (const float*)d_in[10];
    const float* ob2 = (const float*)d_in[11];
    const int* head = (const int*)d_in[12];
    const int* tail = (const int*)d_in[13];
    float* out = (float*)d_out;

    float* ws = (float*)d_ws;
    const size_t SZ = (size_t)NN * 64;
    // budget: 2*11.52M + 23.04M + 3*6.4M floats + ~1.34M ints ≈ 66.6M float-equiv < 78.1M (R4-proven)
    float* A      = ws;                        // layer-0 emb out [NN,64]
    float* B      = A + SZ;                    // layer-0 off out [NN,64]
    uint2* packed = (uint2*)(B + SZ);          // [NN,64] fp16 quads (2 float-equiv each)
    float* redI_  = (float*)(packed + SZ);     // [NU,64]
    float* meanU_ = redI_ + (size_t)NU * 64;
    float* redU_  = meanU_ + (size_t)NU * 64;
    int* counts   = (int*)(redU_ + (size_t)NU * 64);
    int* offsets  = counts + NN;               // NN+1 (doubles as excl-scan buffer)
    int* cursor   = offsets + NN + 1;
    int* sorted_t = cursor + NN;               // NEDGE
    int* partials = sorted_t + NEDGE;          // SCAN_NB
    int* carries  = partials + SCAN_NB;        // SCAN_NB

    // CSR build (per call; layer-independent)
    hipMemsetAsync(counts, 0, NN * sizeof(int), stream);
    hist_k<<<(NEDGE + 255) / 256, 256, 0, stream>>>(head, counts);
    scan_local<<<SCAN_NB, 1024, 0, stream>>>(counts, offsets, partials);
    scan_carry<<<1, 256, 0, stream>>>(partials, carries);
    scan_add<<<SCAN_NB, 1024, 0, stream>>>(offsets, carries, cursor);
    scatter_k<<<(NEDGE + 255) / 256, 256, 0, stream>>>(head, tail, cursor, sorted_t);

    for (int layer = 0; layer < 2; ++layer) {
        const float *eU, *eE, *oU, *oE;
        float *embOutU, *embOutE, *entOff, *meanI_, *uOffOut;
        if (layer == 0) {
            eU = user_emb; eE = item_emb; oU = user_off; oE = item_off;
            embOutU = A;               embOutE = A + (size_t)NU * 64;
            entOff  = B + (size_t)NU * 64;
            meanI_  = B;               // rows [0,NU) of B; user_fin2 reads row u then writes row u
            uOffOut = B;
        } else {
            eU = A; eE = A + (size_t)NU * 64; oU = B; oE = B + (size_t)NU * 64;
            embOutU = out;             embOutE = out + (size_t)2 * NU * 64;
            entOff  = out + ((size_t)2 * NU + NENT) * 64;
            meanI_  = out + (size_t)NU * 64;   // offU output region as scratch (row-matched)
            uOffOut = out + (size_t)NU * 64;
        }
        node_pass<<<(NN + 63) / 64, 256, 0, stream>>>(eU, eE, oU, oE,
                                                      cW1, cb1, cW2, cb2, oW1, ob1, packed);
        seg_pass<<<(NN + 15) / 16, 1024, 0, stream>>>(packed, offsets, sorted_t,
                                                      oW2, ob2, embOutU, embOutE, entOff,
                                                      meanI_, redI_, meanU_, redU_);
        user_fin2<<<(NU + 63) / 64, 256, 0, stream>>>(meanI_, redI_, meanU_, redU_,
                                                      oW1, ob1, oW2, ob2, uOffOut);
    }
}

// Round 6
// 761.379 us; speedup vs baseline: 13.8876x; 1.6194x over previous
//
#include <hip/hip_runtime.h>
#include <hip/hip_fp16.h>
#include <math.h>

#define NU 100000
#define NI 50000
#define NENT 80000
#define NN 180000
#define NEDGE 800000
#define SCAN_NB ((NN + 1023) / 1024)   // 176

typedef _Float16 f16x4 __attribute__((ext_vector_type(4)));
typedef float f32x4 __attribute__((ext_vector_type(4)));

__device__ __forceinline__ float rlf(float v, int k) {
    return __uint_as_float(__builtin_amdgcn_readlane(__float_as_uint(v), k));
}
__device__ __forceinline__ float sigmoid_f(float x) { return 1.0f / (1.0f + __expf(-x)); }
__device__ __forceinline__ unsigned pack2(float a, float b) {
    __half2 h = __floats2half2_rn(a, b);
    return *(unsigned*)&h;
}
__device__ __forceinline__ float2 unpack2(unsigned u) {
    __half2 h = *(__half2*)&u;
    return __half22float2(h);
}
__device__ __forceinline__ f16x4 frag4(const float* __restrict__ p) {
    float4 v = *(const float4*)p;
    f16x4 r; r[0] = (_Float16)v.x; r[1] = (_Float16)v.y; r[2] = (_Float16)v.z; r[3] = (_Float16)v.w;
    return r;
}
__device__ __forceinline__ f16x4 frag4r(const float* __restrict__ p) {   // relu before cvt
    float4 v = *(const float4*)p;
    f16x4 r;
    r[0] = (_Float16)fmaxf(v.x, 0.f); r[1] = (_Float16)fmaxf(v.y, 0.f);
    r[2] = (_Float16)fmaxf(v.z, 0.f); r[3] = (_Float16)fmaxf(v.w, 0.f);
    return r;
}
__device__ __forceinline__ f32x4 mm(f16x4 a, f16x4 b, f32x4 c) {
    return __builtin_amdgcn_mfma_f32_16x16x16f16(a, b, c, 0, 0, 0);
}

// ---------------- node pass: 16 nodes/wave via MFMA; writes packed fp16 quad {EV,P,AO,OFF} ----
// out[i][d] = sum_k in[i][k] * W[d][k]:  A[i][k]=in, B[k][d]=W[d][k] (8 contig floats of W row d)
__global__ __launch_bounds__(256) void node_pass(
    const float* __restrict__ embU, const float* __restrict__ embE,
    const float* __restrict__ offU, const float* __restrict__ offE,
    const float* __restrict__ cW1, const float* __restrict__ cb1,
    const float* __restrict__ cW2, const float* __restrict__ cb2,
    const float* __restrict__ oW1, const float* __restrict__ ob1,
    uint2* __restrict__ packed)
{
    __shared__ _Float16 tb[4][16 * 72];   // per-wave transpose tile, +8 f16 pad
    int lane = threadIdx.x & 63, wid = threadIdx.x >> 6;
    int n0 = (blockIdx.x * 4 + wid) * 16;
    if (n0 >= NN) return;
    int lr = lane & 15, lk = lane >> 4;
    const float* eb; const float* ob;
    if (n0 < NU) { eb = embU + (size_t)n0 * 64; ob = offU + (size_t)n0 * 64; }
    else         { eb = embE + (size_t)(n0 - NU) * 64; ob = offE + (size_t)(n0 - NU) * 64; }

    // ---- center net: a1 = relu(W1 x + b1) ----
    f16x4 ax[4];
    #pragma unroll
    for (int ks = 0; ks < 4; ++ks) ax[ks] = frag4(eb + (size_t)lr * 64 + ks * 16 + lk * 4);
    f32x4 acc[4];
    #pragma unroll
    for (int dt = 0; dt < 4; ++dt) {
        float b = cb1[dt * 16 + lr];
        f32x4 c = {b, b, b, b};
        #pragma unroll
        for (int ks = 0; ks < 4; ++ks)
            c = mm(ax[ks], frag4(cW1 + (size_t)(dt * 16 + lr) * 64 + ks * 16 + lk * 4), c);
        acc[dt] = c;
    }
    // transpose relu(a1): D-layout -> A-frags via wave-private LDS
    _Float16* T = tb[wid];
    #pragma unroll
    for (int dt = 0; dt < 4; ++dt)
        #pragma unroll
        for (int r = 0; r < 4; ++r)
            T[(lk * 4 + r) * 72 + dt * 16 + lr] = (_Float16)fmaxf(acc[dt][r], 0.f);
    f16x4 a1[4];
    #pragma unroll
    for (int ks = 0; ks < 4; ++ks) a1[ks] = *(const f16x4*)(T + lr * 72 + ks * 16 + lk * 4);
    // lg = W2 a1 + b2
    #pragma unroll
    for (int dt = 0; dt < 4; ++dt) {
        float b = cb2[dt * 16 + lr];
        f32x4 c = {b, b, b, b};
        #pragma unroll
        for (int ks = 0; ks < 4; ++ks)
            c = mm(a1[ks], frag4(cW2 + (size_t)(dt * 16 + lr) * 64 + ks * 16 + lk * 4), c);
        acc[dt] = c;
    }
    // ---- offset net: ao = relu(O1 relu(o) + ob1) ----
    f16x4 axo[4];
    #pragma unroll
    for (int ks = 0; ks < 4; ++ks) axo[ks] = frag4r(ob + (size_t)lr * 64 + ks * 16 + lk * 4);
    f32x4 acco[4];
    #pragma unroll
    for (int dt = 0; dt < 4; ++dt) {
        float b = ob1[dt * 16 + lr];
        f32x4 c = {b, b, b, b};
        #pragma unroll
        for (int ks = 0; ks < 4; ++ks)
            c = mm(axo[ks], frag4(oW1 + (size_t)(dt * 16 + lr) * 64 + ks * 16 + lk * 4), c);
        acco[dt] = c;
    }
    // ---- store packed (D-layout: row node = lk*4+r, col = dt*16+lr) ----
    #pragma unroll
    for (int dt = 0; dt < 4; ++dt) {
        #pragma unroll
        for (int r = 0; r < 4; ++r) {
            int li = lk * 4 + r;
            float xv = eb[(size_t)li * 64 + dt * 16 + lr];
            float ov = fmaxf(ob[(size_t)li * 64 + dt * 16 + lr], 0.f);
            float ev = __expf(acc[dt][r]);   // segment-max shift skipped: |lg| << 1
            float aov = fmaxf(acco[dt][r], 0.f);
            packed[(size_t)(n0 + li) * 64 + dt * 16 + lr] = make_uint2(pack2(ev, ev * xv), pack2(aov, ov));
        }
    }
}

// ---------------- CSR build ----------------
__global__ __launch_bounds__(256) void hist_k(const int* __restrict__ head, int* __restrict__ counts) {
    int e = blockIdx.x * 256 + threadIdx.x;
    if (e < NEDGE) atomicAdd(&counts[head[e]], 1);
}

__global__ __launch_bounds__(1024) void scan_local(const int* __restrict__ counts,
                                                   int* __restrict__ excl, int* __restrict__ partials) {
    __shared__ int wsum[16];
    int tid = threadIdx.x, lane = tid & 63, wid = tid >> 6;
    int i = blockIdx.x * 1024 + tid;
    int v = (i < NN) ? counts[i] : 0;
    int s = v;
    #pragma unroll
    for (int d = 1; d < 64; d <<= 1) { int u = __shfl_up(s, d, 64); if (lane >= d) s += u; }
    if (lane == 63) wsum[wid] = s;
    __syncthreads();
    if (wid == 0 && lane < 16) {
        int w = wsum[lane];
        #pragma unroll
        for (int d = 1; d < 16; d <<= 1) { int u = __shfl_up(w, d, 64); if (lane >= d) w += u; }
        wsum[lane] = w;
    }
    __syncthreads();
    int base = wid ? wsum[wid - 1] : 0;
    if (i < NN) excl[i] = base + s - v;
    if (tid == 1023) partials[blockIdx.x] = wsum[15];
}

__global__ __launch_bounds__(256) void scan_carry(const int* __restrict__ partials, int* __restrict__ carries) {
    __shared__ int ws[4];
    int tid = threadIdx.x, lane = tid & 63, wid = tid >> 6;
    int v = (tid < SCAN_NB) ? partials[tid] : 0;
    int s = v;
    #pragma unroll
    for (int d = 1; d < 64; d <<= 1) { int u = __shfl_up(s, d, 64); if (lane >= d) s += u; }
    if (lane == 63) ws[wid] = s;
    __syncthreads();
    int add = 0;
    for (int w = 0; w < wid; ++w) add += ws[w];
    if (tid < SCAN_NB) carries[tid] = add + s - v;
}

__global__ __launch_bounds__(1024) void scan_add(int* __restrict__ excl, const int* __restrict__ carries,
                                                 int* __restrict__ cursor) {
    int i = blockIdx.x * 1024 + threadIdx.x;
    if (i < NN) { int o = excl[i] + carries[blockIdx.x]; excl[i] = o; cursor[i] = o; }
    if (i == 0) excl[NN] = NEDGE;
}

__global__ __launch_bounds__(256) void scatter_k(const int* __restrict__ head, const int* __restrict__ tail,
                                                 int* __restrict__ cursor, int* __restrict__ sorted_t) {
    int e = blockIdx.x * 256 + threadIdx.x;
    if (e < NEDGE) { int pos = atomicAdd(&cursor[head[e]], 1); sorted_t[pos] = tail[e]; }
}

// ---------------- segment pass: one wave per head node, one 8B gather per edge ----------------
__global__ __launch_bounds__(1024) void seg_pass(
    const uint2* __restrict__ packed,
    const int* __restrict__ offsets, const int* __restrict__ sorted_t,
    const float* __restrict__ oW2, const float* __restrict__ ob2,
    float* __restrict__ embOutU, float* __restrict__ embOutE,
    float* __restrict__ entOff,
    _Float16* __restrict__ meanI, _Float16* __restrict__ redI,
    _Float16* __restrict__ meanU, _Float16* __restrict__ redU)
{
    __shared__ float O2t[4096];
    bool hasEnt = (blockIdx.x >= NU / 16);     // block-uniform: heads >= NU exist in this block
    if (hasEnt) {
        for (int i = threadIdx.x; i < 4096; i += 1024) { int k = i >> 6, d = i & 63; O2t[i] = oW2[d * 64 + k]; }
        __syncthreads();
    }
    int lane = threadIdx.x & 63;
    int h = blockIdx.x * 16 + (threadIdx.x >> 6);
    if (h >= NN) return;
    int beg = offsets[h], end = offsets[h + 1];
    bool isUser = (h < NU);
    bool entMin = (h >= NU + NI);
    float num = 0.f, den = 0.f;
    float s_i = 0.f, s_u = 0.f, m_u = 0.f;
    float m_i = (isUser || entMin) ? INFINITY : 0.0f;
    int c_i = 0, c_u = 0;

    // depth-2 prefetch pipeline
    int t0 = 0, t1 = 0; uint2 q0 = make_uint2(0u, 0u), q1 = q0;
    if (beg < end)     { t0 = sorted_t[beg];     q0 = packed[(size_t)t0 * 64 + lane]; }
    if (beg + 1 < end) { t1 = sorted_t[beg + 1]; q1 = packed[(size_t)t1 * 64 + lane]; }
    for (int e = beg; e < end; ++e) {
        int tc = t0; uint2 qc = q0;
        t0 = t1; q0 = q1;
        if (e + 2 < end) { t1 = sorted_t[e + 2]; q1 = packed[(size_t)t1 * 64 + lane]; }
        float2 evp = unpack2(qc.x);             // {EV, P}
        den += evp.x; num += evp.y;
        float2 ao_o = unpack2(qc.y);            // {AO, OFF}
        if (isUser) {
            if (tc >= NU) {
                if (tc < NU + NI) { s_i += ao_o.x; m_i = fminf(m_i, ao_o.y); c_i++; }
                else              { s_u += ao_o.x; m_u = fmaxf(m_u, ao_o.y); c_u++; }
            }
        } else {
            s_i += ao_o.x; c_i++;
            m_i = entMin ? fminf(m_i, ao_o.y) : fmaxf(m_i, ao_o.y);
        }
    }
    // center: softmax-weighted mean + row L2 normalize
    float v = (den > 0.f) ? num / den : 0.f;
    float sq = v * v;
    #pragma unroll
    for (int m = 32; m; m >>= 1) sq += __shfl_xor(sq, m, 64);
    v = v / fmaxf(sqrtf(sq), 1e-12f);
    if (isUser) embOutU[(size_t)h * 64 + lane] = v;
    else        embOutE[(size_t)(h - NU) * 64 + lane] = v;

    if (isUser) {
        size_t r = (size_t)h * 64 + lane;
        meanI[r] = (_Float16)(s_i / fmaxf((float)c_i, 1.f));
        redI[r]  = (_Float16)((m_i > 1e37f) ? 0.f : m_i);
        meanU[r] = (_Float16)(s_u / fmaxf((float)c_u, 1.f));
        redU[r]  = (_Float16)m_u;
    } else {
        float mean = s_i / fmaxf((float)c_i, 1.f);
        float g = ob2[lane];
        #pragma unroll 8
        for (int k = 0; k < 64; ++k) g = fmaf(rlf(mean, k), O2t[k * 64 + lane], g);
        g = sigmoid_f(g);
        float rdv = (m_i > 1e37f) ? 0.f : m_i;
        entOff[(size_t)(h - NU) * 64 + lane] = rdv * g;
    }
}

// ---------------- user offset finalize: 16 users/wave via MFMA ----------------
__global__ __launch_bounds__(256) void user_fin2(
    const _Float16* __restrict__ meanI, const _Float16* __restrict__ redI,
    const _Float16* __restrict__ meanU, const _Float16* __restrict__ redU,
    const float* __restrict__ oW1, const float* __restrict__ ob1,
    const float* __restrict__ oW2, const float* __restrict__ ob2,
    float* __restrict__ outOffU)
{
    __shared__ _Float16 tb[4][16 * 72];
    int lane = threadIdx.x & 63, wid = threadIdx.x >> 6;
    int u0 = (blockIdx.x * 4 + wid) * 16;
    if (u0 >= NU) return;
    int lr = lane & 15, lk = lane >> 4;
    _Float16* T = tb[wid];

    f16x4 W1f[4][4], W2f[4][4];
    float b1d[4], b2d[4];
    #pragma unroll
    for (int dt = 0; dt < 4; ++dt) {
        b1d[dt] = ob1[dt * 16 + lr]; b2d[dt] = ob2[dt * 16 + lr];
        #pragma unroll
        for (int ks = 0; ks < 4; ++ks) {
            W1f[dt][ks] = frag4(oW1 + (size_t)(dt * 16 + lr) * 64 + ks * 16 + lk * 4);
            W2f[dt][ks] = frag4(oW2 + (size_t)(dt * 16 + lr) * 64 + ks * 16 + lk * 4);
        }
    }

    // iu = redI * sigmoid(O2 @ meanI + b2)
    f16x4 am[4];
    #pragma unroll
    for (int ks = 0; ks < 4; ++ks) am[ks] = *(const f16x4*)(meanI + (size_t)(u0 + lr) * 64 + ks * 16 + lk * 4);
    f32x4 iu[4], uu[4];
    #pragma unroll
    for (int dt = 0; dt < 4; ++dt) {
        f32x4 c = {b2d[dt], b2d[dt], b2d[dt], b2d[dt]};
        #pragma unroll
        for (int ks = 0; ks < 4; ++ks) c = mm(am[ks], W2f[dt][ks], c);
        #pragma unroll
        for (int r = 0; r < 4; ++r)
            iu[dt][r] = (float)redI[(size_t)(u0 + lk * 4 + r) * 64 + dt * 16 + lr] * sigmoid_f(c[r]);
    }
    // uu = redU * sigmoid(O2 @ meanU + b2)
    #pragma unroll
    for (int ks = 0; ks < 4; ++ks) am[ks] = *(const f16x4*)(meanU + (size_t)(u0 + lr) * 64 + ks * 16 + lk * 4);
    #pragma unroll
    for (int dt = 0; dt < 4; ++dt) {
        f32x4 c = {b2d[dt], b2d[dt], b2d[dt], b2d[dt]};
        #pragma unroll
        for (int ks = 0; ks < 4; ++ks) c = mm(am[ks], W2f[dt][ks], c);
        #pragma unroll
        for (int r = 0; r < 4; ++r)
            uu[dt][r] = (float)redU[(size_t)(u0 + lk * 4 + r) * 64 + dt * 16 + lr] * sigmoid_f(c[r]);
    }
    // a1 = relu(O1 @ iu + b1)
    #pragma unroll
    for (int dt = 0; dt < 4; ++dt)
        #pragma unroll
        for (int r = 0; r < 4; ++r) T[(lk * 4 + r) * 72 + dt * 16 + lr] = (_Float16)iu[dt][r];
    #pragma unroll
    for (int ks = 0; ks < 4; ++ks) am[ks] = *(const f16x4*)(T + lr * 72 + ks * 16 + lk * 4);
    f32x4 mn[4];
    #pragma unroll
    for (int dt = 0; dt < 4; ++dt) {
        f32x4 c = {b1d[dt], b1d[dt], b1d[dt], b1d[dt]};
        #pragma unroll
        for (int ks = 0; ks < 4; ++ks) c = mm(am[ks], W1f[dt][ks], c);
        #pragma unroll
        for (int r = 0; r < 4; ++r) mn[dt][r] = fmaxf(c[r], 0.f);
    }
    // a2 = relu(O1 @ uu + b1); mn = (a1+a2)/2
    #pragma unroll
    for (int dt = 0; dt < 4; ++dt)
        #pragma unroll
        for (int r = 0; r < 4; ++r) T[(lk * 4 + r) * 72 + dt * 16 + lr] = (_Float16)uu[dt][r];
    #pragma unroll
    for (int ks = 0; ks < 4; ++ks) am[ks] = *(const f16x4*)(T + lr * 72 + ks * 16 + lk * 4);
    #pragma unroll
    for (int dt = 0; dt < 4; ++dt) {
        f32x4 c = {b1d[dt], b1d[dt], b1d[dt], b1d[dt]};
        #pragma unroll
        for (int ks = 0; ks < 4; ++ks) c = mm(am[ks], W1f[dt][ks], c);
        #pragma unroll
        for (int r = 0; r < 4; ++r) mn[dt][r] = 0.5f * (mn[dt][r] + fmaxf(c[r], 0.f));
    }
    // g = sigmoid(O2 @ mn + b2); out = max(max(iu,uu)*g, 0)
    #pragma unroll
    for (int dt = 0; dt < 4; ++dt)
        #pragma unroll
        for (int r = 0; r < 4; ++r) T[(lk * 4 + r) * 72 + dt * 16 + lr] = (_Float16)mn[dt][r];
    #pragma unroll
    for (int ks = 0; ks < 4; ++ks) am[ks] = *(const f16x4*)(T + lr * 72 + ks * 16 + lk * 4);
    #pragma unroll
    for (int dt = 0; dt < 4; ++dt) {
        f32x4 c = {b2d[dt], b2d[dt], b2d[dt], b2d[dt]};
        #pragma unroll
        for (int ks = 0; ks < 4; ++ks) c = mm(am[ks], W2f[dt][ks], c);
        #pragma unroll
        for (int r = 0; r < 4; ++r)
            outOffU[(size_t)(u0 + lk * 4 + r) * 64 + dt * 16 + lr] =
                fmaxf(fmaxf(iu[dt][r], uu[dt][r]) * sigmoid_f(c[r]), 0.f);
    }
}

extern "C" void kernel_launch(void* const* d_in, const int* in_sizes, int n_in,
                              void* d_out, int out_size, void* d_ws, size_t ws_size,
                              hipStream_t stream)
{
    const float* user_emb = (const float*)d_in[0];
    const float* user_off = (const float*)d_in[1];
    const float* item_emb = (const float*)d_in[2];
    const float* item_off = (const float*)d_in[3];
    const float* cW1 = (const float*)d_in[4];
    const float* cb1 = (const float*)d_in[5];
    const float* cW2 = (const float*)d_in[6];
    const float* cb2 = (const float*)d_in[7];
    const float* oW1 = (const float*)d_in[8];
    const float* ob1 = (const float*)d_in[9];
    const float* oW2 = (const float*)d_in[10];
    const float* ob2 = (const float*)d_in[11];
    const int* head = (const int*)d_in[12];
    const int* tail = (const int*)d_in[13];
    float* out = (float*)d_out;

    float* ws = (float*)d_ws;
    const size_t SZ = (size_t)NN * 64;
    // budget ≈ 60.2M float-equiv (~243 MB) < 66.6M proven in R5
    float* A      = ws;                        // layer-0 emb out [NN,64]
    float* B      = A + SZ;                    // layer-0 off out [NN,64]
    uint2* packed = (uint2*)(B + SZ);          // [NN,64] fp16 quads
    _Float16* meanI_h = (_Float16*)(packed + SZ);   // [NU,64] f16 each
    _Float16* redI_h  = meanI_h + (size_t)NU * 64;
    _Float16* meanU_h = redI_h + (size_t)NU * 64;
    _Float16* redU_h  = meanU_h + (size_t)NU * 64;
    int* counts   = (int*)(redU_h + (size_t)NU * 64);
    int* offsets  = counts + NN;               // NN+1
    int* cursor   = offsets + NN + 1;
    int* sorted_t = cursor + NN;               // NEDGE
    int* partials = sorted_t + NEDGE;          // SCAN_NB
    int* carries  = partials + SCAN_NB;        // SCAN_NB

    // CSR build (per call; layer-independent)
    hipMemsetAsync(counts, 0, NN * sizeof(int), stream);
    hist_k<<<(NEDGE + 255) / 256, 256, 0, stream>>>(head, counts);
    scan_local<<<SCAN_NB, 1024, 0, stream>>>(counts, offsets, partials);
    scan_carry<<<1, 256, 0, stream>>>(partials, carries);
    scan_add<<<SCAN_NB, 1024, 0, stream>>>(offsets, carries, cursor);
    scatter_k<<<(NEDGE + 255) / 256, 256, 0, stream>>>(head, tail, cursor, sorted_t);

    for (int layer = 0; layer < 2; ++layer) {
        const float *eU, *eE, *oU, *oE;
        float *embOutU, *embOutE, *entOff, *uOffOut;
        if (layer == 0) {
            eU = user_emb; eE = item_emb; oU = user_off; oE = item_off;
            embOutU = A;               embOutE = A + (size_t)NU * 64;
            entOff  = B + (size_t)NU * 64;
            uOffOut = B;
        } else {
            eU = A; eE = A + (size_t)NU * 64; oU = B; oE = B + (size_t)NU * 64;
            embOutU = out;             embOutE = out + (size_t)2 * NU * 64;
            entOff  = out + ((size_t)2 * NU + NENT) * 64;
            uOffOut = out + (size_t)NU * 64;
        }
        node_pass<<<(NN + 63) / 64, 256, 0, stream>>>(eU, eE, oU, oE,
                                                      cW1, cb1, cW2, cb2, oW1, ob1, packed);
        seg_pass<<<(NN + 15) / 16, 1024, 0, stream>>>(packed, offsets, sorted_t,
                                                      oW2, ob2, embOutU, embOutE, entOff,
                                                      meanI_h, redI_h, meanU_h, redU_h);
        user_fin2<<<(NU + 63) / 64, 256, 0, stream>>>(meanI_h, redI_h, meanU_h, redU_h,
                                                      oW1, ob1, oW2, ob2, uOffOut);
    }
}

// Round 7
// 680.604 us; speedup vs baseline: 15.5358x; 1.1187x over previous
//
#include <hip/hip_runtime.h>
#include <hip/hip_fp16.h>
#include <math.h>

#define NU 100000
#define NI 50000
#define NENT 80000
#define NN 180000
#define NEDGE 800000
#define SCAN_NB ((NN + 1023) / 1024)   // 176

typedef _Float16 f16x4 __attribute__((ext_vector_type(4)));
typedef float f32x4 __attribute__((ext_vector_type(4)));

__device__ __forceinline__ float sigmoid_f(float x) { return 1.0f / (1.0f + __expf(-x)); }
__device__ __forceinline__ unsigned pack2(float a, float b) {
    __half2 h = __floats2half2_rn(a, b);
    return *(unsigned*)&h;
}
__device__ __forceinline__ float2 unpack2(unsigned u) {
    __half2 h = *(__half2*)&u;
    return __half22float2(h);
}
__device__ __forceinline__ f16x4 frag4(const float* __restrict__ p) {
    float4 v = *(const float4*)p;
    f16x4 r; r[0] = (_Float16)v.x; r[1] = (_Float16)v.y; r[2] = (_Float16)v.z; r[3] = (_Float16)v.w;
    return r;
}
__device__ __forceinline__ f16x4 frag4r(const float* __restrict__ p) {   // relu before cvt
    float4 v = *(const float4*)p;
    f16x4 r;
    r[0] = (_Float16)fmaxf(v.x, 0.f); r[1] = (_Float16)fmaxf(v.y, 0.f);
    r[2] = (_Float16)fmaxf(v.z, 0.f); r[3] = (_Float16)fmaxf(v.w, 0.f);
    return r;
}
__device__ __forceinline__ f32x4 mm(f16x4 a, f16x4 b, f32x4 c) {
    return __builtin_amdgcn_mfma_f32_16x16x16f16(a, b, c, 0, 0, 0);
}

// ---------------- node pass: 16 nodes/wave via MFMA; writes packed fp16 quad {EV,P,AO,OFF} ----
__global__ __launch_bounds__(256) void node_pass(
    const float* __restrict__ embU, const float* __restrict__ embE,
    const float* __restrict__ offU, const float* __restrict__ offE,
    const float* __restrict__ cW1, const float* __restrict__ cb1,
    const float* __restrict__ cW2, const float* __restrict__ cb2,
    const float* __restrict__ oW1, const float* __restrict__ ob1,
    uint2* __restrict__ packed)
{
    __shared__ _Float16 tb[4][16 * 72];   // per-wave transpose tile, +8 f16 pad
    int lane = threadIdx.x & 63, wid = threadIdx.x >> 6;
    int n0 = (blockIdx.x * 4 + wid) * 16;
    if (n0 >= NN) return;
    int lr = lane & 15, lk = lane >> 4;
    const float* eb; const float* ob;
    if (n0 < NU) { eb = embU + (size_t)n0 * 64; ob = offU + (size_t)n0 * 64; }
    else         { eb = embE + (size_t)(n0 - NU) * 64; ob = offE + (size_t)(n0 - NU) * 64; }

    // ---- center net: a1 = relu(W1 x + b1) ----
    f16x4 ax[4];
    #pragma unroll
    for (int ks = 0; ks < 4; ++ks) ax[ks] = frag4(eb + (size_t)lr * 64 + ks * 16 + lk * 4);
    f32x4 acc[4];
    #pragma unroll
    for (int dt = 0; dt < 4; ++dt) {
        float b = cb1[dt * 16 + lr];
        f32x4 c = {b, b, b, b};
        #pragma unroll
        for (int ks = 0; ks < 4; ++ks)
            c = mm(ax[ks], frag4(cW1 + (size_t)(dt * 16 + lr) * 64 + ks * 16 + lk * 4), c);
        acc[dt] = c;
    }
    _Float16* T = tb[wid];
    #pragma unroll
    for (int dt = 0; dt < 4; ++dt)
        #pragma unroll
        for (int r = 0; r < 4; ++r)
            T[(lk * 4 + r) * 72 + dt * 16 + lr] = (_Float16)fmaxf(acc[dt][r], 0.f);
    f16x4 a1[4];
    #pragma unroll
    for (int ks = 0; ks < 4; ++ks) a1[ks] = *(const f16x4*)(T + lr * 72 + ks * 16 + lk * 4);
    #pragma unroll
    for (int dt = 0; dt < 4; ++dt) {
        float b = cb2[dt * 16 + lr];
        f32x4 c = {b, b, b, b};
        #pragma unroll
        for (int ks = 0; ks < 4; ++ks)
            c = mm(a1[ks], frag4(cW2 + (size_t)(dt * 16 + lr) * 64 + ks * 16 + lk * 4), c);
        acc[dt] = c;
    }
    // ---- offset net: ao = relu(O1 relu(o) + ob1) ----
    f16x4 axo[4];
    #pragma unroll
    for (int ks = 0; ks < 4; ++ks) axo[ks] = frag4r(ob + (size_t)lr * 64 + ks * 16 + lk * 4);
    f32x4 acco[4];
    #pragma unroll
    for (int dt = 0; dt < 4; ++dt) {
        float b = ob1[dt * 16 + lr];
        f32x4 c = {b, b, b, b};
        #pragma unroll
        for (int ks = 0; ks < 4; ++ks)
            c = mm(axo[ks], frag4(oW1 + (size_t)(dt * 16 + lr) * 64 + ks * 16 + lk * 4), c);
        acco[dt] = c;
    }
    // ---- store packed ----
    #pragma unroll
    for (int dt = 0; dt < 4; ++dt) {
        #pragma unroll
        for (int r = 0; r < 4; ++r) {
            int li = lk * 4 + r;
            float xv = eb[(size_t)li * 64 + dt * 16 + lr];
            float ov = fmaxf(ob[(size_t)li * 64 + dt * 16 + lr], 0.f);
            float ev = __expf(acc[dt][r]);   // segment-max shift skipped: |lg| << 1
            float aov = fmaxf(acco[dt][r], 0.f);
            packed[(size_t)(n0 + li) * 64 + dt * 16 + lr] = make_uint2(pack2(ev, ev * xv), pack2(aov, ov));
        }
    }
}

// ---------------- CSR build ----------------
__global__ __launch_bounds__(256) void hist_k(const int* __restrict__ head, int* __restrict__ counts) {
    int e = blockIdx.x * 256 + threadIdx.x;
    if (e < NEDGE) atomicAdd(&counts[head[e]], 1);
}

__global__ __launch_bounds__(1024) void scan_local(const int* __restrict__ counts,
                                                   int* __restrict__ excl, int* __restrict__ partials) {
    __shared__ int wsum[16];
    int tid = threadIdx.x, lane = tid & 63, wid = tid >> 6;
    int i = blockIdx.x * 1024 + tid;
    int v = (i < NN) ? counts[i] : 0;
    int s = v;
    #pragma unroll
    for (int d = 1; d < 64; d <<= 1) { int u = __shfl_up(s, d, 64); if (lane >= d) s += u; }
    if (lane == 63) wsum[wid] = s;
    __syncthreads();
    if (wid == 0 && lane < 16) {
        int w = wsum[lane];
        #pragma unroll
        for (int d = 1; d < 16; d <<= 1) { int u = __shfl_up(w, d, 64); if (lane >= d) w += u; }
        wsum[lane] = w;
    }
    __syncthreads();
    int base = wid ? wsum[wid - 1] : 0;
    if (i < NN) excl[i] = base + s - v;
    if (tid == 1023) partials[blockIdx.x] = wsum[15];
}

__global__ __launch_bounds__(256) void scan_carry(const int* __restrict__ partials, int* __restrict__ carries) {
    __shared__ int ws[4];
    int tid = threadIdx.x, lane = tid & 63, wid = tid >> 6;
    int v = (tid < SCAN_NB) ? partials[tid] : 0;
    int s = v;
    #pragma unroll
    for (int d = 1; d < 64; d <<= 1) { int u = __shfl_up(s, d, 64); if (lane >= d) s += u; }
    if (lane == 63) ws[wid] = s;
    __syncthreads();
    int add = 0;
    for (int w = 0; w < wid; ++w) add += ws[w];
    if (tid < SCAN_NB) carries[tid] = add + s - v;
}

__global__ __launch_bounds__(1024) void scan_add(int* __restrict__ excl, const int* __restrict__ carries,
                                                 int* __restrict__ cursor) {
    int i = blockIdx.x * 1024 + threadIdx.x;
    if (i < NN) { int o = excl[i] + carries[blockIdx.x]; excl[i] = o; cursor[i] = o; }
    if (i == 0) excl[NN] = NEDGE;
}

__global__ __launch_bounds__(256) void scatter_k(const int* __restrict__ head, const int* __restrict__ tail,
                                                 int* __restrict__ cursor, int* __restrict__ sorted_t) {
    int e = blockIdx.x * 256 + threadIdx.x;
    if (e < NEDGE) { int pos = atomicAdd(&cursor[head[e]], 1); sorted_t[pos] = tail[e]; }
}

// ---------------- segment pass: one wave per head node; SGPR-based gathers ----------------
__global__ __launch_bounds__(1024) void seg_pass(
    const uint2* __restrict__ packed,
    const int* __restrict__ offsets, const int* __restrict__ sorted_t,
    float* __restrict__ embOutU, float* __restrict__ embOutE,
    _Float16* __restrict__ meanI, _Float16* __restrict__ redI,
    _Float16* __restrict__ meanU, _Float16* __restrict__ redU,
    _Float16* __restrict__ meanE, _Float16* __restrict__ redE)
{
    int lane = threadIdx.x & 63;
    int h = blockIdx.x * 16 + (threadIdx.x >> 6);
    if (h >= NN) return;
    int beg = offsets[h], end = offsets[h + 1];
    bool isUser = (h < NU);
    bool entMin = (h >= NU + NI);
    float num = 0.f, den = 0.f;
    float s_i = 0.f, s_u = 0.f, m_u = 0.f;
    float m_i = (isUser || entMin) ? 3.0e38f : 0.0f;
    int c_i = 0, c_u = 0;

    const char* pbase = (const char*)packed;
    int loff = lane << 3;
    for (int base = beg; base < end; base += 64) {
        int rem = end - base; if (rem > 64) rem = 64;
        // one coalesced load of up to 64 tail ids; each edge's id then comes via readlane (SGPR)
        int tv = sorted_t[base + (lane < rem ? lane : 0)];
        int t0 = __builtin_amdgcn_readlane(tv, 0);
        uint2 q0 = *(const uint2*)(pbase + ((size_t)(unsigned)t0 << 9) + loff);
        int t1 = t0; uint2 q1 = q0;
        if (rem > 1) {
            t1 = __builtin_amdgcn_readlane(tv, 1);
            q1 = *(const uint2*)(pbase + ((size_t)(unsigned)t1 << 9) + loff);
        }
        for (int j = 0; j < rem; ++j) {
            int tc = t0; uint2 qc = q0;
            t0 = t1; q0 = q1;
            if (j + 2 < rem) {
                t1 = __builtin_amdgcn_readlane(tv, j + 2);
                q1 = *(const uint2*)(pbase + ((size_t)(unsigned)t1 << 9) + loff);
            }
            float2 evp = unpack2(qc.x);             // {EV, P}
            den += evp.x; num += evp.y;
            float2 ao_o = unpack2(qc.y);            // {AO, OFF}
            if (isUser) {
                if (tc >= NU) {
                    if (tc < NU + NI) { s_i += ao_o.x; m_i = fminf(m_i, ao_o.y); c_i++; }
                    else              { s_u += ao_o.x; m_u = fmaxf(m_u, ao_o.y); c_u++; }
                }
            } else {
                s_i += ao_o.x; c_i++;
                m_i = entMin ? fminf(m_i, ao_o.y) : fmaxf(m_i, ao_o.y);
            }
        }
    }
    // center: softmax-weighted mean + row L2 normalize
    float v = (den > 0.f) ? num / den : 0.f;
    float sq = v * v;
    #pragma unroll
    for (int m = 32; m; m >>= 1) sq += __shfl_xor(sq, m, 64);
    v = v / fmaxf(sqrtf(sq), 1e-12f);

    if (isUser) {
        embOutU[(size_t)h * 64 + lane] = v;
        size_t r = (size_t)h * 64 + lane;
        meanI[r] = (_Float16)(s_i / fmaxf((float)c_i, 1.f));
        redI[r]  = (_Float16)((m_i > 1e37f) ? 0.f : m_i);
        meanU[r] = (_Float16)(s_u / fmaxf((float)c_u, 1.f));
        redU[r]  = (_Float16)m_u;
    } else {
        embOutE[(size_t)(h - NU) * 64 + lane] = v;
        size_t r = (size_t)(h - NU) * 64 + lane;
        meanE[r] = (_Float16)(s_i / fmaxf((float)c_i, 1.f));
        redE[r]  = (_Float16)((m_i > 1e37f) ? 0.f : m_i);
    }
}

// ---------------- ent offset finalize: 16 ents/wave via MFMA ----------------
__global__ __launch_bounds__(256) void ent_fin(
    const _Float16* __restrict__ meanE, const _Float16* __restrict__ redE,
    const float* __restrict__ oW2, const float* __restrict__ ob2,
    float* __restrict__ entOff)
{
    int lane = threadIdx.x & 63, wid = threadIdx.x >> 6;
    int n0 = (blockIdx.x * 4 + wid) * 16;
    if (n0 >= NENT) return;
    int lr = lane & 15, lk = lane >> 4;
    f16x4 am[4];
    #pragma unroll
    for (int ks = 0; ks < 4; ++ks) am[ks] = *(const f16x4*)(meanE + (size_t)(n0 + lr) * 64 + ks * 16 + lk * 4);
    #pragma unroll
    for (int dt = 0; dt < 4; ++dt) {
        float b = ob2[dt * 16 + lr];
        f32x4 c = {b, b, b, b};
        #pragma unroll
        for (int ks = 0; ks < 4; ++ks)
            c = mm(am[ks], frag4(oW2 + (size_t)(dt * 16 + lr) * 64 + ks * 16 + lk * 4), c);
        #pragma unroll
        for (int r = 0; r < 4; ++r) {
            size_t row = (size_t)(n0 + lk * 4 + r);
            entOff[row * 64 + dt * 16 + lr] = (float)redE[row * 64 + dt * 16 + lr] * sigmoid_f(c[r]);
        }
    }
}

// ---------------- user offset finalize: 16 users/wave via MFMA ----------------
__global__ __launch_bounds__(256) void user_fin2(
    const _Float16* __restrict__ meanI, const _Float16* __restrict__ redI,
    const _Float16* __restrict__ meanU, const _Float16* __restrict__ redU,
    const float* __restrict__ oW1, const float* __restrict__ ob1,
    const float* __restrict__ oW2, const float* __restrict__ ob2,
    float* __restrict__ outOffU)
{
    __shared__ _Float16 tb[4][16 * 72];
    int lane = threadIdx.x & 63, wid = threadIdx.x >> 6;
    int u0 = (blockIdx.x * 4 + wid) * 16;
    if (u0 >= NU) return;
    int lr = lane & 15, lk = lane >> 4;
    _Float16* T = tb[wid];

    f16x4 W1f[4][4], W2f[4][4];
    float b1d[4], b2d[4];
    #pragma unroll
    for (int dt = 0; dt < 4; ++dt) {
        b1d[dt] = ob1[dt * 16 + lr]; b2d[dt] = ob2[dt * 16 + lr];
        #pragma unroll
        for (int ks = 0; ks < 4; ++ks) {
            W1f[dt][ks] = frag4(oW1 + (size_t)(dt * 16 + lr) * 64 + ks * 16 + lk * 4);
            W2f[dt][ks] = frag4(oW2 + (size_t)(dt * 16 + lr) * 64 + ks * 16 + lk * 4);
        }
    }

    f16x4 am[4];
    #pragma unroll
    for (int ks = 0; ks < 4; ++ks) am[ks] = *(const f16x4*)(meanI + (size_t)(u0 + lr) * 64 + ks * 16 + lk * 4);
    f32x4 iu[4], uu[4];
    #pragma unroll
    for (int dt = 0; dt < 4; ++dt) {
        f32x4 c = {b2d[dt], b2d[dt], b2d[dt], b2d[dt]};
        #pragma unroll
        for (int ks = 0; ks < 4; ++ks) c = mm(am[ks], W2f[dt][ks], c);
        #pragma unroll
        for (int r = 0; r < 4; ++r)
            iu[dt][r] = (float)redI[(size_t)(u0 + lk * 4 + r) * 64 + dt * 16 + lr] * sigmoid_f(c[r]);
    }
    #pragma unroll
    for (int ks = 0; ks < 4; ++ks) am[ks] = *(const f16x4*)(meanU + (size_t)(u0 + lr) * 64 + ks * 16 + lk * 4);
    #pragma unroll
    for (int dt = 0; dt < 4; ++dt) {
        f32x4 c = {b2d[dt], b2d[dt], b2d[dt], b2d[dt]};
        #pragma unroll
        for (int ks = 0; ks < 4; ++ks) c = mm(am[ks], W2f[dt][ks], c);
        #pragma unroll
        for (int r = 0; r < 4; ++r)
            uu[dt][r] = (float)redU[(size_t)(u0 + lk * 4 + r) * 64 + dt * 16 + lr] * sigmoid_f(c[r]);
    }
    #pragma unroll
    for (int dt = 0; dt < 4; ++dt)
        #pragma unroll
        for (int r = 0; r < 4; ++r) T[(lk * 4 + r) * 72 + dt * 16 + lr] = (_Float16)iu[dt][r];
    #pragma unroll
    for (int ks = 0; ks < 4; ++ks) am[ks] = *(const f16x4*)(T + lr * 72 + ks * 16 + lk * 4);
    f32x4 mn[4];
    #pragma unroll
    for (int dt = 0; dt < 4; ++dt) {
        f32x4 c = {b1d[dt], b1d[dt], b1d[dt], b1d[dt]};
        #pragma unroll
        for (int ks = 0; ks < 4; ++ks) c = mm(am[ks], W1f[dt][ks], c);
        #pragma unroll
        for (int r = 0; r < 4; ++r) mn[dt][r] = fmaxf(c[r], 0.f);
    }
    #pragma unroll
    for (int dt = 0; dt < 4; ++dt)
        #pragma unroll
        for (int r = 0; r < 4; ++r) T[(lk * 4 + r) * 72 + dt * 16 + lr] = (_Float16)uu[dt][r];
    #pragma unroll
    for (int ks = 0; ks < 4; ++ks) am[ks] = *(const f16x4*)(T + lr * 72 + ks * 16 + lk * 4);
    #pragma unroll
    for (int dt = 0; dt < 4; ++dt) {
        f32x4 c = {b1d[dt], b1d[dt], b1d[dt], b1d[dt]};
        #pragma unroll
        for (int ks = 0; ks < 4; ++ks) c = mm(am[ks], W1f[dt][ks], c);
        #pragma unroll
        for (int r = 0; r < 4; ++r) mn[dt][r] = 0.5f * (mn[dt][r] + fmaxf(c[r], 0.f));
    }
    #pragma unroll
    for (int dt = 0; dt < 4; ++dt)
        #pragma unroll
        for (int r = 0; r < 4; ++r) T[(lk * 4 + r) * 72 + dt * 16 + lr] = (_Float16)mn[dt][r];
    #pragma unroll
    for (int ks = 0; ks < 4; ++ks) am[ks] = *(const f16x4*)(T + lr * 72 + ks * 16 + lk * 4);
    #pragma unroll
    for (int dt = 0; dt < 4; ++dt) {
        f32x4 c = {b2d[dt], b2d[dt], b2d[dt], b2d[dt]};
        #pragma unroll
        for (int ks = 0; ks < 4; ++ks) c = mm(am[ks], W2f[dt][ks], c);
        #pragma unroll
        for (int r = 0; r < 4; ++r)
            outOffU[(size_t)(u0 + lk * 4 + r) * 64 + dt * 16 + lr] =
                fmaxf(fmaxf(iu[dt][r], uu[dt][r]) * sigmoid_f(c[r]), 0.f);
    }
}

extern "C" void kernel_launch(void* const* d_in, const int* in_sizes, int n_in,
                              void* d_out, int out_size, void* d_ws, size_t ws_size,
                              hipStream_t stream)
{
    const float* user_emb = (const float*)d_in[0];
    const float* user_off = (const float*)d_in[1];
    const float* item_emb = (const float*)d_in[2];
    const float* item_off = (const float*)d_in[3];
    const float* cW1 = (const float*)d_in[4];
    const float* cb1 = (const float*)d_in[5];
    const float* cW2 = (const float*)d_in[6];
    const float* cb2 = (const float*)d_in[7];
    const float* oW1 = (const float*)d_in[8];
    const float* ob1 = (const float*)d_in[9];
    const float* oW2 = (const float*)d_in[10];
    const float* ob2 = (const float*)d_in[11];
    const int* head = (const int*)d_in[12];
    const int* tail = (const int*)d_in[13];
    float* out = (float*)d_out;

    float* ws = (float*)d_ws;
    const size_t SZ = (size_t)NN * 64;
    // budget ≈ 65.3M float-equiv < 66.6M proven in R5
    float* A      = ws;                        // layer-0 emb out [NN,64]
    float* B      = A + SZ;                    // layer-0 off out [NN,64]
    uint2* packed = (uint2*)(B + SZ);          // [NN,64] fp16 quads
    _Float16* meanI_h = (_Float16*)(packed + SZ);   // [NU,64] f16
    _Float16* redI_h  = meanI_h + (size_t)NU * 64;
    _Float16* meanU_h = redI_h + (size_t)NU * 64;
    _Float16* redU_h  = meanU_h + (size_t)NU * 64;
    _Float16* meanE_h = redU_h + (size_t)NU * 64;   // [NENT,64] f16
    _Float16* redE_h  = meanE_h + (size_t)NENT * 64;
    int* counts   = (int*)(redE_h + (size_t)NENT * 64);
    int* offsets  = counts + NN;               // NN+1
    int* cursor   = offsets + NN + 1;
    int* sorted_t = cursor + NN;               // NEDGE
    int* partials = sorted_t + NEDGE;          // SCAN_NB
    int* carries  = partials + SCAN_NB;        // SCAN_NB

    // CSR build (per call; layer-independent)
    hipMemsetAsync(counts, 0, NN * sizeof(int), stream);
    hist_k<<<(NEDGE + 255) / 256, 256, 0, stream>>>(head, counts);
    scan_local<<<SCAN_NB, 1024, 0, stream>>>(counts, offsets, partials);
    scan_carry<<<1, 256, 0, stream>>>(partials, carries);
    scan_add<<<SCAN_NB, 1024, 0, stream>>>(offsets, carries, cursor);
    scatter_k<<<(NEDGE + 255) / 256, 256, 0, stream>>>(head, tail, cursor, sorted_t);

    for (int layer = 0; layer < 2; ++layer) {
        const float *eU, *eE, *oU, *oE;
        float *embOutU, *embOutE, *entOff, *uOffOut;
        if (layer == 0) {
            eU = user_emb; eE = item_emb; oU = user_off; oE = item_off;
            embOutU = A;               embOutE = A + (size_t)NU * 64;
            entOff  = B + (size_t)NU * 64;
            uOffOut = B;
        } else {
            eU = A; eE = A + (size_t)NU * 64; oU = B; oE = B + (size_t)NU * 64;
            embOutU = out;             embOutE = out + (size_t)2 * NU * 64;
            entOff  = out + ((size_t)2 * NU + NENT) * 64;
            uOffOut = out + (size_t)NU * 64;
        }
        node_pass<<<(NN + 63) / 64, 256, 0, stream>>>(eU, eE, oU, oE,
                                                      cW1, cb1, cW2, cb2, oW1, ob1, packed);
        seg_pass<<<(NN + 15) / 16, 1024, 0, stream>>>(packed, offsets, sorted_t,
                                                      embOutU, embOutE,
                                                      meanI_h, redI_h, meanU_h, redU_h,
                                                      meanE_h, redE_h);
        ent_fin<<<(NENT / 16 + 3) / 4, 256, 0, stream>>>(meanE_h, redE_h, oW2, ob2, entOff);
        user_fin2<<<(NU + 63) / 64, 256, 0, stream>>>(meanI_h, redI_h, meanU_h, redU_h,
                                                      oW1, ob1, oW2, ob2, uOffOut);
    }
}

// Round 8
// 476.869 us; speedup vs baseline: 22.1733x; 1.4272x over previous
//
#include <hip/hip_runtime.h>
#include <hip/hip_fp16.h>
#include <math.h>

#define NU 100000
#define NI 50000
#define NENT 80000
#define NN 180000
#define NEDGE 800000
#define SCAN_NB ((NN + 1023) / 1024)   // 176

typedef _Float16 f16x4 __attribute__((ext_vector_type(4)));
typedef float f32x4 __attribute__((ext_vector_type(4)));

__device__ __forceinline__ float sigmoid_f(float x) { return 1.0f / (1.0f + __expf(-x)); }
__device__ __forceinline__ unsigned pack2(float a, float b) {
    __half2 h = __floats2half2_rn(a, b);
    return *(unsigned*)&h;
}
__device__ __forceinline__ float2 unpack2(unsigned u) {
    __half2 h = *(__half2*)&u;
    return __half22float2(h);
}
__device__ __forceinline__ f16x4 frag4(const float* __restrict__ p) {
    float4 v = *(const float4*)p;
    f16x4 r; r[0] = (_Float16)v.x; r[1] = (_Float16)v.y; r[2] = (_Float16)v.z; r[3] = (_Float16)v.w;
    return r;
}
__device__ __forceinline__ f16x4 frag4r(const float* __restrict__ p) {   // relu before cvt
    float4 v = *(const float4*)p;
    f16x4 r;
    r[0] = (_Float16)fmaxf(v.x, 0.f); r[1] = (_Float16)fmaxf(v.y, 0.f);
    r[2] = (_Float16)fmaxf(v.z, 0.f); r[3] = (_Float16)fmaxf(v.w, 0.f);
    return r;
}
// prepacked weight frag: coalesced 8B/lane from an L1-resident 8KB table
__device__ __forceinline__ f16x4 fragp(const _Float16* __restrict__ Wp, int dt, int ks, int lane) {
    return *(const f16x4*)(Wp + (((dt * 4 + ks) * 64 + lane) << 2));
}
__device__ __forceinline__ f32x4 mm(f16x4 a, f16x4 b, f32x4 c) {
    return __builtin_amdgcn_mfma_f32_16x16x16f16(a, b, c, 0, 0, 0);
}

// ---------------- weight prepack: f32 row-major -> frag-linear f16 ----------------
// out[mat][((dt*4+ks)*64 + lane)*4 + j] = W[(dt*16 + (lane&15))*64 + ks*16 + (lane>>4)*4 + j]
__global__ __launch_bounds__(256) void prep_w(
    const float* __restrict__ W0, const float* __restrict__ W1,
    const float* __restrict__ W2, const float* __restrict__ W3,
    _Float16* __restrict__ out)
{
    int idx = blockIdx.x * 256 + threadIdx.x;          // 0 .. 16383
    int mat = idx >> 12, wi = idx & 4095;
    const float* W = (mat == 0) ? W0 : (mat == 1) ? W1 : (mat == 2) ? W2 : W3;
    int tile = wi >> 8;            // dt*4+ks
    int dt = tile >> 2, ks = tile & 3;
    int ln = (wi >> 2) & 63, j = wi & 3;
    int lr = ln & 15, lk = ln >> 4;
    out[idx] = (_Float16)W[(size_t)(dt * 16 + lr) * 64 + ks * 16 + lk * 4 + j];
}

// ---------------- node pass: 16 nodes/wave via MFMA; writes packed fp16 quad {EV,P,AO,OFF} ----
__global__ __launch_bounds__(256) void node_pass(
    const float* __restrict__ embU, const float* __restrict__ embE,
    const float* __restrict__ offU, const float* __restrict__ offE,
    const _Float16* __restrict__ cW1f, const float* __restrict__ cb1,
    const _Float16* __restrict__ cW2f, const float* __restrict__ cb2,
    const _Float16* __restrict__ oW1f, const float* __restrict__ ob1,
    uint2* __restrict__ packed)
{
    __shared__ _Float16 tb[4][16 * 72];   // per-wave transpose tile, +8 f16 pad
    int lane = threadIdx.x & 63, wid = threadIdx.x >> 6;
    int n0 = (blockIdx.x * 4 + wid) * 16;
    if (n0 >= NN) return;
    int lr = lane & 15, lk = lane >> 4;
    const float* eb; const float* ob;
    if (n0 < NU) { eb = embU + (size_t)n0 * 64; ob = offU + (size_t)n0 * 64; }
    else         { eb = embE + (size_t)(n0 - NU) * 64; ob = offE + (size_t)(n0 - NU) * 64; }

    // ---- center net: a1 = relu(W1 x + b1) ----
    f16x4 ax[4];
    #pragma unroll
    for (int ks = 0; ks < 4; ++ks) ax[ks] = frag4(eb + (size_t)lr * 64 + ks * 16 + lk * 4);
    f32x4 acc[4];
    #pragma unroll
    for (int dt = 0; dt < 4; ++dt) {
        float b = cb1[dt * 16 + lr];
        f32x4 c = {b, b, b, b};
        #pragma unroll
        for (int ks = 0; ks < 4; ++ks) c = mm(ax[ks], fragp(cW1f, dt, ks, lane), c);
        acc[dt] = c;
    }
    _Float16* T = tb[wid];
    #pragma unroll
    for (int dt = 0; dt < 4; ++dt)
        #pragma unroll
        for (int r = 0; r < 4; ++r)
            T[(lk * 4 + r) * 72 + dt * 16 + lr] = (_Float16)fmaxf(acc[dt][r], 0.f);
    f16x4 a1[4];
    #pragma unroll
    for (int ks = 0; ks < 4; ++ks) a1[ks] = *(const f16x4*)(T + lr * 72 + ks * 16 + lk * 4);
    #pragma unroll
    for (int dt = 0; dt < 4; ++dt) {
        float b = cb2[dt * 16 + lr];
        f32x4 c = {b, b, b, b};
        #pragma unroll
        for (int ks = 0; ks < 4; ++ks) c = mm(a1[ks], fragp(cW2f, dt, ks, lane), c);
        acc[dt] = c;
    }
    // ---- offset net: ao = relu(O1 relu(o) + ob1) ----
    f16x4 axo[4];
    #pragma unroll
    for (int ks = 0; ks < 4; ++ks) axo[ks] = frag4r(ob + (size_t)lr * 64 + ks * 16 + lk * 4);
    f32x4 acco[4];
    #pragma unroll
    for (int dt = 0; dt < 4; ++dt) {
        float b = ob1[dt * 16 + lr];
        f32x4 c = {b, b, b, b};
        #pragma unroll
        for (int ks = 0; ks < 4; ++ks) c = mm(axo[ks], fragp(oW1f, dt, ks, lane), c);
        acco[dt] = c;
    }
    // ---- transpose x to D-layout via T (wave-private sequential reuse; no barrier) ----
    #pragma unroll
    for (int ks = 0; ks < 4; ++ks) *(f16x4*)(T + lr * 72 + ks * 16 + lk * 4) = ax[ks];
    _Float16 xv[16];
    #pragma unroll
    for (int dt = 0; dt < 4; ++dt)
        #pragma unroll
        for (int r = 0; r < 4; ++r) xv[dt * 4 + r] = T[(lk * 4 + r) * 72 + dt * 16 + lr];
    // ---- transpose relu(o) similarly ----
    #pragma unroll
    for (int ks = 0; ks < 4; ++ks) *(f16x4*)(T + lr * 72 + ks * 16 + lk * 4) = axo[ks];
    #pragma unroll
    for (int dt = 0; dt < 4; ++dt) {
        #pragma unroll
        for (int r = 0; r < 4; ++r) {
            int li = lk * 4 + r;
            float ev = __expf(acc[dt][r]);   // segment-max shift skipped: |lg| << 1
            float xf = (float)xv[dt * 4 + r];
            float ovf = (float)T[(lk * 4 + r) * 72 + dt * 16 + lr];
            float aov = fmaxf(acco[dt][r], 0.f);
            packed[(size_t)(n0 + li) * 64 + dt * 16 + lr] = make_uint2(pack2(ev, ev * xf), pack2(aov, ovf));
        }
    }
}

// ---------------- CSR build ----------------
__global__ __launch_bounds__(256) void hist_k(const int* __restrict__ head, int* __restrict__ counts) {
    int e = blockIdx.x * 256 + threadIdx.x;
    if (e < NEDGE) atomicAdd(&counts[head[e]], 1);
}

__global__ __launch_bounds__(1024) void scan_local(const int* __restrict__ counts,
                                                   int* __restrict__ excl, int* __restrict__ partials) {
    __shared__ int wsum[16];
    int tid = threadIdx.x, lane = tid & 63, wid = tid >> 6;
    int i = blockIdx.x * 1024 + tid;
    int v = (i < NN) ? counts[i] : 0;
    int s = v;
    #pragma unroll
    for (int d = 1; d < 64; d <<= 1) { int u = __shfl_up(s, d, 64); if (lane >= d) s += u; }
    if (lane == 63) wsum[wid] = s;
    __syncthreads();
    if (wid == 0 && lane < 16) {
        int w = wsum[lane];
        #pragma unroll
        for (int d = 1; d < 16; d <<= 1) { int u = __shfl_up(w, d, 64); if (lane >= d) w += u; }
        wsum[lane] = w;
    }
    __syncthreads();
    int base = wid ? wsum[wid - 1] : 0;
    if (i < NN) excl[i] = base + s - v;
    if (tid == 1023) partials[blockIdx.x] = wsum[15];
}

__global__ __launch_bounds__(256) void scan_carry(const int* __restrict__ partials, int* __restrict__ carries) {
    __shared__ int ws[4];
    int tid = threadIdx.x, lane = tid & 63, wid = tid >> 6;
    int v = (tid < SCAN_NB) ? partials[tid] : 0;
    int s = v;
    #pragma unroll
    for (int d = 1; d < 64; d <<= 1) { int u = __shfl_up(s, d, 64); if (lane >= d) s += u; }
    if (lane == 63) ws[wid] = s;
    __syncthreads();
    int add = 0;
    for (int w = 0; w < wid; ++w) add += ws[w];
    if (tid < SCAN_NB) carries[tid] = add + s - v;
}

__global__ __launch_bounds__(1024) void scan_add(int* __restrict__ excl, const int* __restrict__ carries,
                                                 int* __restrict__ cursor) {
    int i = blockIdx.x * 1024 + threadIdx.x;
    if (i < NN) { int o = excl[i] + carries[blockIdx.x]; excl[i] = o; cursor[i] = o; }
    if (i == 0) excl[NN] = NEDGE;
}

__global__ __launch_bounds__(256) void scatter_k(const int* __restrict__ head, const int* __restrict__ tail,
                                                 int* __restrict__ cursor, int* __restrict__ sorted_t) {
    int e = blockIdx.x * 256 + threadIdx.x;
    if (e < NEDGE) { int pos = atomicAdd(&cursor[head[e]], 1); sorted_t[pos] = tail[e]; }
}

// ---------------- segment pass: one wave per head node; SGPR-based gathers ----------------
__global__ __launch_bounds__(1024) void seg_pass(
    const uint2* __restrict__ packed,
    const int* __restrict__ offsets, const int* __restrict__ sorted_t,
    float* __restrict__ embOutU, float* __restrict__ embOutE,
    _Float16* __restrict__ meanI, _Float16* __restrict__ redI,
    _Float16* __restrict__ meanU, _Float16* __restrict__ redU,
    _Float16* __restrict__ meanE, _Float16* __restrict__ redE)
{
    int lane = threadIdx.x & 63;
    int h = blockIdx.x * 16 + (threadIdx.x >> 6);
    if (h >= NN) return;
    int beg = offsets[h], end = offsets[h + 1];
    bool isUser = (h < NU);
    bool entMin = (h >= NU + NI);
    float num = 0.f, den = 0.f;
    float s_i = 0.f, s_u = 0.f, m_u = 0.f;
    float m_i = (isUser || entMin) ? 3.0e38f : 0.0f;
    int c_i = 0, c_u = 0;

    const char* pbase = (const char*)packed;
    int loff = lane << 3;
    for (int base = beg; base < end; base += 64) {
        int rem = end - base; if (rem > 64) rem = 64;
        int tv = sorted_t[base + (lane < rem ? lane : 0)];
        int t0 = __builtin_amdgcn_readlane(tv, 0);
        uint2 q0 = *(const uint2*)(pbase + ((size_t)(unsigned)t0 << 9) + loff);
        int t1 = t0; uint2 q1 = q0;
        if (rem > 1) {
            t1 = __builtin_amdgcn_readlane(tv, 1);
            q1 = *(const uint2*)(pbase + ((size_t)(unsigned)t1 << 9) + loff);
        }
        for (int j = 0; j < rem; ++j) {
            int tc = t0; uint2 qc = q0;
            t0 = t1; q0 = q1;
            if (j + 2 < rem) {
                t1 = __builtin_amdgcn_readlane(tv, j + 2);
                q1 = *(const uint2*)(pbase + ((size_t)(unsigned)t1 << 9) + loff);
            }
            float2 evp = unpack2(qc.x);             // {EV, P}
            den += evp.x; num += evp.y;
            float2 ao_o = unpack2(qc.y);            // {AO, OFF}
            if (isUser) {
                if (tc >= NU) {
                    if (tc < NU + NI) { s_i += ao_o.x; m_i = fminf(m_i, ao_o.y); c_i++; }
                    else              { s_u += ao_o.x; m_u = fmaxf(m_u, ao_o.y); c_u++; }
                }
            } else {
                s_i += ao_o.x; c_i++;
                m_i = entMin ? fminf(m_i, ao_o.y) : fmaxf(m_i, ao_o.y);
            }
        }
    }
    // center: softmax-weighted mean + row L2 normalize
    float v = (den > 0.f) ? num / den : 0.f;
    float sq = v * v;
    #pragma unroll
    for (int m = 32; m; m >>= 1) sq += __shfl_xor(sq, m, 64);
    v = v / fmaxf(sqrtf(sq), 1e-12f);

    if (isUser) {
        embOutU[(size_t)h * 64 + lane] = v;
        size_t r = (size_t)h * 64 + lane;
        meanI[r] = (_Float16)(s_i / fmaxf((float)c_i, 1.f));
        redI[r]  = (_Float16)((m_i > 1e37f) ? 0.f : m_i);
        meanU[r] = (_Float16)(s_u / fmaxf((float)c_u, 1.f));
        redU[r]  = (_Float16)m_u;
    } else {
        embOutE[(size_t)(h - NU) * 64 + lane] = v;
        size_t r = (size_t)(h - NU) * 64 + lane;
        meanE[r] = (_Float16)(s_i / fmaxf((float)c_i, 1.f));
        redE[r]  = (_Float16)((m_i > 1e37f) ? 0.f : m_i);
    }
}

// ---------------- ent offset finalize: 16 ents/wave via MFMA ----------------
__global__ __launch_bounds__(256) void ent_fin(
    const _Float16* __restrict__ meanE, const _Float16* __restrict__ redE,
    const _Float16* __restrict__ oW2f, const float* __restrict__ ob2,
    float* __restrict__ entOff)
{
    int lane = threadIdx.x & 63, wid = threadIdx.x >> 6;
    int n0 = (blockIdx.x * 4 + wid) * 16;
    if (n0 >= NENT) return;
    int lr = lane & 15, lk = lane >> 4;
    f16x4 am[4];
    #pragma unroll
    for (int ks = 0; ks < 4; ++ks) am[ks] = *(const f16x4*)(meanE + (size_t)(n0 + lr) * 64 + ks * 16 + lk * 4);
    #pragma unroll
    for (int dt = 0; dt < 4; ++dt) {
        float b = ob2[dt * 16 + lr];
        f32x4 c = {b, b, b, b};
        #pragma unroll
        for (int ks = 0; ks < 4; ++ks) c = mm(am[ks], fragp(oW2f, dt, ks, lane), c);
        #pragma unroll
        for (int r = 0; r < 4; ++r) {
            size_t row = (size_t)(n0 + lk * 4 + r);
            entOff[row * 64 + dt * 16 + lr] = (float)redE[row * 64 + dt * 16 + lr] * sigmoid_f(c[r]);
        }
    }
}

// ---------------- user offset finalize: 16 users/wave via MFMA ----------------
__global__ __launch_bounds__(256) void user_fin2(
    const _Float16* __restrict__ meanI, const _Float16* __restrict__ redI,
    const _Float16* __restrict__ meanU, const _Float16* __restrict__ redU,
    const _Float16* __restrict__ oW1f, const float* __restrict__ ob1,
    const _Float16* __restrict__ oW2f, const float* __restrict__ ob2,
    float* __restrict__ outOffU)
{
    __shared__ _Float16 tb[4][16 * 72];
    int lane = threadIdx.x & 63, wid = threadIdx.x >> 6;
    int u0 = (blockIdx.x * 4 + wid) * 16;
    if (u0 >= NU) return;
    int lr = lane & 15, lk = lane >> 4;
    _Float16* T = tb[wid];

    f16x4 W1f[4][4], W2f[4][4];
    float b1d[4], b2d[4];
    #pragma unroll
    for (int dt = 0; dt < 4; ++dt) {
        b1d[dt] = ob1[dt * 16 + lr]; b2d[dt] = ob2[dt * 16 + lr];
        #pragma unroll
        for (int ks = 0; ks < 4; ++ks) {
            W1f[dt][ks] = fragp(oW1f, dt, ks, lane);
            W2f[dt][ks] = fragp(oW2f, dt, ks, lane);
        }
    }

    f16x4 am[4];
    #pragma unroll
    for (int ks = 0; ks < 4; ++ks) am[ks] = *(const f16x4*)(meanI + (size_t)(u0 + lr) * 64 + ks * 16 + lk * 4);
    f32x4 iu[4], uu[4];
    #pragma unroll
    for (int dt = 0; dt < 4; ++dt) {
        f32x4 c = {b2d[dt], b2d[dt], b2d[dt], b2d[dt]};
        #pragma unroll
        for (int ks = 0; ks < 4; ++ks) c = mm(am[ks], W2f[dt][ks], c);
        #pragma unroll
        for (int r = 0; r < 4; ++r)
            iu[dt][r] = (float)redI[(size_t)(u0 + lk * 4 + r) * 64 + dt * 16 + lr] * sigmoid_f(c[r]);
    }
    #pragma unroll
    for (int ks = 0; ks < 4; ++ks) am[ks] = *(const f16x4*)(meanU + (size_t)(u0 + lr) * 64 + ks * 16 + lk * 4);
    #pragma unroll
    for (int dt = 0; dt < 4; ++dt) {
        f32x4 c = {b2d[dt], b2d[dt], b2d[dt], b2d[dt]};
        #pragma unroll
        for (int ks = 0; ks < 4; ++ks) c = mm(am[ks], W2f[dt][ks], c);
        #pragma unroll
        for (int r = 0; r < 4; ++r)
            uu[dt][r] = (float)redU[(size_t)(u0 + lk * 4 + r) * 64 + dt * 16 + lr] * sigmoid_f(c[r]);
    }
    #pragma unroll
    for (int dt = 0; dt < 4; ++dt)
        #pragma unroll
        for (int r = 0; r < 4; ++r) T[(lk * 4 + r) * 72 + dt * 16 + lr] = (_Float16)iu[dt][r];
    #pragma unroll
    for (int ks = 0; ks < 4; ++ks) am[ks] = *(const f16x4*)(T + lr * 72 + ks * 16 + lk * 4);
    f32x4 mn[4];
    #pragma unroll
    for (int dt = 0; dt < 4; ++dt) {
        f32x4 c = {b1d[dt], b1d[dt], b1d[dt], b1d[dt]};
        #pragma unroll
        for (int ks = 0; ks < 4; ++ks) c = mm(am[ks], W1f[dt][ks], c);
        #pragma unroll
        for (int r = 0; r < 4; ++r) mn[dt][r] = fmaxf(c[r], 0.f);
    }
    #pragma unroll
    for (int dt = 0; dt < 4; ++dt)
        #pragma unroll
        for (int r = 0; r < 4; ++r) T[(lk * 4 + r) * 72 + dt * 16 + lr] = (_Float16)uu[dt][r];
    #pragma unroll
    for (int ks = 0; ks < 4; ++ks) am[ks] = *(const f16x4*)(T + lr * 72 + ks * 16 + lk * 4);
    #pragma unroll
    for (int dt = 0; dt < 4; ++dt) {
        f32x4 c = {b1d[dt], b1d[dt], b1d[dt], b1d[dt]};
        #pragma unroll
        for (int ks = 0; ks < 4; ++ks) c = mm(am[ks], W1f[dt][ks], c);
        #pragma unroll
        for (int r = 0; r < 4; ++r) mn[dt][r] = 0.5f * (mn[dt][r] + fmaxf(c[r], 0.f));
    }
    #pragma unroll
    for (int dt = 0; dt < 4; ++dt)
        #pragma unroll
        for (int r = 0; r < 4; ++r) T[(lk * 4 + r) * 72 + dt * 16 + lr] = (_Float16)mn[dt][r];
    #pragma unroll
    for (int ks = 0; ks < 4; ++ks) am[ks] = *(const f16x4*)(T + lr * 72 + ks * 16 + lk * 4);
    #pragma unroll
    for (int dt = 0; dt < 4; ++dt) {
        f32x4 c = {b2d[dt], b2d[dt], b2d[dt], b2d[dt]};
        #pragma unroll
        for (int ks = 0; ks < 4; ++ks) c = mm(am[ks], W2f[dt][ks], c);
        #pragma unroll
        for (int r = 0; r < 4; ++r)
            outOffU[(size_t)(u0 + lk * 4 + r) * 64 + dt * 16 + lr] =
                fmaxf(fmaxf(iu[dt][r], uu[dt][r]) * sigmoid_f(c[r]), 0.f);
    }
}

extern "C" void kernel_launch(void* const* d_in, const int* in_sizes, int n_in,
                              void* d_out, int out_size, void* d_ws, size_t ws_size,
                              hipStream_t stream)
{
    const float* user_emb = (const float*)d_in[0];
    const float* user_off = (const float*)d_in[1];
    const float* item_emb = (const float*)d_in[2];
    const float* item_off = (const float*)d_in[3];
    const float* cW1 = (const float*)d_in[4];
    const float* cb1 = (const float*)d_in[5];
    const float* cW2 = (const float*)d_in[6];
    const float* cb2 = (const float*)d_in[7];
    const float* oW1 = (const float*)d_in[8];
    const float* ob1 = (const float*)d_in[9];
    const float* oW2 = (const float*)d_in[10];
    const float* ob2 = (const float*)d_in[11];
    const int* head = (const int*)d_in[12];
    const int* tail = (const int*)d_in[13];
    float* out = (float*)d_out;

    float* ws = (float*)d_ws;
    const size_t SZ = (size_t)NN * 64;
    // budget ≈ 65.3M float-equiv (+8K for wpre) < 66.6M proven in R5
    float* A      = ws;                        // layer-0 emb out [NN,64]
    float* B      = A + SZ;                    // layer-0 off out [NN,64]
    uint2* packed = (uint2*)(B + SZ);          // [NN,64] fp16 quads
    _Float16* meanI_h = (_Float16*)(packed + SZ);   // [NU,64] f16
    _Float16* redI_h  = meanI_h + (size_t)NU * 64;
    _Float16* meanU_h = redI_h + (size_t)NU * 64;
    _Float16* redU_h  = meanU_h + (size_t)NU * 64;
    _Float16* meanE_h = redU_h + (size_t)NU * 64;   // [NENT,64] f16
    _Float16* redE_h  = meanE_h + (size_t)NENT * 64;
    _Float16* wpre    = redE_h + (size_t)NENT * 64; // 4 * 4096 f16 frag-linear tables
    int* counts   = (int*)(wpre + 4 * 4096);
    int* offsets  = counts + NN;               // NN+1
    int* cursor   = offsets + NN + 1;
    int* sorted_t = cursor + NN;               // NEDGE
    int* partials = sorted_t + NEDGE;          // SCAN_NB
    int* carries  = partials + SCAN_NB;        // SCAN_NB

    const _Float16* cW1f = wpre;
    const _Float16* cW2f = wpre + 4096;
    const _Float16* oW1f = wpre + 8192;
    const _Float16* oW2f = wpre + 12288;

    // weight prepack + CSR build (per call; layer-independent)
    prep_w<<<64, 256, 0, stream>>>(cW1, cW2, oW1, oW2, wpre);
    hipMemsetAsync(counts, 0, NN * sizeof(int), stream);
    hist_k<<<(NEDGE + 255) / 256, 256, 0, stream>>>(head, counts);
    scan_local<<<SCAN_NB, 1024, 0, stream>>>(counts, offsets, partials);
    scan_carry<<<1, 256, 0, stream>>>(partials, carries);
    scan_add<<<SCAN_NB, 1024, 0, stream>>>(offsets, carries, cursor);
    scatter_k<<<(NEDGE + 255) / 256, 256, 0, stream>>>(head, tail, cursor, sorted_t);

    for (int layer = 0; layer < 2; ++layer) {
        const float *eU, *eE, *oU, *oE;
        float *embOutU, *embOutE, *entOff, *uOffOut;
        if (layer == 0) {
            eU = user_emb; eE = item_emb; oU = user_off; oE = item_off;
            embOutU = A;               embOutE = A + (size_t)NU * 64;
            entOff  = B + (size_t)NU * 64;
            uOffOut = B;
        } else {
            eU = A; eE = A + (size_t)NU * 64; oU = B; oE = B + (size_t)NU * 64;
            embOutU = out;             embOutE = out + (size_t)2 * NU * 64;
            entOff  = out + ((size_t)2 * NU + NENT) * 64;
            uOffOut = out + (size_t)NU * 64;
        }
        node_pass<<<(NN + 63) / 64, 256, 0, stream>>>(eU, eE, oU, oE,
                                                      cW1f, cb1, cW2f, cb2, oW1f, ob1, packed);
        seg_pass<<<(NN + 15) / 16, 1024, 0, stream>>>(packed, offsets, sorted_t,
                                                      embOutU, embOutE,
                                                      meanI_h, redI_h, meanU_h, redU_h,
                                                      meanE_h, redE_h);
        ent_fin<<<(NENT / 16 + 3) / 4, 256, 0, stream>>>(meanE_h, redE_h, oW2f, ob2, entOff);
        user_fin2<<<(NU + 63) / 64, 256, 0, stream>>>(meanI_h, redI_h, meanU_h, redU_h,
                                                      oW1f, ob1, oW2f, ob2, uOffOut);
    }
}

// Round 10
// 444.495 us; speedup vs baseline: 23.7882x; 1.0728x over previous
//
#include <hip/hip_runtime.h>
#include <hip/hip_fp16.h>
#include <math.h>

#define NU 100000
#define NI 50000
#define NENT 80000
#define NN 180000
#define NEDGE 800000
#define SCAN_NB ((NN + 1023) / 1024)   // 176

typedef _Float16 f16x4 __attribute__((ext_vector_type(4)));
typedef _Float16 f16x2 __attribute__((ext_vector_type(2)));
typedef float f32x4 __attribute__((ext_vector_type(4)));

__device__ __forceinline__ float sigmoid_f(float x) { return 1.0f / (1.0f + __expf(-x)); }
__device__ __forceinline__ unsigned pack2(float a, float b) {
    __half2 h = __floats2half2_rn(a, b);
    return *(unsigned*)&h;
}
__device__ __forceinline__ f16x2 u2h2(unsigned u) { union { unsigned u; f16x2 h; } x; x.u = u; return x.h; }
__device__ __forceinline__ float fdot2f(f16x2 a, f16x2 b, float c) {
#if __has_builtin(__builtin_amdgcn_fdot2)
    return __builtin_amdgcn_fdot2(a, b, c, false);
#else
    return (float)a[0] * (float)b[0] + (float)a[1] * (float)b[1] + c;
#endif
}
__device__ __forceinline__ _Float16 hminf(_Float16 a, _Float16 b) { return a < b ? a : b; }
__device__ __forceinline__ _Float16 hmaxf(_Float16 a, _Float16 b) { return a > b ? a : b; }
__device__ __forceinline__ f16x4 frag4(const float* __restrict__ p) {
    float4 v = *(const float4*)p;
    f16x4 r; r[0] = (_Float16)v.x; r[1] = (_Float16)v.y; r[2] = (_Float16)v.z; r[3] = (_Float16)v.w;
    return r;
}
__device__ __forceinline__ f16x4 frag4r(const float* __restrict__ p) {   // relu before cvt
    float4 v = *(const float4*)p;
    f16x4 r;
    r[0] = (_Float16)fmaxf(v.x, 0.f); r[1] = (_Float16)fmaxf(v.y, 0.f);
    r[2] = (_Float16)fmaxf(v.z, 0.f); r[3] = (_Float16)fmaxf(v.w, 0.f);
    return r;
}
// prepacked weight frag: coalesced 8B/lane from an L1-resident 8KB table
__device__ __forceinline__ f16x4 fragp(const _Float16* __restrict__ Wp, int dt, int ks, int lane) {
    return *(const f16x4*)(Wp + (((dt * 4 + ks) * 64 + lane) << 2));
}
__device__ __forceinline__ f32x4 mm(f16x4 a, f16x4 b, f32x4 c) {
    return __builtin_amdgcn_mfma_f32_16x16x16f16(a, b, c, 0, 0, 0);
}

// ---------------- weight prepack: f32 row-major -> frag-linear f16 ----------------
__global__ __launch_bounds__(256) void prep_w(
    const float* __restrict__ W0, const float* __restrict__ W1,
    const float* __restrict__ W2, const float* __restrict__ W3,
    _Float16* __restrict__ out)
{
    int idx = blockIdx.x * 256 + threadIdx.x;          // 0 .. 16383
    int mat = idx >> 12, wi = idx & 4095;
    const float* W = (mat == 0) ? W0 : (mat == 1) ? W1 : (mat == 2) ? W2 : W3;
    int tile = wi >> 8;            // dt*4+ks
    int dt = tile >> 2, ks = tile & 3;
    int ln = (wi >> 2) & 63, j = wi & 3;
    int lr = ln & 15, lk = ln >> 4;
    out[idx] = (_Float16)W[(size_t)(dt * 16 + lr) * 64 + ks * 16 + lk * 4 + j];
}

// ---------------- node pass: 16 nodes/wave via MFMA; writes packed fp16 quad {EV,P,AO,OFF} ----
__global__ __launch_bounds__(256) void node_pass(
    const float* __restrict__ embU, const float* __restrict__ embE,
    const float* __restrict__ offU, const float* __restrict__ offE,
    const _Float16* __restrict__ cW1f, const float* __restrict__ cb1,
    const _Float16* __restrict__ cW2f, const float* __restrict__ cb2,
    const _Float16* __restrict__ oW1f, const float* __restrict__ ob1,
    uint2* __restrict__ packed)
{
    __shared__ _Float16 tb[4][16 * 72];   // per-wave transpose tile, +8 f16 pad
    int lane = threadIdx.x & 63, wid = threadIdx.x >> 6;
    int n0 = (blockIdx.x * 4 + wid) * 16;
    if (n0 >= NN) return;
    int lr = lane & 15, lk = lane >> 4;
    const float* eb; const float* ob;
    if (n0 < NU) { eb = embU + (size_t)n0 * 64; ob = offU + (size_t)n0 * 64; }
    else         { eb = embE + (size_t)(n0 - NU) * 64; ob = offE + (size_t)(n0 - NU) * 64; }

    // ---- center net: a1 = relu(W1 x + b1) ----
    f16x4 ax[4];
    #pragma unroll
    for (int ks = 0; ks < 4; ++ks) ax[ks] = frag4(eb + (size_t)lr * 64 + ks * 16 + lk * 4);
    f32x4 acc[4];
    #pragma unroll
    for (int dt = 0; dt < 4; ++dt) {
        float b = cb1[dt * 16 + lr];
        f32x4 c = {b, b, b, b};
        #pragma unroll
        for (int ks = 0; ks < 4; ++ks) c = mm(ax[ks], fragp(cW1f, dt, ks, lane), c);
        acc[dt] = c;
    }
    _Float16* T = tb[wid];
    #pragma unroll
    for (int dt = 0; dt < 4; ++dt)
        #pragma unroll
        for (int r = 0; r < 4; ++r)
            T[(lk * 4 + r) * 72 + dt * 16 + lr] = (_Float16)fmaxf(acc[dt][r], 0.f);
    f16x4 a1[4];
    #pragma unroll
    for (int ks = 0; ks < 4; ++ks) a1[ks] = *(const f16x4*)(T + lr * 72 + ks * 16 + lk * 4);
    #pragma unroll
    for (int dt = 0; dt < 4; ++dt) {
        float b = cb2[dt * 16 + lr];
        f32x4 c = {b, b, b, b};
        #pragma unroll
        for (int ks = 0; ks < 4; ++ks) c = mm(a1[ks], fragp(cW2f, dt, ks, lane), c);
        acc[dt] = c;
    }
    // ---- offset net: ao = relu(O1 relu(o) + ob1) ----
    f16x4 axo[4];
    #pragma unroll
    for (int ks = 0; ks < 4; ++ks) axo[ks] = frag4r(ob + (size_t)lr * 64 + ks * 16 + lk * 4);
    f32x4 acco[4];
    #pragma unroll
    for (int dt = 0; dt < 4; ++dt) {
        float b = ob1[dt * 16 + lr];
        f32x4 c = {b, b, b, b};
        #pragma unroll
        for (int ks = 0; ks < 4; ++ks) c = mm(axo[ks], fragp(oW1f, dt, ks, lane), c);
        acco[dt] = c;
    }
    // ---- transpose x to D-layout via T (wave-private sequential reuse; no barrier) ----
    #pragma unroll
    for (int ks = 0; ks < 4; ++ks) *(f16x4*)(T + lr * 72 + ks * 16 + lk * 4) = ax[ks];
    _Float16 xv[16];
    #pragma unroll
    for (int dt = 0; dt < 4; ++dt)
        #pragma unroll
        for (int r = 0; r < 4; ++r) xv[dt * 4 + r] = T[(lk * 4 + r) * 72 + dt * 16 + lr];
    // ---- transpose relu(o) similarly ----
    #pragma unroll
    for (int ks = 0; ks < 4; ++ks) *(f16x4*)(T + lr * 72 + ks * 16 + lk * 4) = axo[ks];
    #pragma unroll
    for (int dt = 0; dt < 4; ++dt) {
        #pragma unroll
        for (int r = 0; r < 4; ++r) {
            int li = lk * 4 + r;
            float ev = __expf(acc[dt][r]);   // segment-max shift skipped: |lg| << 1
            float xf = (float)xv[dt * 4 + r];
            float ovf = (float)T[(lk * 4 + r) * 72 + dt * 16 + lr];
            float aov = fmaxf(acco[dt][r], 0.f);
            packed[(size_t)(n0 + li) * 64 + dt * 16 + lr] = make_uint2(pack2(ev, ev * xf), pack2(aov, ovf));
        }
    }
}

// ---------------- CSR build ----------------
__global__ __launch_bounds__(256) void hist_k(const int* __restrict__ head, int* __restrict__ counts) {
    int e = blockIdx.x * 256 + threadIdx.x;
    if (e < NEDGE) atomicAdd(&counts[head[e]], 1);
}

__global__ __launch_bounds__(1024) void scan_local(const int* __restrict__ counts,
                                                   int* __restrict__ excl, int* __restrict__ partials) {
    __shared__ int wsum[16];
    int tid = threadIdx.x, lane = tid & 63, wid = tid >> 6;
    int i = blockIdx.x * 1024 + tid;
    int v = (i < NN) ? counts[i] : 0;
    int s = v;
    #pragma unroll
    for (int d = 1; d < 64; d <<= 1) { int u = __shfl_up(s, d, 64); if (lane >= d) s += u; }
    if (lane == 63) wsum[wid] = s;
    __syncthreads();
    if (wid == 0 && lane < 16) {
        int w = wsum[lane];
        #pragma unroll
        for (int d = 1; d < 16; d <<= 1) { int u = __shfl_up(w, d, 64); if (lane >= d) w += u; }
        wsum[lane] = w;
    }
    __syncthreads();
    int base = wid ? wsum[wid - 1] : 0;
    if (i < NN) excl[i] = base + s - v;
    if (tid == 1023) partials[blockIdx.x] = wsum[15];
}

__global__ __launch_bounds__(256) void scan_carry(const int* __restrict__ partials, int* __restrict__ carries) {
    __shared__ int ws[4];
    int tid = threadIdx.x, lane = tid & 63, wid = tid >> 6;
    int v = (tid < SCAN_NB) ? partials[tid] : 0;
    int s = v;
    #pragma unroll
    for (int d = 1; d < 64; d <<= 1) { int u = __shfl_up(s, d, 64); if (lane >= d) s += u; }
    if (lane == 63) ws[wid] = s;
    __syncthreads();
    int add = 0;
    for (int w = 0; w < wid; ++w) add += ws[w];
    if (tid < SCAN_NB) carries[tid] = add + s - v;
}

__global__ __launch_bounds__(1024) void scan_add(int* __restrict__ excl, const int* __restrict__ carries,
                                                 int* __restrict__ cursor) {
    int i = blockIdx.x * 1024 + threadIdx.x;
    if (i < NN) { int o = excl[i] + carries[blockIdx.x]; excl[i] = o; cursor[i] = o; }
    if (i == 0) excl[NN] = NEDGE;
}

__global__ __launch_bounds__(256) void scatter_k(const int* __restrict__ head, const int* __restrict__ tail,
                                                 int* __restrict__ cursor, int* __restrict__ sorted_t) {
    int e = blockIdx.x * 256 + threadIdx.x;
    if (e < NEDGE) { int pos = atomicAdd(&cursor[head[e]], 1); sorted_t[pos] = tail[e]; }
}

// ---------------- segment pass: one wave per head; dot2/f16-min edge math ----------------
__global__ __launch_bounds__(256) void seg_pass(
    const uint2* __restrict__ packed,
    const int* __restrict__ offsets, const int* __restrict__ sorted_t,
    float* __restrict__ embOutU, float* __restrict__ embOutE,
    _Float16* __restrict__ meanI, _Float16* __restrict__ redI,
    _Float16* __restrict__ meanU, _Float16* __restrict__ redU,
    _Float16* __restrict__ meanE, _Float16* __restrict__ redE)
{
    int lane = threadIdx.x & 63;
    int h = blockIdx.x * 4 + (threadIdx.x >> 6);    // NN % 4 == 0
    int beg = offsets[h], end = offsets[h + 1];
    bool isUser = (h < NU);
    bool entMin = (h >= NU + NI);
    const f16x2 SEL_LO = {(_Float16)1.0f, (_Float16)0.0f};
    const f16x2 SEL_HI = {(_Float16)0.0f, (_Float16)1.0f};
    float num = 0.f, den = 0.f, s_i = 0.f, s_u = 0.f;
    const _Float16 HINF = u2h2(0x7C007C00u)[0];
    _Float16 m_i = (isUser || entMin) ? HINF : (_Float16)0.f;   // min classes start at +inf
    _Float16 m_u = (_Float16)0.f;
    int c_i = 0, c_u = 0;

    const char* pbase = (const char*)packed;
    int loff = lane << 3;
    for (int base = beg; base < end; base += 64) {
        int rem = end - base; if (rem > 64) rem = 64;
        int tv = sorted_t[base + (lane < rem ? lane : 0)];
        int t0 = __builtin_amdgcn_readlane(tv, 0);
        uint2 q0 = *(const uint2*)(pbase + ((size_t)(unsigned)t0 << 9) + loff);
        int t1 = t0; uint2 q1 = q0;
        if (rem > 1) {
            t1 = __builtin_amdgcn_readlane(tv, 1);
            q1 = *(const uint2*)(pbase + ((size_t)(unsigned)t1 << 9) + loff);
        }
        for (int j = 0; j < rem; ++j) {
            int tc = t0; uint2 qc = q0;
            t0 = t1; q0 = q1;
            if (j + 2 < rem) {
                t1 = __builtin_amdgcn_readlane(tv, j + 2);
                q1 = *(const uint2*)(pbase + ((size_t)(unsigned)t1 << 9) + loff);
            }
            f16x2 evp = u2h2(qc.x);                  // {EV, P}
            den = fdot2f(evp, SEL_LO, den);
            num = fdot2f(evp, SEL_HI, num);
            f16x2 aoo = u2h2(qc.y);                  // {AO, OFF}
            if (isUser) {
                if (tc >= NU) {                      // tc uniform -> scalar branch
                    if (tc < NU + NI) { s_i = fdot2f(aoo, SEL_LO, s_i); m_i = hminf(m_i, aoo[1]); c_i++; }
                    else              { s_u = fdot2f(aoo, SEL_LO, s_u); m_u = hmaxf(m_u, aoo[1]); c_u++; }
                }
            } else {
                s_i = fdot2f(aoo, SEL_LO, s_i); c_i++;
                m_i = entMin ? hminf(m_i, aoo[1]) : hmaxf(m_i, aoo[1]);
            }
        }
    }
    // center: softmax-weighted mean + row L2 normalize
    float v = (den > 0.f) ? num / den : 0.f;
    float sq = v * v;
    #pragma unroll
    for (int m = 32; m; m >>= 1) sq += __shfl_xor(sq, m, 64);
    v = v / fmaxf(sqrtf(sq), 1e-12f);

    float m_if = (float)m_i;
    if (m_if > 1e37f) m_if = 0.f;                   // empty min-segment -> 0
    float rc_i = __builtin_amdgcn_rcpf(fmaxf((float)c_i, 1.f));
    if (isUser) {
        embOutU[(size_t)h * 64 + lane] = v;
        size_t r = (size_t)h * 64 + lane;
        float rc_u = __builtin_amdgcn_rcpf(fmaxf((float)c_u, 1.f));
        meanI[r] = (_Float16)(s_i * rc_i);
        redI[r]  = (_Float16)m_if;
        meanU[r] = (_Float16)(s_u * rc_u);
        redU[r]  = m_u;
    } else {
        embOutE[(size_t)(h - NU) * 64 + lane] = v;
        size_t r = (size_t)(h - NU) * 64 + lane;
        meanE[r] = (_Float16)(s_i * rc_i);
        redE[r]  = (_Float16)m_if;
    }
}

// ---------------- ent offset finalize: 16 ents/wave via MFMA ----------------
__global__ __launch_bounds__(256) void ent_fin(
    const _Float16* __restrict__ meanE, const _Float16* __restrict__ redE,
    const _Float16* __restrict__ oW2f, const float* __restrict__ ob2,
    float* __restrict__ entOff)
{
    int lane = threadIdx.x & 63, wid = threadIdx.x >> 6;
    int n0 = (blockIdx.x * 4 + wid) * 16;
    if (n0 >= NENT) return;
    int lr = lane & 15, lk = lane >> 4;
    f16x4 am[4];
    #pragma unroll
    for (int ks = 0; ks < 4; ++ks) am[ks] = *(const f16x4*)(meanE + (size_t)(n0 + lr) * 64 + ks * 16 + lk * 4);
    #pragma unroll
    for (int dt = 0; dt < 4; ++dt) {
        float b = ob2[dt * 16 + lr];
        f32x4 c = {b, b, b, b};
        #pragma unroll
        for (int ks = 0; ks < 4; ++ks) c = mm(am[ks], fragp(oW2f, dt, ks, lane), c);
        #pragma unroll
        for (int r = 0; r < 4; ++r) {
            size_t row = (size_t)(n0 + lk * 4 + r);
            entOff[row * 64 + dt * 16 + lr] = (float)redE[row * 64 + dt * 16 + lr] * sigmoid_f(c[r]);
        }
    }
}

// ---------------- user offset finalize: 16 users/wave via MFMA ----------------
__global__ __launch_bounds__(256) void user_fin2(
    const _Float16* __restrict__ meanI, const _Float16* __restrict__ redI,
    const _Float16* __restrict__ meanU, const _Float16* __restrict__ redU,
    const _Float16* __restrict__ oW1f, const float* __restrict__ ob1,
    const _Float16* __restrict__ oW2f, const float* __restrict__ ob2,
    float* __restrict__ outOffU)
{
    __shared__ _Float16 tb[4][16 * 72];
    int lane = threadIdx.x & 63, wid = threadIdx.x >> 6;
    int u0 = (blockIdx.x * 4 + wid) * 16;
    if (u0 >= NU) return;
    int lr = lane & 15, lk = lane >> 4;
    _Float16* T = tb[wid];

    f16x4 W1f[4][4], W2f[4][4];
    float b1d[4], b2d[4];
    #pragma unroll
    for (int dt = 0; dt < 4; ++dt) {
        b1d[dt] = ob1[dt * 16 + lr]; b2d[dt] = ob2[dt * 16 + lr];
        #pragma unroll
        for (int ks = 0; ks < 4; ++ks) {
            W1f[dt][ks] = fragp(oW1f, dt, ks, lane);
            W2f[dt][ks] = fragp(oW2f, dt, ks, lane);
        }
    }

    f16x4 am[4];
    #pragma unroll
    for (int ks = 0; ks < 4; ++ks) am[ks] = *(const f16x4*)(meanI + (size_t)(u0 + lr) * 64 + ks * 16 + lk * 4);
    f32x4 iu[4], uu[4];
    #pragma unroll
    for (int dt = 0; dt < 4; ++dt) {
        f32x4 c = {b2d[dt], b2d[dt], b2d[dt], b2d[dt]};
        #pragma unroll
        for (int ks = 0; ks < 4; ++ks) c = mm(am[ks], W2f[dt][ks], c);
        #pragma unroll
        for (int r = 0; r < 4; ++r)
            iu[dt][r] = (float)redI[(size_t)(u0 + lk * 4 + r) * 64 + dt * 16 + lr] * sigmoid_f(c[r]);
    }
    #pragma unroll
    for (int ks = 0; ks < 4; ++ks) am[ks] = *(const f16x4*)(meanU + (size_t)(u0 + lr) * 64 + ks * 16 + lk * 4);
    #pragma unroll
    for (int dt = 0; dt < 4; ++dt) {
        f32x4 c = {b2d[dt], b2d[dt], b2d[dt], b2d[dt]};
        #pragma unroll
        for (int ks = 0; ks < 4; ++ks) c = mm(am[ks], W2f[dt][ks], c);
        #pragma unroll
        for (int r = 0; r < 4; ++r)
            uu[dt][r] = (float)redU[(size_t)(u0 + lk * 4 + r) * 64 + dt * 16 + lr] * sigmoid_f(c[r]);
    }
    #pragma unroll
    for (int dt = 0; dt < 4; ++dt)
        #pragma unroll
        for (int r = 0; r < 4; ++r) T[(lk * 4 + r) * 72 + dt * 16 + lr] = (_Float16)iu[dt][r];
    #pragma unroll
    for (int ks = 0; ks < 4; ++ks) am[ks] = *(const f16x4*)(T + lr * 72 + ks * 16 + lk * 4);
    f32x4 mn[4];
    #pragma unroll
    for (int dt = 0; dt < 4; ++dt) {
        f32x4 c = {b1d[dt], b1d[dt], b1d[dt], b1d[dt]};
        #pragma unroll
        for (int ks = 0; ks < 4; ++ks) c = mm(am[ks], W1f[dt][ks], c);
        #pragma unroll
        for (int r = 0; r < 4; ++r) mn[dt][r] = fmaxf(c[r], 0.f);
    }
    #pragma unroll
    for (int dt = 0; dt < 4; ++dt)
        #pragma unroll
        for (int r = 0; r < 4; ++r) T[(lk * 4 + r) * 72 + dt * 16 + lr] = (_Float16)uu[dt][r];
    #pragma unroll
    for (int ks = 0; ks < 4; ++ks) am[ks] = *(const f16x4*)(T + lr * 72 + ks * 16 + lk * 4);
    #pragma unroll
    for (int dt = 0; dt < 4; ++dt) {
        f32x4 c = {b1d[dt], b1d[dt], b1d[dt], b1d[dt]};
        #pragma unroll
        for (int ks = 0; ks < 4; ++ks) c = mm(am[ks], W1f[dt][ks], c);
        #pragma unroll
        for (int r = 0; r < 4; ++r) mn[dt][r] = 0.5f * (mn[dt][r] + fmaxf(c[r], 0.f));
    }
    #pragma unroll
    for (int dt = 0; dt < 4; ++dt)
        #pragma unroll
        for (int r = 0; r < 4; ++r) T[(lk * 4 + r) * 72 + dt * 16 + lr] = (_Float16)mn[dt][r];
    #pragma unroll
    for (int ks = 0; ks < 4; ++ks) am[ks] = *(const f16x4*)(T + lr * 72 + ks * 16 + lk * 4);
    #pragma unroll
    for (int dt = 0; dt < 4; ++dt) {
        f32x4 c = {b2d[dt], b2d[dt], b2d[dt], b2d[dt]};
        #pragma unroll
        for (int ks = 0; ks < 4; ++ks) c = mm(am[ks], W2f[dt][ks], c);
        #pragma unroll
        for (int r = 0; r < 4; ++r)
            outOffU[(size_t)(u0 + lk * 4 + r) * 64 + dt * 16 + lr] =
                fmaxf(fmaxf(iu[dt][r], uu[dt][r]) * sigmoid_f(c[r]), 0.f);
    }
}

extern "C" void kernel_launch(void* const* d_in, const int* in_sizes, int n_in,
                              void* d_out, int out_size, void* d_ws, size_t ws_size,
                              hipStream_t stream)
{
    const float* user_emb = (const float*)d_in[0];
    const float* user_off = (const float*)d_in[1];
    const float* item_emb = (const float*)d_in[2];
    const float* item_off = (const float*)d_in[3];
    const float* cW1 = (const float*)d_in[4];
    const float* cb1 = (const float*)d_in[5];
    const float* cW2 = (const float*)d_in[6];
    const float* cb2 = (const float*)d_in[7];
    const float* oW1 = (const float*)d_in[8];
    const float* ob1 = (const float*)d_in[9];
    const float* oW2 = (const float*)d_in[10];
    const float* ob2 = (const float*)d_in[11];
    const int* head = (const int*)d_in[12];
    const int* tail = (const int*)d_in[13];
    float* out = (float*)d_out;

    float* ws = (float*)d_ws;
    const size_t SZ = (size_t)NN * 64;
    // budget ≈ 65.3M float-equiv (+8K for wpre) < 66.6M proven in R5
    float* A      = ws;                        // layer-0 emb out [NN,64]
    float* B      = A + SZ;                    // layer-0 off out [NN,64]
    uint2* packed = (uint2*)(B + SZ);          // [NN,64] fp16 quads
    _Float16* meanI_h = (_Float16*)(packed + SZ);   // [NU,64] f16
    _Float16* redI_h  = meanI_h + (size_t)NU * 64;
    _Float16* meanU_h = redI_h + (size_t)NU * 64;
    _Float16* redU_h  = meanU_h + (size_t)NU * 64;
    _Float16* meanE_h = redU_h + (size_t)NU * 64;   // [NENT,64] f16
    _Float16* redE_h  = meanE_h + (size_t)NENT * 64;
    _Float16* wpre    = redE_h + (size_t)NENT * 64; // 4 * 4096 f16 frag-linear tables
    int* counts   = (int*)(wpre + 4 * 4096);
    int* offsets  = counts + NN;               // NN+1
    int* cursor   = offsets + NN + 1;
    int* sorted_t = cursor + NN;               // NEDGE
    int* partials = sorted_t + NEDGE;          // SCAN_NB
    int* carries  = partials + SCAN_NB;        // SCAN_NB

    const _Float16* cW1f = wpre;
    const _Float16* cW2f = wpre + 4096;
    const _Float16* oW1f = wpre + 8192;
    const _Float16* oW2f = wpre + 12288;

    // weight prepack + CSR build (per call; layer-independent)
    prep_w<<<64, 256, 0, stream>>>(cW1, cW2, oW1, oW2, wpre);
    hipMemsetAsync(counts, 0, NN * sizeof(int), stream);
    hist_k<<<(NEDGE + 255) / 256, 256, 0, stream>>>(head, counts);
    scan_local<<<SCAN_NB, 1024, 0, stream>>>(counts, offsets, partials);
    scan_carry<<<1, 256, 0, stream>>>(partials, carries);
    scan_add<<<SCAN_NB, 1024, 0, stream>>>(offsets, carries, cursor);
    scatter_k<<<(NEDGE + 255) / 256, 256, 0, stream>>>(head, tail, cursor, sorted_t);

    for (int layer = 0; layer < 2; ++layer) {
        const float *eU, *eE, *oU, *oE;
        float *embOutU, *embOutE, *entOff, *uOffOut;
        if (layer == 0) {
            eU = user_emb; eE = item_emb; oU = user_off; oE = item_off;
            embOutU = A;               embOutE = A + (size_t)NU * 64;
            entOff  = B + (size_t)NU * 64;
            uOffOut = B;
        } else {
            eU = A; eE = A + (size_t)NU * 64; oU = B; oE = B + (size_t)NU * 64;
            embOutU = out;             embOutE = out + (size_t)2 * NU * 64;
            entOff  = out + ((size_t)2 * NU + NENT) * 64;
            uOffOut = out + (size_t)NU * 64;
        }
        node_pass<<<(NN + 63) / 64, 256, 0, stream>>>(eU, eE, oU, oE,
                                                      cW1f, cb1, cW2f, cb2, oW1f, ob1, packed);
        seg_pass<<<NN / 4, 256, 0, stream>>>(packed, offsets, sorted_t,
                                             embOutU, embOutE,
                                             meanI_h, redI_h, meanU_h, redU_h,
                                             meanE_h, redE_h);
        ent_fin<<<(NENT / 16 + 3) / 4, 256, 0, stream>>>(meanE_h, redE_h, oW2f, ob2, entOff);
        user_fin2<<<(NU + 63) / 64, 256, 0, stream>>>(meanI_h, redI_h, meanU_h, redU_h,
                                                      oW1f, ob1, oW2f, ob2, uOffOut);
    }
}

// Round 11
// 436.211 us; speedup vs baseline: 24.2400x; 1.0190x over previous
//
#include <hip/hip_runtime.h>
#include <hip/hip_fp16.h>
#include <math.h>

#define NU 100000
#define NI 50000
#define NENT 80000
#define NN 180000
#define NEDGE 800000
#define SCAN_NB ((NN + 1023) / 1024)   // 176

typedef _Float16 f16x4 __attribute__((ext_vector_type(4)));
typedef _Float16 f16x2 __attribute__((ext_vector_type(2)));
typedef float f32x4 __attribute__((ext_vector_type(4)));

__device__ __forceinline__ float sigmoid_f(float x) { return 1.0f / (1.0f + __expf(-x)); }
__device__ __forceinline__ unsigned pack2(float a, float b) {
    __half2 h = __floats2half2_rn(a, b);
    return *(unsigned*)&h;
}
__device__ __forceinline__ f16x2 u2h2(unsigned u) { union { unsigned u; f16x2 h; } x; x.u = u; return x.h; }
__device__ __forceinline__ float fdot2f(f16x2 a, f16x2 b, float c) {
#if __has_builtin(__builtin_amdgcn_fdot2)
    return __builtin_amdgcn_fdot2(a, b, c, false);
#else
    return (float)a[0] * (float)b[0] + (float)a[1] * (float)b[1] + c;
#endif
}
__device__ __forceinline__ _Float16 hminf(_Float16 a, _Float16 b) { return a < b ? a : b; }
__device__ __forceinline__ _Float16 hmaxf(_Float16 a, _Float16 b) { return a > b ? a : b; }

// frag load (f32: convert; f16: direct)
template<typename T>
__device__ __forceinline__ f16x4 ldfrag(const T* __restrict__ p) {
    if constexpr (sizeof(T) == 2) {
        return *(const f16x4*)p;
    } else {
        float4 v = *(const float4*)p;
        f16x4 r; r[0] = (_Float16)v.x; r[1] = (_Float16)v.y; r[2] = (_Float16)v.z; r[3] = (_Float16)v.w;
        return r;
    }
}
template<typename T>
__device__ __forceinline__ f16x4 ldfragr(const T* __restrict__ p) {   // relu before/after cvt
    if constexpr (sizeof(T) == 2) {
        f16x4 v = *(const f16x4*)p;
        #pragma unroll
        for (int i = 0; i < 4; ++i) v[i] = hmaxf(v[i], (_Float16)0.f);
        return v;
    } else {
        float4 v = *(const float4*)p;
        f16x4 r;
        r[0] = (_Float16)fmaxf(v.x, 0.f); r[1] = (_Float16)fmaxf(v.y, 0.f);
        r[2] = (_Float16)fmaxf(v.z, 0.f); r[3] = (_Float16)fmaxf(v.w, 0.f);
        return r;
    }
}
// prepacked weight frag: coalesced 8B/lane from an L1-resident 8KB table
__device__ __forceinline__ f16x4 fragp(const _Float16* __restrict__ Wp, int dt, int ks, int lane) {
    return *(const f16x4*)(Wp + (((dt * 4 + ks) * 64 + lane) << 2));
}
__device__ __forceinline__ f32x4 mm(f16x4 a, f16x4 b, f32x4 c) {
    return __builtin_amdgcn_mfma_f32_16x16x16f16(a, b, c, 0, 0, 0);
}

// ---------------- weight prepack: f32 row-major -> frag-linear f16 ----------------
__global__ __launch_bounds__(256) void prep_w(
    const float* __restrict__ W0, const float* __restrict__ W1,
    const float* __restrict__ W2, const float* __restrict__ W3,
    _Float16* __restrict__ out)
{
    int idx = blockIdx.x * 256 + threadIdx.x;          // 0 .. 16383
    int mat = idx >> 12, wi = idx & 4095;
    const float* W = (mat == 0) ? W0 : (mat == 1) ? W1 : (mat == 2) ? W2 : W3;
    int tile = wi >> 8;            // dt*4+ks
    int dt = tile >> 2, ks = tile & 3;
    int ln = (wi >> 2) & 63, j = wi & 3;
    int lr = ln & 15, lk = ln >> 4;
    out[idx] = (_Float16)W[(size_t)(dt * 16 + lr) * 64 + ks * 16 + lk * 4 + j];
}

// ---------------- node pass: 16 nodes/wave via MFMA; writes split f16 pairs ----------------
template<typename T>
__global__ __launch_bounds__(256) void node_pass(
    const T* __restrict__ embU, const T* __restrict__ embE,
    const T* __restrict__ offU, const T* __restrict__ offE,
    const _Float16* __restrict__ cW1f, const float* __restrict__ cb1,
    const _Float16* __restrict__ cW2f, const float* __restrict__ cb2,
    const _Float16* __restrict__ oW1f, const float* __restrict__ ob1,
    unsigned* __restrict__ packedA, unsigned* __restrict__ packedB)
{
    __shared__ _Float16 tb[4][16 * 72];   // per-wave transpose tile, +8 f16 pad
    int lane = threadIdx.x & 63, wid = threadIdx.x >> 6;
    int n0 = (blockIdx.x * 4 + wid) * 16;
    if (n0 >= NN) return;
    int lr = lane & 15, lk = lane >> 4;
    const T* eb; const T* ob;
    if (n0 < NU) { eb = embU + (size_t)n0 * 64; ob = offU + (size_t)n0 * 64; }
    else         { eb = embE + (size_t)(n0 - NU) * 64; ob = offE + (size_t)(n0 - NU) * 64; }

    // ---- center net: a1 = relu(W1 x + b1) ----
    f16x4 ax[4];
    #pragma unroll
    for (int ks = 0; ks < 4; ++ks) ax[ks] = ldfrag(eb + (size_t)lr * 64 + ks * 16 + lk * 4);
    f32x4 acc[4];
    #pragma unroll
    for (int dt = 0; dt < 4; ++dt) {
        float b = cb1[dt * 16 + lr];
        f32x4 c = {b, b, b, b};
        #pragma unroll
        for (int ks = 0; ks < 4; ++ks) c = mm(ax[ks], fragp(cW1f, dt, ks, lane), c);
        acc[dt] = c;
    }
    _Float16* T16 = tb[wid];
    #pragma unroll
    for (int dt = 0; dt < 4; ++dt)
        #pragma unroll
        for (int r = 0; r < 4; ++r)
            T16[(lk * 4 + r) * 72 + dt * 16 + lr] = (_Float16)fmaxf(acc[dt][r], 0.f);
    f16x4 a1[4];
    #pragma unroll
    for (int ks = 0; ks < 4; ++ks) a1[ks] = *(const f16x4*)(T16 + lr * 72 + ks * 16 + lk * 4);
    #pragma unroll
    for (int dt = 0; dt < 4; ++dt) {
        float b = cb2[dt * 16 + lr];
        f32x4 c = {b, b, b, b};
        #pragma unroll
        for (int ks = 0; ks < 4; ++ks) c = mm(a1[ks], fragp(cW2f, dt, ks, lane), c);
        acc[dt] = c;
    }
    // ---- offset net: ao = relu(O1 relu(o) + ob1) ----
    f16x4 axo[4];
    #pragma unroll
    for (int ks = 0; ks < 4; ++ks) axo[ks] = ldfragr(ob + (size_t)lr * 64 + ks * 16 + lk * 4);
    f32x4 acco[4];
    #pragma unroll
    for (int dt = 0; dt < 4; ++dt) {
        float b = ob1[dt * 16 + lr];
        f32x4 c = {b, b, b, b};
        #pragma unroll
        for (int ks = 0; ks < 4; ++ks) c = mm(axo[ks], fragp(oW1f, dt, ks, lane), c);
        acco[dt] = c;
    }
    // ---- transpose x to D-layout via T (wave-private sequential reuse; no barrier) ----
    #pragma unroll
    for (int ks = 0; ks < 4; ++ks) *(f16x4*)(T16 + lr * 72 + ks * 16 + lk * 4) = ax[ks];
    _Float16 xv[16];
    #pragma unroll
    for (int dt = 0; dt < 4; ++dt)
        #pragma unroll
        for (int r = 0; r < 4; ++r) xv[dt * 4 + r] = T16[(lk * 4 + r) * 72 + dt * 16 + lr];
    // ---- transpose relu(o) similarly ----
    #pragma unroll
    for (int ks = 0; ks < 4; ++ks) *(f16x4*)(T16 + lr * 72 + ks * 16 + lk * 4) = axo[ks];
    #pragma unroll
    for (int dt = 0; dt < 4; ++dt) {
        #pragma unroll
        for (int r = 0; r < 4; ++r) {
            int li = lk * 4 + r;
            float ev = __expf(acc[dt][r]);   // segment-max shift skipped: |lg| << 1
            float xf = (float)xv[dt * 4 + r];
            float ovf = (float)T16[(lk * 4 + r) * 72 + dt * 16 + lr];
            float aov = fmaxf(acco[dt][r], 0.f);
            size_t idx = (size_t)(n0 + li) * 64 + dt * 16 + lr;
            packedA[idx] = pack2(ev, ev * xf);
            packedB[idx] = pack2(aov, ovf);
        }
    }
}

// ---------------- CSR build ----------------
__global__ __launch_bounds__(256) void hist_k(const int* __restrict__ head, int* __restrict__ counts) {
    int e = blockIdx.x * 256 + threadIdx.x;
    if (e < NEDGE) atomicAdd(&counts[head[e]], 1);
}

__global__ __launch_bounds__(1024) void scan_local(const int* __restrict__ counts,
                                                   int* __restrict__ excl, int* __restrict__ partials) {
    __shared__ int wsum[16];
    int tid = threadIdx.x, lane = tid & 63, wid = tid >> 6;
    int i = blockIdx.x * 1024 + tid;
    int v = (i < NN) ? counts[i] : 0;
    int s = v;
    #pragma unroll
    for (int d = 1; d < 64; d <<= 1) { int u = __shfl_up(s, d, 64); if (lane >= d) s += u; }
    if (lane == 63) wsum[wid] = s;
    __syncthreads();
    if (wid == 0 && lane < 16) {
        int w = wsum[lane];
        #pragma unroll
        for (int d = 1; d < 16; d <<= 1) { int u = __shfl_up(w, d, 64); if (lane >= d) w += u; }
        wsum[lane] = w;
    }
    __syncthreads();
    int base = wid ? wsum[wid - 1] : 0;
    if (i < NN) excl[i] = base + s - v;
    if (tid == 1023) partials[blockIdx.x] = wsum[15];
}

__global__ __launch_bounds__(256) void scan_carry(const int* __restrict__ partials, int* __restrict__ carries) {
    __shared__ int ws[4];
    int tid = threadIdx.x, lane = tid & 63, wid = tid >> 6;
    int v = (tid < SCAN_NB) ? partials[tid] : 0;
    int s = v;
    #pragma unroll
    for (int d = 1; d < 64; d <<= 1) { int u = __shfl_up(s, d, 64); if (lane >= d) s += u; }
    if (lane == 63) ws[wid] = s;
    __syncthreads();
    int add = 0;
    for (int w = 0; w < wid; ++w) add += ws[w];
    if (tid < SCAN_NB) carries[tid] = add + s - v;
}

__global__ __launch_bounds__(1024) void scan_add(int* __restrict__ excl, const int* __restrict__ carries,
                                                 int* __restrict__ cursor) {
    int i = blockIdx.x * 1024 + threadIdx.x;
    if (i < NN) { int o = excl[i] + carries[blockIdx.x]; excl[i] = o; cursor[i] = o; }
    if (i == 0) excl[NN] = NEDGE;
}

__global__ __launch_bounds__(256) void scatter_k(const int* __restrict__ head, const int* __restrict__ tail,
                                                 int* __restrict__ cursor, int* __restrict__ sorted_t) {
    int e = blockIdx.x * 256 + threadIdx.x;
    if (e < NEDGE) { int pos = atomicAdd(&cursor[head[e]], 1); sorted_t[pos] = tail[e]; }
}

// ---------------- segment pass: one wave per head; split A/B gathers, B skipped when dead ----
template<bool OUT16>
__global__ __launch_bounds__(256) void seg_pass(
    const unsigned* __restrict__ packedA, const unsigned* __restrict__ packedB,
    const int* __restrict__ offsets, const int* __restrict__ sorted_t,
    void* __restrict__ embOutU_, void* __restrict__ embOutE_,
    _Float16* __restrict__ meanI, _Float16* __restrict__ redI,
    _Float16* __restrict__ meanU, _Float16* __restrict__ redU,
    _Float16* __restrict__ meanE, _Float16* __restrict__ redE)
{
    int lane = threadIdx.x & 63;
    int h = blockIdx.x * 4 + (threadIdx.x >> 6);    // NN % 4 == 0
    int beg = offsets[h], end = offsets[h + 1];
    bool isUser = (h < NU);
    bool entMin = (h >= NU + NI);
    const f16x2 SEL_LO = {(_Float16)1.0f, (_Float16)0.0f};
    const f16x2 SEL_HI = {(_Float16)0.0f, (_Float16)1.0f};
    float num = 0.f, den = 0.f, s_i = 0.f, s_u = 0.f;
    const _Float16 HINF = u2h2(0x7C007C00u)[0];
    _Float16 m_i = (isUser || entMin) ? HINF : (_Float16)0.f;   // min classes start at +inf
    _Float16 m_u = (_Float16)0.f;
    int c_i = 0, c_u = 0;

    const char* pA = (const char*)packedA;
    const char* pB = (const char*)packedB;
    int loff = lane << 2;
    for (int base = beg; base < end; base += 64) {
        int rem = end - base; if (rem > 64) rem = 64;
        int tv = sorted_t[base + (lane < rem ? lane : 0)];
        // depth-2 prefetch; B loaded only when consumed (wave-uniform condition)
        int t0 = __builtin_amdgcn_readlane(tv, 0);
        unsigned a0 = *(const unsigned*)(pA + ((size_t)(unsigned)t0 << 8) + loff);
        unsigned b0 = 0;
        if (!isUser || t0 >= NU) b0 = *(const unsigned*)(pB + ((size_t)(unsigned)t0 << 8) + loff);
        int t1 = t0; unsigned a1 = a0, b1 = b0;
        if (rem > 1) {
            t1 = __builtin_amdgcn_readlane(tv, 1);
            a1 = *(const unsigned*)(pA + ((size_t)(unsigned)t1 << 8) + loff);
            if (!isUser || t1 >= NU) b1 = *(const unsigned*)(pB + ((size_t)(unsigned)t1 << 8) + loff);
        }
        for (int j = 0; j < rem; ++j) {
            int tc = t0; unsigned qa = a0, qb = b0;
            t0 = t1; a0 = a1; b0 = b1;
            if (j + 2 < rem) {
                t1 = __builtin_amdgcn_readlane(tv, j + 2);
                a1 = *(const unsigned*)(pA + ((size_t)(unsigned)t1 << 8) + loff);
                if (!isUser || t1 >= NU) b1 = *(const unsigned*)(pB + ((size_t)(unsigned)t1 << 8) + loff);
            }
            f16x2 ea = u2h2(qa);                     // {EV, P}
            den = fdot2f(ea, SEL_LO, den);
            num = fdot2f(ea, SEL_HI, num);
            if (isUser) {
                if (tc >= NU) {                      // tc uniform -> scalar branch
                    f16x2 ab = u2h2(qb);             // {AO, OFF}
                    if (tc < NU + NI) { s_i = fdot2f(ab, SEL_LO, s_i); m_i = hminf(m_i, ab[1]); c_i++; }
                    else              { s_u = fdot2f(ab, SEL_LO, s_u); m_u = hmaxf(m_u, ab[1]); c_u++; }
                }
            } else {
                f16x2 ab = u2h2(qb);
                s_i = fdot2f(ab, SEL_LO, s_i); c_i++;
                m_i = entMin ? hminf(m_i, ab[1]) : hmaxf(m_i, ab[1]);
            }
        }
    }
    // center: softmax-weighted mean + row L2 normalize
    float v = (den > 0.f) ? num / den : 0.f;
    float sq = v * v;
    #pragma unroll
    for (int m = 32; m; m >>= 1) sq += __shfl_xor(sq, m, 64);
    v = v / fmaxf(sqrtf(sq), 1e-12f);

    float m_if = (float)m_i;
    if (m_if > 1e37f) m_if = 0.f;                   // empty min-segment -> 0
    float rc_i = __builtin_amdgcn_rcpf(fmaxf((float)c_i, 1.f));
    if (isUser) {
        size_t r = (size_t)h * 64 + lane;
        if constexpr (OUT16) ((_Float16*)embOutU_)[r] = (_Float16)v;
        else                 ((float*)embOutU_)[r] = v;
        float rc_u = __builtin_amdgcn_rcpf(fmaxf((float)c_u, 1.f));
        meanI[r] = (_Float16)(s_i * rc_i);
        redI[r]  = (_Float16)m_if;
        meanU[r] = (_Float16)(s_u * rc_u);
        redU[r]  = m_u;
    } else {
        size_t r = (size_t)(h - NU) * 64 + lane;
        if constexpr (OUT16) ((_Float16*)embOutE_)[r] = (_Float16)v;
        else                 ((float*)embOutE_)[r] = v;
        meanE[r] = (_Float16)(s_i * rc_i);
        redE[r]  = (_Float16)m_if;
    }
}

// ---------------- ent offset finalize: 16 ents/wave via MFMA ----------------
template<bool OUT16>
__global__ __launch_bounds__(256) void ent_fin(
    const _Float16* __restrict__ meanE, const _Float16* __restrict__ redE,
    const _Float16* __restrict__ oW2f, const float* __restrict__ ob2,
    void* __restrict__ entOff_)
{
    int lane = threadIdx.x & 63, wid = threadIdx.x >> 6;
    int n0 = (blockIdx.x * 4 + wid) * 16;
    if (n0 >= NENT) return;
    int lr = lane & 15, lk = lane >> 4;
    f16x4 am[4];
    #pragma unroll
    for (int ks = 0; ks < 4; ++ks) am[ks] = *(const f16x4*)(meanE + (size_t)(n0 + lr) * 64 + ks * 16 + lk * 4);
    #pragma unroll
    for (int dt = 0; dt < 4; ++dt) {
        float b = ob2[dt * 16 + lr];
        f32x4 c = {b, b, b, b};
        #pragma unroll
        for (int ks = 0; ks < 4; ++ks) c = mm(am[ks], fragp(oW2f, dt, ks, lane), c);
        #pragma unroll
        for (int r = 0; r < 4; ++r) {
            size_t row = (size_t)(n0 + lk * 4 + r);
            float val = (float)redE[row * 64 + dt * 16 + lr] * sigmoid_f(c[r]);
            if constexpr (OUT16) ((_Float16*)entOff_)[row * 64 + dt * 16 + lr] = (_Float16)val;
            else                 ((float*)entOff_)[row * 64 + dt * 16 + lr] = val;
        }
    }
}

// ---------------- user offset finalize: 16 users/wave via MFMA ----------------
template<bool OUT16>
__global__ __launch_bounds__(256) void user_fin2(
    const _Float16* __restrict__ meanI, const _Float16* __restrict__ redI,
    const _Float16* __restrict__ meanU, const _Float16* __restrict__ redU,
    const _Float16* __restrict__ oW1f, const float* __restrict__ ob1,
    const _Float16* __restrict__ oW2f, const float* __restrict__ ob2,
    void* __restrict__ outOffU_)
{
    __shared__ _Float16 tb[4][16 * 72];
    int lane = threadIdx.x & 63, wid = threadIdx.x >> 6;
    int u0 = (blockIdx.x * 4 + wid) * 16;
    if (u0 >= NU) return;
    int lr = lane & 15, lk = lane >> 4;
    _Float16* T16 = tb[wid];

    f16x4 W1f[4][4], W2f[4][4];
    float b1d[4], b2d[4];
    #pragma unroll
    for (int dt = 0; dt < 4; ++dt) {
        b1d[dt] = ob1[dt * 16 + lr]; b2d[dt] = ob2[dt * 16 + lr];
        #pragma unroll
        for (int ks = 0; ks < 4; ++ks) {
            W1f[dt][ks] = fragp(oW1f, dt, ks, lane);
            W2f[dt][ks] = fragp(oW2f, dt, ks, lane);
        }
    }

    f16x4 am[4];
    #pragma unroll
    for (int ks = 0; ks < 4; ++ks) am[ks] = *(const f16x4*)(meanI + (size_t)(u0 + lr) * 64 + ks * 16 + lk * 4);
    f32x4 iu[4], uu[4];
    #pragma unroll
    for (int dt = 0; dt < 4; ++dt) {
        f32x4 c = {b2d[dt], b2d[dt], b2d[dt], b2d[dt]};
        #pragma unroll
        for (int ks = 0; ks < 4; ++ks) c = mm(am[ks], W2f[dt][ks], c);
        #pragma unroll
        for (int r = 0; r < 4; ++r)
            iu[dt][r] = (float)redI[(size_t)(u0 + lk * 4 + r) * 64 + dt * 16 + lr] * sigmoid_f(c[r]);
    }
    #pragma unroll
    for (int ks = 0; ks < 4; ++ks) am[ks] = *(const f16x4*)(meanU + (size_t)(u0 + lr) * 64 + ks * 16 + lk * 4);
    #pragma unroll
    for (int dt = 0; dt < 4; ++dt) {
        f32x4 c = {b2d[dt], b2d[dt], b2d[dt], b2d[dt]};
        #pragma unroll
        for (int ks = 0; ks < 4; ++ks) c = mm(am[ks], W2f[dt][ks], c);
        #pragma unroll
        for (int r = 0; r < 4; ++r)
            uu[dt][r] = (float)redU[(size_t)(u0 + lk * 4 + r) * 64 + dt * 16 + lr] * sigmoid_f(c[r]);
    }
    #pragma unroll
    for (int dt = 0; dt < 4; ++dt)
        #pragma unroll
        for (int r = 0; r < 4; ++r) T16[(lk * 4 + r) * 72 + dt * 16 + lr] = (_Float16)iu[dt][r];
    #pragma unroll
    for (int ks = 0; ks < 4; ++ks) am[ks] = *(const f16x4*)(T16 + lr * 72 + ks * 16 + lk * 4);
    f32x4 mn[4];
    #pragma unroll
    for (int dt = 0; dt < 4; ++dt) {
        f32x4 c = {b1d[dt], b1d[dt], b1d[dt], b1d[dt]};
        #pragma unroll
        for (int ks = 0; ks < 4; ++ks) c = mm(am[ks], W1f[dt][ks], c);
        #pragma unroll
        for (int r = 0; r < 4; ++r) mn[dt][r] = fmaxf(c[r], 0.f);
    }
    #pragma unroll
    for (int dt = 0; dt < 4; ++dt)
        #pragma unroll
        for (int r = 0; r < 4; ++r) T16[(lk * 4 + r) * 72 + dt * 16 + lr] = (_Float16)uu[dt][r];
    #pragma unroll
    for (int ks = 0; ks < 4; ++ks) am[ks] = *(const f16x4*)(T16 + lr * 72 + ks * 16 + lk * 4);
    #pragma unroll
    for (int dt = 0; dt < 4; ++dt) {
        f32x4 c = {b1d[dt], b1d[dt], b1d[dt], b1d[dt]};
        #pragma unroll
        for (int ks = 0; ks < 4; ++ks) c = mm(am[ks], W1f[dt][ks], c);
        #pragma unroll
        for (int r = 0; r < 4; ++r) mn[dt][r] = 0.5f * (mn[dt][r] + fmaxf(c[r], 0.f));
    }
    #pragma unroll
    for (int dt = 0; dt < 4; ++dt)
        #pragma unroll
        for (int r = 0; r < 4; ++r) T16[(lk * 4 + r) * 72 + dt * 16 + lr] = (_Float16)mn[dt][r];
    #pragma unroll
    for (int ks = 0; ks < 4; ++ks) am[ks] = *(const f16x4*)(T16 + lr * 72 + ks * 16 + lk * 4);
    #pragma unroll
    for (int dt = 0; dt < 4; ++dt) {
        f32x4 c = {b2d[dt], b2d[dt], b2d[dt], b2d[dt]};
        #pragma unroll
        for (int ks = 0; ks < 4; ++ks) c = mm(am[ks], W2f[dt][ks], c);
        #pragma unroll
        for (int r = 0; r < 4; ++r) {
            float val = fmaxf(fmaxf(iu[dt][r], uu[dt][r]) * sigmoid_f(c[r]), 0.f);
            size_t idx = (size_t)(u0 + lk * 4 + r) * 64 + dt * 16 + lr;
            if constexpr (OUT16) ((_Float16*)outOffU_)[idx] = (_Float16)val;
            else                 ((float*)outOffU_)[idx] = val;
        }
    }
}

extern "C" void kernel_launch(void* const* d_in, const int* in_sizes, int n_in,
                              void* d_out, int out_size, void* d_ws, size_t ws_size,
                              hipStream_t stream)
{
    const float* user_emb = (const float*)d_in[0];
    const float* user_off = (const float*)d_in[1];
    const float* item_emb = (const float*)d_in[2];
    const float* item_off = (const float*)d_in[3];
    const float* cW1 = (const float*)d_in[4];
    const float* cb1 = (const float*)d_in[5];
    const float* cW2 = (const float*)d_in[6];
    const float* cb2 = (const float*)d_in[7];
    const float* oW1 = (const float*)d_in[8];
    const float* ob1 = (const float*)d_in[9];
    const float* oW2 = (const float*)d_in[10];
    const float* ob2 = (const float*)d_in[11];
    const int* head = (const int*)d_in[12];
    const int* tail = (const int*)d_in[13];
    float* out = (float*)d_out;

    const size_t SZ = (size_t)NN * 64;
    // budget ≈ 53.8M float-equiv < 65.3M proven in R7/R8
    _Float16* A16   = (_Float16*)d_ws;             // layer-0 emb out [NN,64] f16
    _Float16* B16   = A16 + SZ;                    // layer-0 off out [NN,64] f16
    unsigned* packedA = (unsigned*)(B16 + SZ);     // [NN,64] {EV,P} f16 pairs
    unsigned* packedB = packedA + SZ;              // [NN,64] {AO,OFF} f16 pairs
    _Float16* meanI_h = (_Float16*)(packedB + SZ); // [NU,64] f16
    _Float16* redI_h  = meanI_h + (size_t)NU * 64;
    _Float16* meanU_h = redI_h + (size_t)NU * 64;
    _Float16* redU_h  = meanU_h + (size_t)NU * 64;
    _Float16* meanE_h = redU_h + (size_t)NU * 64;  // [NENT,64] f16
    _Float16* redE_h  = meanE_h + (size_t)NENT * 64;
    _Float16* wpre    = redE_h + (size_t)NENT * 64; // 4 * 4096 f16 frag-linear tables
    int* counts   = (int*)(wpre + 4 * 4096);
    int* offsets  = counts + NN;               // NN+1
    int* cursor   = offsets + NN + 1;
    int* sorted_t = cursor + NN;               // NEDGE
    int* partials = sorted_t + NEDGE;          // SCAN_NB
    int* carries  = partials + SCAN_NB;        // SCAN_NB

    const _Float16* cW1f = wpre;
    const _Float16* cW2f = wpre + 4096;
    const _Float16* oW1f = wpre + 8192;
    const _Float16* oW2f = wpre + 12288;

    // weight prepack + CSR build (per call; layer-independent)
    prep_w<<<64, 256, 0, stream>>>(cW1, cW2, oW1, oW2, wpre);
    hipMemsetAsync(counts, 0, NN * sizeof(int), stream);
    hist_k<<<(NEDGE + 255) / 256, 256, 0, stream>>>(head, counts);
    scan_local<<<SCAN_NB, 1024, 0, stream>>>(counts, offsets, partials);
    scan_carry<<<1, 256, 0, stream>>>(partials, carries);
    scan_add<<<SCAN_NB, 1024, 0, stream>>>(offsets, carries, cursor);
    scatter_k<<<(NEDGE + 255) / 256, 256, 0, stream>>>(head, tail, cursor, sorted_t);

    // ---- layer 0: f32 inputs -> f16 A/B ----
    node_pass<float><<<(NN + 63) / 64, 256, 0, stream>>>(
        user_emb, item_emb, user_off, item_off,
        cW1f, cb1, cW2f, cb2, oW1f, ob1, packedA, packedB);
    seg_pass<true><<<NN / 4, 256, 0, stream>>>(
        packedA, packedB, offsets, sorted_t,
        A16, A16 + (size_t)NU * 64,
        meanI_h, redI_h, meanU_h, redU_h, meanE_h, redE_h);
    ent_fin<true><<<(NENT / 16 + 3) / 4, 256, 0, stream>>>(
        meanE_h, redE_h, oW2f, ob2, B16 + (size_t)NU * 64);
    user_fin2<true><<<(NU + 63) / 64, 256, 0, stream>>>(
        meanI_h, redI_h, meanU_h, redU_h, oW1f, ob1, oW2f, ob2, B16);

    // ---- layer 1: f16 inputs -> f32 outputs in d_out ----
    node_pass<_Float16><<<(NN + 63) / 64, 256, 0, stream>>>(
        A16, A16 + (size_t)NU * 64, B16, B16 + (size_t)NU * 64,
        cW1f, cb1, cW2f, cb2, oW1f, ob1, packedA, packedB);
    seg_pass<false><<<NN / 4, 256, 0, stream>>>(
        packedA, packedB, offsets, sorted_t,
        out, out + (size_t)2 * NU * 64,
        meanI_h, redI_h, meanU_h, redU_h, meanE_h, redE_h);
    ent_fin<false><<<(NENT / 16 + 3) / 4, 256, 0, stream>>>(
        meanE_h, redE_h, oW2f, ob2, out + ((size_t)2 * NU + NENT) * 64);
    user_fin2<false><<<(NU + 63) / 64, 256, 0, stream>>>(
        meanI_h, redI_h, meanU_h, redU_h, oW1f, ob1, oW2f, ob2, out + (size_t)NU * 64);
}

// Round 12
// 404.371 us; speedup vs baseline: 26.1486x; 1.0787x over previous
//
#include <hip/hip_runtime.h>
#include <hip/hip_fp16.h>
#include <math.h>

#define NU 100000
#define NI 50000
#define NENT 80000
#define NN 180000
#define NEDGE 800000
#define SCAN_NB ((NN + 1023) / 1024)   // 176
#define UFIN_BLKS ((NU + 63) / 64)     // 1563
#define EFIN_BLKS (NENT / 64)          // 1250

typedef _Float16 f16x4 __attribute__((ext_vector_type(4)));
typedef _Float16 f16x2 __attribute__((ext_vector_type(2)));
typedef float f32x4 __attribute__((ext_vector_type(4)));

__device__ __forceinline__ float sigmoid_f(float x) { return 1.0f / (1.0f + __expf(-x)); }
__device__ __forceinline__ unsigned pack2(float a, float b) {
    __half2 h = __floats2half2_rn(a, b);
    return *(unsigned*)&h;
}
__device__ __forceinline__ f16x2 u2h2(unsigned u) { union { unsigned u; f16x2 h; } x; x.u = u; return x.h; }
__device__ __forceinline__ float fdot2f(f16x2 a, f16x2 b, float c) {
#if __has_builtin(__builtin_amdgcn_fdot2)
    return __builtin_amdgcn_fdot2(a, b, c, false);
#else
    return (float)a[0] * (float)b[0] + (float)a[1] * (float)b[1] + c;
#endif
}
__device__ __forceinline__ _Float16 hminf(_Float16 a, _Float16 b) { return a < b ? a : b; }
__device__ __forceinline__ _Float16 hmaxf(_Float16 a, _Float16 b) { return a > b ? a : b; }

// frag load (f32: convert; f16: direct)
template<typename T>
__device__ __forceinline__ f16x4 ldfrag(const T* __restrict__ p) {
    if constexpr (sizeof(T) == 2) {
        return *(const f16x4*)p;
    } else {
        float4 v = *(const float4*)p;
        f16x4 r; r[0] = (_Float16)v.x; r[1] = (_Float16)v.y; r[2] = (_Float16)v.z; r[3] = (_Float16)v.w;
        return r;
    }
}
template<typename T>
__device__ __forceinline__ f16x4 ldfragr(const T* __restrict__ p) {   // relu before/after cvt
    if constexpr (sizeof(T) == 2) {
        f16x4 v = *(const f16x4*)p;
        #pragma unroll
        for (int i = 0; i < 4; ++i) v[i] = hmaxf(v[i], (_Float16)0.f);
        return v;
    } else {
        float4 v = *(const float4*)p;
        f16x4 r;
        r[0] = (_Float16)fmaxf(v.x, 0.f); r[1] = (_Float16)fmaxf(v.y, 0.f);
        r[2] = (_Float16)fmaxf(v.z, 0.f); r[3] = (_Float16)fmaxf(v.w, 0.f);
        return r;
    }
}
// prepacked weight frag: coalesced 8B/lane from an L1-resident 8KB table
__device__ __forceinline__ f16x4 fragp(const _Float16* __restrict__ Wp, int dt, int ks, int lane) {
    return *(const f16x4*)(Wp + (((dt * 4 + ks) * 64 + lane) << 2));
}
__device__ __forceinline__ f32x4 mm(f16x4 a, f16x4 b, f32x4 c) {
    return __builtin_amdgcn_mfma_f32_16x16x16f16(a, b, c, 0, 0, 0);
}

// ---------------- weight prepack: f32 row-major -> frag-linear f16 ----------------
__global__ __launch_bounds__(256) void prep_w(
    const float* __restrict__ W0, const float* __restrict__ W1,
    const float* __restrict__ W2, const float* __restrict__ W3,
    _Float16* __restrict__ out)
{
    int idx = blockIdx.x * 256 + threadIdx.x;          // 0 .. 16383
    int mat = idx >> 12, wi = idx & 4095;
    const float* W = (mat == 0) ? W0 : (mat == 1) ? W1 : (mat == 2) ? W2 : W3;
    int tile = wi >> 8;            // dt*4+ks
    int dt = tile >> 2, ks = tile & 3;
    int ln = (wi >> 2) & 63, j = wi & 3;
    int lr = ln & 15, lk = ln >> 4;
    out[idx] = (_Float16)W[(size_t)(dt * 16 + lr) * 64 + ks * 16 + lk * 4 + j];
}

// ---------------- node pass: 16 nodes/wave via MFMA; writes split f16 pairs ----------------
template<typename T>
__global__ __launch_bounds__(256) void node_pass(
    const T* __restrict__ embU, const T* __restrict__ embE,
    const T* __restrict__ offU, const T* __restrict__ offE,
    const _Float16* __restrict__ cW1f, const float* __restrict__ cb1,
    const _Float16* __restrict__ cW2f, const float* __restrict__ cb2,
    const _Float16* __restrict__ oW1f, const float* __restrict__ ob1,
    unsigned* __restrict__ packedA, unsigned* __restrict__ packedB)
{
    __shared__ _Float16 tb[4][16 * 72];   // per-wave transpose tile, +8 f16 pad
    int lane = threadIdx.x & 63, wid = threadIdx.x >> 6;
    int n0 = (blockIdx.x * 4 + wid) * 16;
    if (n0 >= NN) return;
    int lr = lane & 15, lk = lane >> 4;
    const T* eb; const T* ob;
    if (n0 < NU) { eb = embU + (size_t)n0 * 64; ob = offU + (size_t)n0 * 64; }
    else         { eb = embE + (size_t)(n0 - NU) * 64; ob = offE + (size_t)(n0 - NU) * 64; }

    // ---- center net: a1 = relu(W1 x + b1) ----
    f16x4 ax[4];
    #pragma unroll
    for (int ks = 0; ks < 4; ++ks) ax[ks] = ldfrag(eb + (size_t)lr * 64 + ks * 16 + lk * 4);
    f32x4 acc[4];
    #pragma unroll
    for (int dt = 0; dt < 4; ++dt) {
        float b = cb1[dt * 16 + lr];
        f32x4 c = {b, b, b, b};
        #pragma unroll
        for (int ks = 0; ks < 4; ++ks) c = mm(ax[ks], fragp(cW1f, dt, ks, lane), c);
        acc[dt] = c;
    }
    _Float16* T16 = tb[wid];
    #pragma unroll
    for (int dt = 0; dt < 4; ++dt)
        #pragma unroll
        for (int r = 0; r < 4; ++r)
            T16[(lk * 4 + r) * 72 + dt * 16 + lr] = (_Float16)fmaxf(acc[dt][r], 0.f);
    f16x4 a1[4];
    #pragma unroll
    for (int ks = 0; ks < 4; ++ks) a1[ks] = *(const f16x4*)(T16 + lr * 72 + ks * 16 + lk * 4);
    #pragma unroll
    for (int dt = 0; dt < 4; ++dt) {
        float b = cb2[dt * 16 + lr];
        f32x4 c = {b, b, b, b};
        #pragma unroll
        for (int ks = 0; ks < 4; ++ks) c = mm(a1[ks], fragp(cW2f, dt, ks, lane), c);
        acc[dt] = c;
    }
    // ---- offset net: ao = relu(O1 relu(o) + ob1) ----
    f16x4 axo[4];
    #pragma unroll
    for (int ks = 0; ks < 4; ++ks) axo[ks] = ldfragr(ob + (size_t)lr * 64 + ks * 16 + lk * 4);
    f32x4 acco[4];
    #pragma unroll
    for (int dt = 0; dt < 4; ++dt) {
        float b = ob1[dt * 16 + lr];
        f32x4 c = {b, b, b, b};
        #pragma unroll
        for (int ks = 0; ks < 4; ++ks) c = mm(axo[ks], fragp(oW1f, dt, ks, lane), c);
        acco[dt] = c;
    }
    // ---- transpose x to D-layout via T (wave-private sequential reuse; no barrier) ----
    #pragma unroll
    for (int ks = 0; ks < 4; ++ks) *(f16x4*)(T16 + lr * 72 + ks * 16 + lk * 4) = ax[ks];
    _Float16 xv[16];
    #pragma unroll
    for (int dt = 0; dt < 4; ++dt)
        #pragma unroll
        for (int r = 0; r < 4; ++r) xv[dt * 4 + r] = T16[(lk * 4 + r) * 72 + dt * 16 + lr];
    // ---- transpose relu(o) similarly ----
    #pragma unroll
    for (int ks = 0; ks < 4; ++ks) *(f16x4*)(T16 + lr * 72 + ks * 16 + lk * 4) = axo[ks];
    #pragma unroll
    for (int dt = 0; dt < 4; ++dt) {
        #pragma unroll
        for (int r = 0; r < 4; ++r) {
            int li = lk * 4 + r;
            float ev = __expf(acc[dt][r]);   // segment-max shift skipped: |lg| << 1
            float xf = (float)xv[dt * 4 + r];
            float ovf = (float)T16[(lk * 4 + r) * 72 + dt * 16 + lr];
            float aov = fmaxf(acco[dt][r], 0.f);
            size_t idx = (size_t)(n0 + li) * 64 + dt * 16 + lr;
            packedA[idx] = pack2(ev, ev * xf);
            packedB[idx] = pack2(aov, ovf);
        }
    }
}

// ---------------- CSR build ----------------
__global__ __launch_bounds__(256) void hist_k(const int* __restrict__ head, int* __restrict__ counts) {
    int e = blockIdx.x * 256 + threadIdx.x;
    if (e < NEDGE) atomicAdd(&counts[head[e]], 1);
}

__global__ __launch_bounds__(1024) void scan_local(const int* __restrict__ counts,
                                                   int* __restrict__ excl, int* __restrict__ partials) {
    __shared__ int wsum[16];
    int tid = threadIdx.x, lane = tid & 63, wid = tid >> 6;
    int i = blockIdx.x * 1024 + tid;
    int v = (i < NN) ? counts[i] : 0;
    int s = v;
    #pragma unroll
    for (int d = 1; d < 64; d <<= 1) { int u = __shfl_up(s, d, 64); if (lane >= d) s += u; }
    if (lane == 63) wsum[wid] = s;
    __syncthreads();
    if (wid == 0 && lane < 16) {
        int w = wsum[lane];
        #pragma unroll
        for (int d = 1; d < 16; d <<= 1) { int u = __shfl_up(w, d, 64); if (lane >= d) w += u; }
        wsum[lane] = w;
    }
    __syncthreads();
    int base = wid ? wsum[wid - 1] : 0;
    if (i < NN) excl[i] = base + s - v;
    if (tid == 1023) partials[blockIdx.x] = wsum[15];
}

__global__ __launch_bounds__(256) void scan_carry(const int* __restrict__ partials, int* __restrict__ carries) {
    __shared__ int ws[4];
    int tid = threadIdx.x, lane = tid & 63, wid = tid >> 6;
    int v = (tid < SCAN_NB) ? partials[tid] : 0;
    int s = v;
    #pragma unroll
    for (int d = 1; d < 64; d <<= 1) { int u = __shfl_up(s, d, 64); if (lane >= d) s += u; }
    if (lane == 63) ws[wid] = s;
    __syncthreads();
    int add = 0;
    for (int w = 0; w < wid; ++w) add += ws[w];
    if (tid < SCAN_NB) carries[tid] = add + s - v;
}

__global__ __launch_bounds__(1024) void scan_add(int* __restrict__ excl, const int* __restrict__ carries,
                                                 int* __restrict__ cursor) {
    int i = blockIdx.x * 1024 + threadIdx.x;
    if (i < NN) { int o = excl[i] + carries[blockIdx.x]; excl[i] = o; cursor[i] = o; }
    if (i == 0) excl[NN] = NEDGE;
}

__global__ __launch_bounds__(256) void scatter_k(const int* __restrict__ head, const int* __restrict__ tail,
                                                 int* __restrict__ cursor, int* __restrict__ sorted_t) {
    int e = blockIdx.x * 256 + threadIdx.x;
    if (e < NEDGE) { int pos = atomicAdd(&cursor[head[e]], 1); sorted_t[pos] = tail[e]; }
}

// ---------------- segment pass: one wave per head; move-free 2-slot pipeline ----------------
template<bool OUT16>
__global__ __launch_bounds__(256) void seg_pass(
    const unsigned* __restrict__ packedA, const unsigned* __restrict__ packedB,
    const int* __restrict__ offsets, const int* __restrict__ sorted_t,
    void* __restrict__ embOutU_, void* __restrict__ embOutE_,
    _Float16* __restrict__ meanI, _Float16* __restrict__ redI,
    _Float16* __restrict__ meanU, _Float16* __restrict__ redU,
    _Float16* __restrict__ meanE, _Float16* __restrict__ redE)
{
    int lane = threadIdx.x & 63;
    int h = blockIdx.x * 4 + (threadIdx.x >> 6);    // NN % 4 == 0
    int beg = offsets[h], end = offsets[h + 1];
    bool isUser = (h < NU);
    bool entMin = (h >= NU + NI);
    const f16x2 SEL_LO = {(_Float16)1.0f, (_Float16)0.0f};
    const f16x2 SEL_HI = {(_Float16)0.0f, (_Float16)1.0f};
    float num = 0.f, den = 0.f, s_i = 0.f, s_u = 0.f;
    const _Float16 HINF = u2h2(0x7C007C00u)[0];
    _Float16 m_i = (isUser || entMin) ? HINF : (_Float16)0.f;   // min classes start at +inf
    _Float16 m_u = (_Float16)0.f;
    int c_i = 0, c_u = 0;

    const char* pA = (const char*)packedA;
    const char* pB = (const char*)packedB;
    int loff = lane << 2;

#define LOADQ(t, a, b)                                                          \
    do {                                                                        \
        a = *(const unsigned*)(pA + ((size_t)(unsigned)(t) << 8) + loff);       \
        if (!isUser || (t) >= NU)                                               \
            b = *(const unsigned*)(pB + ((size_t)(unsigned)(t) << 8) + loff);   \
    } while (0)

#define CONSUME(tc, qa, qb)                                                     \
    do {                                                                        \
        f16x2 ea = u2h2(qa);                                                    \
        den = fdot2f(ea, SEL_LO, den);                                          \
        num = fdot2f(ea, SEL_HI, num);                                          \
        if (isUser) {                                                           \
            if ((tc) >= NU) {                                                   \
                f16x2 ab = u2h2(qb);                                            \
                if ((tc) < NU + NI) { s_i = fdot2f(ab, SEL_LO, s_i); m_i = hminf(m_i, ab[1]); c_i++; } \
                else                { s_u = fdot2f(ab, SEL_LO, s_u); m_u = hmaxf(m_u, ab[1]); c_u++; } \
            }                                                                   \
        } else {                                                                \
            f16x2 ab = u2h2(qb);                                                \
            s_i = fdot2f(ab, SEL_LO, s_i); c_i++;                               \
            m_i = entMin ? hminf(m_i, ab[1]) : hmaxf(m_i, ab[1]);               \
        }                                                                       \
    } while (0)

    for (int base = beg; base < end; base += 64) {
        int rem = end - base; if (rem > 64) rem = 64;
        int tv = sorted_t[base + (lane < rem ? lane : 0)];
        // two slots, consumed then reloaded in place: no register rotation moves
        int tA = 0, tB = 0; unsigned aA = 0, aB = 0, bA = 0, bB = 0;
        tA = __builtin_amdgcn_readlane(tv, 0);
        LOADQ(tA, aA, bA);
        if (rem > 1) { tB = __builtin_amdgcn_readlane(tv, 1); LOADQ(tB, aB, bB); }
        int j = 0;
        for (; j + 2 <= rem; j += 2) {
            CONSUME(tA, aA, bA);
            if (j + 2 < rem) { tA = __builtin_amdgcn_readlane(tv, j + 2); LOADQ(tA, aA, bA); }
            CONSUME(tB, aB, bB);
            if (j + 3 < rem) { tB = __builtin_amdgcn_readlane(tv, j + 3); LOADQ(tB, aB, bB); }
        }
        if (j < rem) CONSUME(tA, aA, bA);   // odd tail
    }
#undef LOADQ
#undef CONSUME

    // center: softmax-weighted mean + row L2 normalize
    float v = (den > 0.f) ? num / den : 0.f;
    float sq = v * v;
    #pragma unroll
    for (int m = 32; m; m >>= 1) sq += __shfl_xor(sq, m, 64);
    v = v / fmaxf(sqrtf(sq), 1e-12f);

    float m_if = (float)m_i;
    if (m_if > 1e37f) m_if = 0.f;                   // empty min-segment -> 0
    float rc_i = __builtin_amdgcn_rcpf(fmaxf((float)c_i, 1.f));
    if (isUser) {
        size_t r = (size_t)h * 64 + lane;
        if constexpr (OUT16) ((_Float16*)embOutU_)[r] = (_Float16)v;
        else                 ((float*)embOutU_)[r] = v;
        float rc_u = __builtin_amdgcn_rcpf(fmaxf((float)c_u, 1.f));
        meanI[r] = (_Float16)(s_i * rc_i);
        redI[r]  = (_Float16)m_if;
        meanU[r] = (_Float16)(s_u * rc_u);
        redU[r]  = m_u;
    } else {
        size_t r = (size_t)(h - NU) * 64 + lane;
        if constexpr (OUT16) ((_Float16*)embOutE_)[r] = (_Float16)v;
        else                 ((float*)embOutE_)[r] = v;
        meanE[r] = (_Float16)(s_i * rc_i);
        redE[r]  = (_Float16)m_if;
    }
}

// ---------------- fused finalize: user blocks then ent blocks ----------------
template<bool OUT16>
__global__ __launch_bounds__(256) void fin_pass(
    const _Float16* __restrict__ meanI, const _Float16* __restrict__ redI,
    const _Float16* __restrict__ meanU, const _Float16* __restrict__ redU,
    const _Float16* __restrict__ meanE, const _Float16* __restrict__ redE,
    const _Float16* __restrict__ oW1f, const float* __restrict__ ob1,
    const _Float16* __restrict__ oW2f, const float* __restrict__ ob2,
    void* __restrict__ outOffU_, void* __restrict__ entOff_)
{
    int lane = threadIdx.x & 63, wid = threadIdx.x >> 6;
    int lr = lane & 15, lk = lane >> 4;

    if (blockIdx.x >= UFIN_BLKS) {
        // ---- ent part: gate matvec only ----
        int n0 = (((int)blockIdx.x - UFIN_BLKS) * 4 + wid) * 16;
        if (n0 >= NENT) return;
        f16x4 am[4];
        #pragma unroll
        for (int ks = 0; ks < 4; ++ks) am[ks] = *(const f16x4*)(meanE + (size_t)(n0 + lr) * 64 + ks * 16 + lk * 4);
        #pragma unroll
        for (int dt = 0; dt < 4; ++dt) {
            float b = ob2[dt * 16 + lr];
            f32x4 c = {b, b, b, b};
            #pragma unroll
            for (int ks = 0; ks < 4; ++ks) c = mm(am[ks], fragp(oW2f, dt, ks, lane), c);
            #pragma unroll
            for (int r = 0; r < 4; ++r) {
                size_t row = (size_t)(n0 + lk * 4 + r);
                float val = (float)redE[row * 64 + dt * 16 + lr] * sigmoid_f(c[r]);
                if constexpr (OUT16) ((_Float16*)entOff_)[row * 64 + dt * 16 + lr] = (_Float16)val;
                else                 ((float*)entOff_)[row * 64 + dt * 16 + lr] = val;
            }
        }
        return;
    }

    // ---- user part: fused 2-level offset net ----
    __shared__ _Float16 tb[4][16 * 72];
    int u0 = (blockIdx.x * 4 + wid) * 16;
    if (u0 >= NU) return;
    _Float16* T16 = tb[wid];

    f16x4 W1f[4][4], W2f[4][4];
    float b1d[4], b2d[4];
    #pragma unroll
    for (int dt = 0; dt < 4; ++dt) {
        b1d[dt] = ob1[dt * 16 + lr]; b2d[dt] = ob2[dt * 16 + lr];
        #pragma unroll
        for (int ks = 0; ks < 4; ++ks) {
            W1f[dt][ks] = fragp(oW1f, dt, ks, lane);
            W2f[dt][ks] = fragp(oW2f, dt, ks, lane);
        }
    }

    f16x4 am[4];
    #pragma unroll
    for (int ks = 0; ks < 4; ++ks) am[ks] = *(const f16x4*)(meanI + (size_t)(u0 + lr) * 64 + ks * 16 + lk * 4);
    f32x4 iu[4], uu[4];
    #pragma unroll
    for (int dt = 0; dt < 4; ++dt) {
        f32x4 c = {b2d[dt], b2d[dt], b2d[dt], b2d[dt]};
        #pragma unroll
        for (int ks = 0; ks < 4; ++ks) c = mm(am[ks], W2f[dt][ks], c);
        #pragma unroll
        for (int r = 0; r < 4; ++r)
            iu[dt][r] = (float)redI[(size_t)(u0 + lk * 4 + r) * 64 + dt * 16 + lr] * sigmoid_f(c[r]);
    }
    #pragma unroll
    for (int ks = 0; ks < 4; ++ks) am[ks] = *(const f16x4*)(meanU + (size_t)(u0 + lr) * 64 + ks * 16 + lk * 4);
    #pragma unroll
    for (int dt = 0; dt < 4; ++dt) {
        f32x4 c = {b2d[dt], b2d[dt], b2d[dt], b2d[dt]};
        #pragma unroll
        for (int ks = 0; ks < 4; ++ks) c = mm(am[ks], W2f[dt][ks], c);
        #pragma unroll
        for (int r = 0; r < 4; ++r)
            uu[dt][r] = (float)redU[(size_t)(u0 + lk * 4 + r) * 64 + dt * 16 + lr] * sigmoid_f(c[r]);
    }
    #pragma unroll
    for (int dt = 0; dt < 4; ++dt)
        #pragma unroll
        for (int r = 0; r < 4; ++r) T16[(lk * 4 + r) * 72 + dt * 16 + lr] = (_Float16)iu[dt][r];
    #pragma unroll
    for (int ks = 0; ks < 4; ++ks) am[ks] = *(const f16x4*)(T16 + lr * 72 + ks * 16 + lk * 4);
    f32x4 mn[4];
    #pragma unroll
    for (int dt = 0; dt < 4; ++dt) {
        f32x4 c = {b1d[dt], b1d[dt], b1d[dt], b1d[dt]};
        #pragma unroll
        for (int ks = 0; ks < 4; ++ks) c = mm(am[ks], W1f[dt][ks], c);
        #pragma unroll
        for (int r = 0; r < 4; ++r) mn[dt][r] = fmaxf(c[r], 0.f);
    }
    #pragma unroll
    for (int dt = 0; dt < 4; ++dt)
        #pragma unroll
        for (int r = 0; r < 4; ++r) T16[(lk * 4 + r) * 72 + dt * 16 + lr] = (_Float16)uu[dt][r];
    #pragma unroll
    for (int ks = 0; ks < 4; ++ks) am[ks] = *(const f16x4*)(T16 + lr * 72 + ks * 16 + lk * 4);
    #pragma unroll
    for (int dt = 0; dt < 4; ++dt) {
        f32x4 c = {b1d[dt], b1d[dt], b1d[dt], b1d[dt]};
        #pragma unroll
        for (int ks = 0; ks < 4; ++ks) c = mm(am[ks], W1f[dt][ks], c);
        #pragma unroll
        for (int r = 0; r < 4; ++r) mn[dt][r] = 0.5f * (mn[dt][r] + fmaxf(c[r], 0.f));
    }
    #pragma unroll
    for (int dt = 0; dt < 4; ++dt)
        #pragma unroll
        for (int r = 0; r < 4; ++r) T16[(lk * 4 + r) * 72 + dt * 16 + lr] = (_Float16)mn[dt][r];
    #pragma unroll
    for (int ks = 0; ks < 4; ++ks) am[ks] = *(const f16x4*)(T16 + lr * 72 + ks * 16 + lk * 4);
    #pragma unroll
    for (int dt = 0; dt < 4; ++dt) {
        f32x4 c = {b2d[dt], b2d[dt], b2d[dt], b2d[dt]};
        #pragma unroll
        for (int ks = 0; ks < 4; ++ks) c = mm(am[ks], W2f[dt][ks], c);
        #pragma unroll
        for (int r = 0; r < 4; ++r) {
            float val = fmaxf(fmaxf(iu[dt][r], uu[dt][r]) * sigmoid_f(c[r]), 0.f);
            size_t idx = (size_t)(u0 + lk * 4 + r) * 64 + dt * 16 + lr;
            if constexpr (OUT16) ((_Float16*)outOffU_)[idx] = (_Float16)val;
            else                 ((float*)outOffU_)[idx] = val;
        }
    }
}

extern "C" void kernel_launch(void* const* d_in, const int* in_sizes, int n_in,
                              void* d_out, int out_size, void* d_ws, size_t ws_size,
                              hipStream_t stream)
{
    const float* user_emb = (const float*)d_in[0];
    const float* user_off = (const float*)d_in[1];
    const float* item_emb = (const float*)d_in[2];
    const float* item_off = (const float*)d_in[3];
    const float* cW1 = (const float*)d_in[4];
    const float* cb1 = (const float*)d_in[5];
    const float* cW2 = (const float*)d_in[6];
    const float* cb2 = (const float*)d_in[7];
    const float* oW1 = (const float*)d_in[8];
    const float* ob1 = (const float*)d_in[9];
    const float* oW2 = (const float*)d_in[10];
    const float* ob2 = (const float*)d_in[11];
    const int* head = (const int*)d_in[12];
    const int* tail = (const int*)d_in[13];
    float* out = (float*)d_out;

    const size_t SZ = (size_t)NN * 64;
    // budget ≈ 53.8M float-equiv < 65.3M proven in R7/R8
    _Float16* A16   = (_Float16*)d_ws;             // layer-0 emb out [NN,64] f16
    _Float16* B16   = A16 + SZ;                    // layer-0 off out [NN,64] f16
    unsigned* packedA = (unsigned*)(B16 + SZ);     // [NN,64] {EV,P} f16 pairs
    unsigned* packedB = packedA + SZ;              // [NN,64] {AO,OFF} f16 pairs
    _Float16* meanI_h = (_Float16*)(packedB + SZ); // [NU,64] f16
    _Float16* redI_h  = meanI_h + (size_t)NU * 64;
    _Float16* meanU_h = redI_h + (size_t)NU * 64;
    _Float16* redU_h  = meanU_h + (size_t)NU * 64;
    _Float16* meanE_h = redU_h + (size_t)NU * 64;  // [NENT,64] f16
    _Float16* redE_h  = meanE_h + (size_t)NENT * 64;
    _Float16* wpre    = redE_h + (size_t)NENT * 64; // 4 * 4096 f16 frag-linear tables
    int* counts   = (int*)(wpre + 4 * 4096);
    int* offsets  = counts + NN;               // NN+1
    int* cursor   = offsets + NN + 1;
    int* sorted_t = cursor + NN;               // NEDGE
    int* partials = sorted_t + NEDGE;          // SCAN_NB
    int* carries  = partials + SCAN_NB;        // SCAN_NB

    const _Float16* cW1f = wpre;
    const _Float16* cW2f = wpre + 4096;
    const _Float16* oW1f = wpre + 8192;
    const _Float16* oW2f = wpre + 12288;

    // weight prepack + CSR build (per call; layer-independent)
    prep_w<<<64, 256, 0, stream>>>(cW1, cW2, oW1, oW2, wpre);
    hipMemsetAsync(counts, 0, NN * sizeof(int), stream);
    hist_k<<<(NEDGE + 255) / 256, 256, 0, stream>>>(head, counts);
    scan_local<<<SCAN_NB, 1024, 0, stream>>>(counts, offsets, partials);
    scan_carry<<<1, 256, 0, stream>>>(partials, carries);
    scan_add<<<SCAN_NB, 1024, 0, stream>>>(offsets, carries, cursor);
    scatter_k<<<(NEDGE + 255) / 256, 256, 0, stream>>>(head, tail, cursor, sorted_t);

    // ---- layer 0: f32 inputs -> f16 A/B ----
    node_pass<float><<<(NN + 63) / 64, 256, 0, stream>>>(
        user_emb, item_emb, user_off, item_off,
        cW1f, cb1, cW2f, cb2, oW1f, ob1, packedA, packedB);
    seg_pass<true><<<NN / 4, 256, 0, stream>>>(
        packedA, packedB, offsets, sorted_t,
        A16, A16 + (size_t)NU * 64,
        meanI_h, redI_h, meanU_h, redU_h, meanE_h, redE_h);
    fin_pass<true><<<UFIN_BLKS + EFIN_BLKS, 256, 0, stream>>>(
        meanI_h, redI_h, meanU_h, redU_h, meanE_h, redE_h,
        oW1f, ob1, oW2f, ob2, B16, B16 + (size_t)NU * 64);

    // ---- layer 1: f16 inputs -> f32 outputs in d_out ----
    node_pass<_Float16><<<(NN + 63) / 64, 256, 0, stream>>>(
        A16, A16 + (size_t)NU * 64, B16, B16 + (size_t)NU * 64,
        cW1f, cb1, cW2f, cb2, oW1f, ob1, packedA, packedB);
    seg_pass<false><<<NN / 4, 256, 0, stream>>>(
        packedA, packedB, offsets, sorted_t,
        out, out + (size_t)2 * NU * 64,
        meanI_h, redI_h, meanU_h, redU_h, meanE_h, redE_h);
    fin_pass<false><<<UFIN_BLKS + EFIN_BLKS, 256, 0, stream>>>(
        meanI_h, redI_h, meanU_h, redU_h, meanE_h, redE_h,
        oW1f, ob1, oW2f, ob2, out + (size_t)NU * 64, out + ((size_t)2 * NU + NENT) * 64);
}